// Round 1
// baseline (1893.315 us; speedup 1.0000x reference)
//
#include <hip/hip_runtime.h>
#include <hip/hip_bf16.h>
#include <math.h>

// Problem constants
#define BB 2
#define TT 2048
#define CC 1024
#define HH 16
#define DD 64
#define CHALF 512
#define NN (BB * TT)   // 4096 rows

__device__ __forceinline__ float gelu_exact(float x) {
    // jax.nn.gelu(approximate=False): 0.5*x*(1+erf(x/sqrt(2)))
    return 0.5f * x * (1.0f + erff(x * 0.70710678118654752f));
}

// ---------------------------------------------------------------------------
// Tiled fp32 GEMM: C[M,N] = A[M,K] @ W[K,N] + bias[N]
// 64x64 tile, 256 threads, 4x4 microtile, K-step 16. All dims multiples of 64/16.
// ---------------------------------------------------------------------------
__global__ __launch_bounds__(256) void gemm_bias(
    const float* __restrict__ A, const float* __restrict__ W,
    const float* __restrict__ bias, float* __restrict__ C,
    int M, int N, int K) {
    __shared__ float As[16][64];  // [k][row]  (transposed on store)
    __shared__ float Ws[16][64];  // [k][col]
    int tid = threadIdx.x;
    int tx = tid & 15, ty = tid >> 4;
    int row0 = blockIdx.y * 64;
    int col0 = blockIdx.x * 64;

    // loader indices
    int lar = tid >> 2;          // 0..63 : A row within tile
    int lak = (tid & 3) * 4;     // 0..12 : A k-chunk
    int lwk = tid >> 4;          // 0..15 : W k within tile
    int lwc = (tid & 15) * 4;    // 0..60 : W col chunk

    float acc[4][4] = {};
    for (int k0 = 0; k0 < K; k0 += 16) {
        float4 av = *(const float4*)&A[(size_t)(row0 + lar) * K + k0 + lak];
        As[lak + 0][lar] = av.x;
        As[lak + 1][lar] = av.y;
        As[lak + 2][lar] = av.z;
        As[lak + 3][lar] = av.w;
        float4 wv = *(const float4*)&W[(size_t)(k0 + lwk) * N + col0 + lwc];
        *(float4*)&Ws[lwk][lwc] = wv;
        __syncthreads();
#pragma unroll
        for (int kk = 0; kk < 16; ++kk) {
            float4 a = *(const float4*)&As[kk][ty * 4];
            float4 bvec = *(const float4*)&Ws[kk][tx * 4];
            float ar[4] = {a.x, a.y, a.z, a.w};
            float br[4] = {bvec.x, bvec.y, bvec.z, bvec.w};
#pragma unroll
            for (int i = 0; i < 4; ++i)
#pragma unroll
                for (int j = 0; j < 4; ++j)
                    acc[i][j] = fmaf(ar[i], br[j], acc[i][j]);
        }
        __syncthreads();
    }
#pragma unroll
    for (int i = 0; i < 4; ++i) {
        int r = row0 + ty * 4 + i;
#pragma unroll
        for (int j = 0; j < 4; ++j) {
            int c = col0 + tx * 4 + j;
            C[(size_t)r * N + c] = acc[i][j] + bias[c];
        }
    }
}

// ---------------------------------------------------------------------------
// Row-wise LayerNorm + exact GELU, in place. One block per row.
// ---------------------------------------------------------------------------
template <int WIDTH>
__global__ __launch_bounds__(256) void ln_gelu_kernel(
    float* __restrict__ Y, const float* __restrict__ g,
    const float* __restrict__ beta) {
    constexpr int PT = WIDTH / 256;
    int row = blockIdx.x;
    int tid = threadIdx.x;
    float* yr = Y + (size_t)row * WIDTH;
    float v[PT];
    float s = 0.f;
#pragma unroll
    for (int i = 0; i < PT; ++i) {
        v[i] = yr[i * 256 + tid];
        s += v[i];
    }
    __shared__ float red[256];
    red[tid] = s;
    __syncthreads();
#pragma unroll
    for (int o = 128; o > 0; o >>= 1) {
        if (tid < o) red[tid] += red[tid + o];
        __syncthreads();
    }
    float mean = red[0] * (1.0f / WIDTH);
    __syncthreads();
    s = 0.f;
#pragma unroll
    for (int i = 0; i < PT; ++i) {
        float d = v[i] - mean;
        s += d * d;
    }
    red[tid] = s;
    __syncthreads();
#pragma unroll
    for (int o = 128; o > 0; o >>= 1) {
        if (tid < o) red[tid] += red[tid + o];
        __syncthreads();
    }
    float inv = rsqrtf(red[0] * (1.0f / WIDTH) + 1e-5f);
#pragma unroll
    for (int i = 0; i < PT; ++i) {
        int c = i * 256 + tid;
        yr[c] = gelu_exact((v[i] - mean) * inv * g[c] + beta[c]);
    }
}

// ---------------------------------------------------------------------------
// importance = max(sigmoid(h1 . imp_w2 + b2), 1e-6); xi = x * importance
// One block per row.
// ---------------------------------------------------------------------------
__global__ __launch_bounds__(256) void imp_scale(
    const float* __restrict__ h1, const float* __restrict__ w2,
    const float* __restrict__ b2, const float* __restrict__ x,
    float* __restrict__ xi) {
    int row = blockIdx.x;
    int tid = threadIdx.x;
    const float* hr = h1 + (size_t)row * CHALF;
    float s = hr[tid] * w2[tid] + hr[tid + 256] * w2[tid + 256];
    __shared__ float red[256];
    red[tid] = s;
    __syncthreads();
#pragma unroll
    for (int o = 128; o > 0; o >>= 1) {
        if (tid < o) red[tid] += red[tid + o];
        __syncthreads();
    }
    float z = red[0] + b2[0];
    float sg = 1.0f / (1.0f + expf(-z));
    float imp = fmaxf(sg, 1e-6f);
#pragma unroll
    for (int i = 0; i < 4; ++i) {
        int c = i * 256 + tid;
        xi[(size_t)row * CC + c] = x[(size_t)row * CC + c] * imp;
    }
}

// ---------------------------------------------------------------------------
// reasoned.mean(axis=1): two-stage, deterministic
// ---------------------------------------------------------------------------
__global__ __launch_bounds__(256) void mean_part(
    const float* __restrict__ R, float* __restrict__ part) {
    int idx = blockIdx.x * 256 + threadIdx.x;  // [b][chunk][c], 2*16*1024
    int c = idx & (CC - 1);
    int chunk = (idx >> 10) & 15;
    int b = idx >> 14;
    const float* base = R + ((size_t)(b * TT + chunk * 128)) * CC + c;
    float s = 0.f;
    for (int t = 0; t < 128; ++t) s += base[(size_t)t * CC];
    part[idx] = s;
}

__global__ __launch_bounds__(256) void mean_fin(
    const float* __restrict__ part, float* __restrict__ rm) {
    int idx = blockIdx.x * 256 + threadIdx.x;  // b*CC + c, 2048 total
    int c = idx & (CC - 1);
    int b = idx >> 10;
    float s = 0.f;
#pragma unroll
    for (int ch = 0; ch < 16; ++ch) s += part[(size_t)(b * 16 + ch) * CC + c];
    rm[idx] = s * (1.0f / TT);
}

// ---------------------------------------------------------------------------
// temp_net: rm[B,C] -> Linear(C,CH) -> LN -> GELU -> Linear(CH,H) -> softplus+0.5
// One block (512 threads) per batch element.
// ---------------------------------------------------------------------------
__global__ __launch_bounds__(512) void temp_net(
    const float* __restrict__ rm, const float* __restrict__ w1,
    const float* __restrict__ b1, const float* __restrict__ g,
    const float* __restrict__ beta, const float* __restrict__ w2,
    const float* __restrict__ b2, float* __restrict__ temp) {
    __shared__ float xr[CC];
    __shared__ float ht[CHALF];
    __shared__ float red[512];
    int b = blockIdx.x;
    int tid = threadIdx.x;
    xr[tid] = rm[b * CC + tid];
    xr[tid + 512] = rm[b * CC + tid + 512];
    __syncthreads();
    float acc = b1[tid];
#pragma unroll 8
    for (int i = 0; i < CC; ++i) acc = fmaf(xr[i], w1[(size_t)i * CHALF + tid], acc);
    // LN over 512
    red[tid] = acc;
    __syncthreads();
#pragma unroll
    for (int o = 256; o > 0; o >>= 1) {
        if (tid < o) red[tid] += red[tid + o];
        __syncthreads();
    }
    float mean = red[0] * (1.0f / CHALF);
    __syncthreads();
    float d = acc - mean;
    red[tid] = d * d;
    __syncthreads();
#pragma unroll
    for (int o = 256; o > 0; o >>= 1) {
        if (tid < o) red[tid] += red[tid + o];
        __syncthreads();
    }
    float inv = rsqrtf(red[0] * (1.0f / CHALF) + 1e-5f);
    ht[tid] = gelu_exact((acc - mean) * inv * g[tid] + beta[tid]);
    __syncthreads();
    if (tid < HH) {
        float s = b2[tid];
        for (int i = 0; i < CHALF; ++i) s = fmaf(ht[i], w2[i * HH + tid], s);
        // stable softplus: max(s,0) + log1p(exp(-|s|))
        float sp = fmaxf(s, 0.f) + log1pf(expf(-fabsf(s)));
        temp[b * HH + tid] = sp + 0.5f;
    }
}

// ---------------------------------------------------------------------------
// Flash attention, fp32. One block per (b, h, 64-row q-tile). 256 threads.
// logits = (q.k * 1/sqrt(D)) masked, then * temp[b,h]; online softmax.
// Output written in [B,T,H*D] layout (ready for o-projection).
// ---------------------------------------------------------------------------
__global__ __launch_bounds__(256) void flash_attn(
    const float* __restrict__ q, const float* __restrict__ k,
    const float* __restrict__ v, const int* __restrict__ mask,
    const float* __restrict__ temp, float* __restrict__ out) {
    __shared__ float Qs[64][65];  // [d][row]   (transposed)
    __shared__ float Ks[64][65];  // [d][key]   (transposed)
    __shared__ float Vs[64][65];  // [key][d]
    __shared__ float Ps[64][65];  // [row][key] scores -> probs
    __shared__ float mrow[64], lrow[64], arow[64];
    int tid = threadIdx.x;
    int tx = tid & 15, ty = tid >> 4;
    int q0 = blockIdx.x * 64;
    int bh = blockIdx.y;
    int b = bh >> 4, h = bh & 15;
    float tscale = temp[bh] * 0.125f;  // temp * 1/sqrt(64)

#pragma unroll
    for (int i = 0; i < 16; ++i) {
        int idx = i * 256 + tid;
        int r = idx >> 6, c = idx & 63;
        Qs[c][r] = q[((size_t)(b * TT + q0 + r)) * CC + h * DD + c];
    }
    if (tid < 64) {
        mrow[tid] = -INFINITY;
        lrow[tid] = 0.f;
    }
    float acc[4][4] = {};
    __syncthreads();

    for (int kt = 0; kt < TT / 64; ++kt) {
        int kb = kt * 64;
#pragma unroll
        for (int i = 0; i < 16; ++i) {
            int idx = i * 256 + tid;
            int r = idx >> 6, c = idx & 63;
            Ks[c][r] = k[((size_t)(b * TT + kb + r)) * CC + h * DD + c];
            Vs[r][c] = v[((size_t)(b * TT + kb + r)) * CC + h * DD + c];
        }
        __syncthreads();
        // S = Q K^T  (4x4 microtile per thread)
        float s[4][4] = {};
        for (int d = 0; d < 64; ++d) {
            float qa[4], ka[4];
#pragma unroll
            for (int i = 0; i < 4; ++i) qa[i] = Qs[d][ty * 4 + i];
#pragma unroll
            for (int j = 0; j < 4; ++j) ka[j] = Ks[d][tx * 4 + j];
#pragma unroll
            for (int i = 0; i < 4; ++i)
#pragma unroll
                for (int j = 0; j < 4; ++j)
                    s[i][j] = fmaf(qa[i], ka[j], s[i][j]);
        }
#pragma unroll
        for (int i = 0; i < 4; ++i)
#pragma unroll
            for (int j = 0; j < 4; ++j) {
                int qg = q0 + ty * 4 + i, kg = kb + tx * 4 + j;
                int mk = mask[((size_t)(b * TT + qg)) * TT + kg];
                Ps[ty * 4 + i][tx * 4 + j] = mk ? s[i][j] * tscale : -INFINITY;
            }
        __syncthreads();
        // online softmax row update (first 64 threads, one row each)
        if (tid < 64) {
            float mold = mrow[tid];
            float rmax = mold;
            for (int c = 0; c < 64; ++c) rmax = fmaxf(rmax, Ps[tid][c]);
            float a = expf(mold - rmax);  // 0 on first tile (mold = -inf)
            float ssum = 0.f;
            for (int c = 0; c < 64; ++c) {
                float p = expf(Ps[tid][c] - rmax);
                Ps[tid][c] = p;
                ssum += p;
            }
            lrow[tid] = lrow[tid] * a + ssum;
            mrow[tid] = rmax;
            arow[tid] = a;
        }
        __syncthreads();
        // O = O*alpha + P @ V
#pragma unroll
        for (int i = 0; i < 4; ++i) {
            float al = arow[ty * 4 + i];
#pragma unroll
            for (int j = 0; j < 4; ++j) acc[i][j] *= al;
        }
        for (int kk = 0; kk < 64; ++kk) {
            float pv[4], vv[4];
#pragma unroll
            for (int i = 0; i < 4; ++i) pv[i] = Ps[ty * 4 + i][kk];
#pragma unroll
            for (int j = 0; j < 4; ++j) vv[j] = Vs[kk][tx * 4 + j];
#pragma unroll
            for (int i = 0; i < 4; ++i)
#pragma unroll
                for (int j = 0; j < 4; ++j)
                    acc[i][j] = fmaf(pv[i], vv[j], acc[i][j]);
        }
        __syncthreads();
    }
#pragma unroll
    for (int i = 0; i < 4; ++i) {
        int r = ty * 4 + i;
        float invl = 1.0f / lrow[r];
#pragma unroll
        for (int j = 0; j < 4; ++j)
            out[((size_t)(b * TT + q0 + r)) * CC + h * DD + tx * 4 + j] =
                acc[i][j] * invl;
    }
}

// ---------------------------------------------------------------------------
// Final: out = LN(x + proj) with norm_g/norm_b
// ---------------------------------------------------------------------------
__global__ __launch_bounds__(256) void final_ln(
    const float* __restrict__ x, const float* __restrict__ p,
    const float* __restrict__ g, const float* __restrict__ beta,
    float* __restrict__ out) {
    int row = blockIdx.x;
    int tid = threadIdx.x;
    const float* xr = x + (size_t)row * CC;
    const float* pr = p + (size_t)row * CC;
    float v[4];
    float s = 0.f;
#pragma unroll
    for (int i = 0; i < 4; ++i) {
        int c = i * 256 + tid;
        v[i] = xr[c] + pr[c];
        s += v[i];
    }
    __shared__ float red[256];
    red[tid] = s;
    __syncthreads();
#pragma unroll
    for (int o = 128; o > 0; o >>= 1) {
        if (tid < o) red[tid] += red[tid + o];
        __syncthreads();
    }
    float mean = red[0] * (1.0f / CC);
    __syncthreads();
    s = 0.f;
#pragma unroll
    for (int i = 0; i < 4; ++i) {
        float d = v[i] - mean;
        s += d * d;
    }
    red[tid] = s;
    __syncthreads();
#pragma unroll
    for (int o = 128; o > 0; o >>= 1) {
        if (tid < o) red[tid] += red[tid + o];
        __syncthreads();
    }
    float inv = rsqrtf(red[0] * (1.0f / CC) + 1e-5f);
#pragma unroll
    for (int i = 0; i < 4; ++i) {
        int c = i * 256 + tid;
        out[(size_t)row * CC + c] = (v[i] - mean) * inv * g[c] + beta[c];
    }
}

extern "C" void kernel_launch(void* const* d_in, const int* in_sizes, int n_in,
                              void* d_out, int out_size, void* d_ws,
                              size_t ws_size, hipStream_t stream) {
    const float* x        = (const float*)d_in[0];
    const int*   mask     = (const int*)d_in[1];
    const float* imp_w1   = (const float*)d_in[2];
    const float* imp_b1   = (const float*)d_in[3];
    const float* imp_g    = (const float*)d_in[4];
    const float* imp_beta = (const float*)d_in[5];
    const float* imp_w2   = (const float*)d_in[6];
    const float* imp_b2   = (const float*)d_in[7];
    const float* rsn_w1   = (const float*)d_in[8];
    const float* rsn_b1   = (const float*)d_in[9];
    const float* rsn_g    = (const float*)d_in[10];
    const float* rsn_beta = (const float*)d_in[11];
    const float* rsn_w2   = (const float*)d_in[12];
    const float* rsn_b2   = (const float*)d_in[13];
    const float* q_w      = (const float*)d_in[14];
    const float* q_b      = (const float*)d_in[15];
    const float* k_w      = (const float*)d_in[16];
    const float* k_b      = (const float*)d_in[17];
    const float* v_w      = (const float*)d_in[18];
    const float* v_b      = (const float*)d_in[19];
    const float* o_w      = (const float*)d_in[20];
    const float* o_b      = (const float*)d_in[21];
    const float* tmp_w1   = (const float*)d_in[22];
    const float* tmp_b1   = (const float*)d_in[23];
    const float* tmp_g    = (const float*)d_in[24];
    const float* tmp_beta = (const float*)d_in[25];
    const float* tmp_w2   = (const float*)d_in[26];
    const float* tmp_b2   = (const float*)d_in[27];
    const float* norm_g   = (const float*)d_in[28];
    const float* norm_b   = (const float*)d_in[29];
    float* out = (float*)d_out;
    float* ws  = (float*)d_ws;

    // workspace layout (floats)
    float* h1   = ws;                 // [4096,512]
    float* xi   = ws + 2097152;       // [4096,1024]
    float* h2   = ws + 6291456;       // [4096,1024]  (later: o-proj)
    float* rs   = ws + 10485760;      // reasoned     (later: attn_out)
    float* qb   = ws + 14680064;      // q
    float* kb   = ws + 18874368;      // k
    float* vb   = ws + 23068672;      // v
    float* rm   = ws + 27262976;      // [2,1024]
    float* tmp  = ws + 27265024;      // [2,16]
    float* part = ws + 27266048;      // [2,16,1024]

    dim3 blk(256);
    // importance net
    gemm_bias<<<dim3(CHALF / 64, NN / 64), blk, 0, stream>>>(x, imp_w1, imp_b1, h1, NN, CHALF, CC);
    ln_gelu_kernel<CHALF><<<NN, blk, 0, stream>>>(h1, imp_g, imp_beta);
    imp_scale<<<NN, blk, 0, stream>>>(h1, imp_w2, imp_b2, x, xi);
    // reasoning net
    gemm_bias<<<dim3(CC / 64, NN / 64), blk, 0, stream>>>(xi, rsn_w1, rsn_b1, h2, NN, CC, CC);
    ln_gelu_kernel<CC><<<NN, blk, 0, stream>>>(h2, rsn_g, rsn_beta);
    gemm_bias<<<dim3(CC / 64, NN / 64), blk, 0, stream>>>(h2, rsn_w2, rsn_b2, rs, NN, CC, CC);
    // q projection (from reasoned) + temperature net (from reasoned mean)
    gemm_bias<<<dim3(CC / 64, NN / 64), blk, 0, stream>>>(rs, q_w, q_b, qb, NN, CC, CC);
    mean_part<<<128, blk, 0, stream>>>(rs, part);
    mean_fin<<<8, blk, 0, stream>>>(part, rm);
    temp_net<<<BB, dim3(512), 0, stream>>>(rm, tmp_w1, tmp_b1, tmp_g, tmp_beta, tmp_w2, tmp_b2, tmp);
    // k, v projections
    gemm_bias<<<dim3(CC / 64, NN / 64), blk, 0, stream>>>(xi, k_w, k_b, kb, NN, CC, CC);
    gemm_bias<<<dim3(CC / 64, NN / 64), blk, 0, stream>>>(x, v_w, v_b, vb, NN, CC, CC);
    // attention (writes into rs, which is free now)
    flash_attn<<<dim3(TT / 64, BB * HH), blk, 0, stream>>>(qb, kb, vb, mask, tmp, rs);
    // output projection (into h2, free now) + residual LN
    gemm_bias<<<dim3(CC / 64, NN / 64), blk, 0, stream>>>(rs, o_w, o_b, h2, NN, CC, CC);
    final_ln<<<NN, blk, 0, stream>>>(x, h2, norm_g, norm_b, out);
}

// Round 2
// 1234.979 us; speedup vs baseline: 1.5331x; 1.5331x over previous
//
#include <hip/hip_runtime.h>
#include <hip/hip_bf16.h>
#include <math.h>

// Problem constants
#define BB 2
#define TT 2048
#define CC 1024
#define HH 16
#define DD 64
#define CHALF 512
#define NN (BB * TT)   // 4096 rows

typedef __attribute__((ext_vector_type(8))) short short8;
typedef __attribute__((ext_vector_type(4))) float f32x4;

__device__ __forceinline__ float gelu_exact(float x) {
    return 0.5f * x * (1.0f + erff(x * 0.70710678118654752f));
}

__device__ __forceinline__ short f2bf(float f) {
    __hip_bfloat16 h = __float2bfloat16(f);
    short s;
    __builtin_memcpy(&s, &h, 2);
    return s;
}

// ---------------------------------------------------------------------------
// Tiled fp32 GEMM: C[M,N] = A[M,K] @ W[K,N] + bias[N]  (fp32 out)
// ---------------------------------------------------------------------------
__global__ __launch_bounds__(256) void gemm_bias(
    const float* __restrict__ A, const float* __restrict__ W,
    const float* __restrict__ bias, float* __restrict__ C,
    int M, int N, int K) {
    __shared__ float As[16][64];
    __shared__ float Ws[16][64];
    int tid = threadIdx.x;
    int tx = tid & 15, ty = tid >> 4;
    int row0 = blockIdx.y * 64;
    int col0 = blockIdx.x * 64;
    int lar = tid >> 2;
    int lak = (tid & 3) * 4;
    int lwk = tid >> 4;
    int lwc = (tid & 15) * 4;
    float acc[4][4] = {};
    for (int k0 = 0; k0 < K; k0 += 16) {
        float4 av = *(const float4*)&A[(size_t)(row0 + lar) * K + k0 + lak];
        As[lak + 0][lar] = av.x;
        As[lak + 1][lar] = av.y;
        As[lak + 2][lar] = av.z;
        As[lak + 3][lar] = av.w;
        float4 wv = *(const float4*)&W[(size_t)(k0 + lwk) * N + col0 + lwc];
        *(float4*)&Ws[lwk][lwc] = wv;
        __syncthreads();
#pragma unroll
        for (int kk = 0; kk < 16; ++kk) {
            float4 a = *(const float4*)&As[kk][ty * 4];
            float4 bvec = *(const float4*)&Ws[kk][tx * 4];
            float ar[4] = {a.x, a.y, a.z, a.w};
            float br[4] = {bvec.x, bvec.y, bvec.z, bvec.w};
#pragma unroll
            for (int i = 0; i < 4; ++i)
#pragma unroll
                for (int j = 0; j < 4; ++j)
                    acc[i][j] = fmaf(ar[i], br[j], acc[i][j]);
        }
        __syncthreads();
    }
#pragma unroll
    for (int i = 0; i < 4; ++i) {
        int r = row0 + ty * 4 + i;
#pragma unroll
        for (int j = 0; j < 4; ++j) {
            int c = col0 + tx * 4 + j;
            C[(size_t)r * N + c] = acc[i][j] + bias[c];
        }
    }
}

// Same GEMM, bf16 output (for q/k/v projections feeding MFMA attention)
__global__ __launch_bounds__(256) void gemm_bias_bf16(
    const float* __restrict__ A, const float* __restrict__ W,
    const float* __restrict__ bias, __hip_bfloat16* __restrict__ C,
    int M, int N, int K) {
    __shared__ float As[16][64];
    __shared__ float Ws[16][64];
    int tid = threadIdx.x;
    int tx = tid & 15, ty = tid >> 4;
    int row0 = blockIdx.y * 64;
    int col0 = blockIdx.x * 64;
    int lar = tid >> 2;
    int lak = (tid & 3) * 4;
    int lwk = tid >> 4;
    int lwc = (tid & 15) * 4;
    float acc[4][4] = {};
    for (int k0 = 0; k0 < K; k0 += 16) {
        float4 av = *(const float4*)&A[(size_t)(row0 + lar) * K + k0 + lak];
        As[lak + 0][lar] = av.x;
        As[lak + 1][lar] = av.y;
        As[lak + 2][lar] = av.z;
        As[lak + 3][lar] = av.w;
        float4 wv = *(const float4*)&W[(size_t)(k0 + lwk) * N + col0 + lwc];
        *(float4*)&Ws[lwk][lwc] = wv;
        __syncthreads();
#pragma unroll
        for (int kk = 0; kk < 16; ++kk) {
            float4 a = *(const float4*)&As[kk][ty * 4];
            float4 bvec = *(const float4*)&Ws[kk][tx * 4];
            float ar[4] = {a.x, a.y, a.z, a.w};
            float br[4] = {bvec.x, bvec.y, bvec.z, bvec.w};
#pragma unroll
            for (int i = 0; i < 4; ++i)
#pragma unroll
                for (int j = 0; j < 4; ++j)
                    acc[i][j] = fmaf(ar[i], br[j], acc[i][j]);
        }
        __syncthreads();
    }
#pragma unroll
    for (int i = 0; i < 4; ++i) {
        int r = row0 + ty * 4 + i;
#pragma unroll
        for (int j = 0; j < 4; ++j) {
            int c = col0 + tx * 4 + j;
            C[(size_t)r * N + c] = __float2bfloat16(acc[i][j] + bias[c]);
        }
    }
}

// ---------------------------------------------------------------------------
// Row-wise LayerNorm + exact GELU, in place.
// ---------------------------------------------------------------------------
template <int WIDTH>
__global__ __launch_bounds__(256) void ln_gelu_kernel(
    float* __restrict__ Y, const float* __restrict__ g,
    const float* __restrict__ beta) {
    constexpr int PT = WIDTH / 256;
    int row = blockIdx.x;
    int tid = threadIdx.x;
    float* yr = Y + (size_t)row * WIDTH;
    float v[PT];
    float s = 0.f;
#pragma unroll
    for (int i = 0; i < PT; ++i) {
        v[i] = yr[i * 256 + tid];
        s += v[i];
    }
    __shared__ float red[256];
    red[tid] = s;
    __syncthreads();
#pragma unroll
    for (int o = 128; o > 0; o >>= 1) {
        if (tid < o) red[tid] += red[tid + o];
        __syncthreads();
    }
    float mean = red[0] * (1.0f / WIDTH);
    __syncthreads();
    s = 0.f;
#pragma unroll
    for (int i = 0; i < PT; ++i) {
        float d = v[i] - mean;
        s += d * d;
    }
    red[tid] = s;
    __syncthreads();
#pragma unroll
    for (int o = 128; o > 0; o >>= 1) {
        if (tid < o) red[tid] += red[tid + o];
        __syncthreads();
    }
    float inv = rsqrtf(red[0] * (1.0f / WIDTH) + 1e-5f);
#pragma unroll
    for (int i = 0; i < PT; ++i) {
        int c = i * 256 + tid;
        yr[c] = gelu_exact((v[i] - mean) * inv * g[c] + beta[c]);
    }
}

// ---------------------------------------------------------------------------
// importance gate
// ---------------------------------------------------------------------------
__global__ __launch_bounds__(256) void imp_scale(
    const float* __restrict__ h1, const float* __restrict__ w2,
    const float* __restrict__ b2, const float* __restrict__ x,
    float* __restrict__ xi) {
    int row = blockIdx.x;
    int tid = threadIdx.x;
    const float* hr = h1 + (size_t)row * CHALF;
    float s = hr[tid] * w2[tid] + hr[tid + 256] * w2[tid + 256];
    __shared__ float red[256];
    red[tid] = s;
    __syncthreads();
#pragma unroll
    for (int o = 128; o > 0; o >>= 1) {
        if (tid < o) red[tid] += red[tid + o];
        __syncthreads();
    }
    float z = red[0] + b2[0];
    float sg = 1.0f / (1.0f + expf(-z));
    float imp = fmaxf(sg, 1e-6f);
#pragma unroll
    for (int i = 0; i < 4; ++i) {
        int c = i * 256 + tid;
        xi[(size_t)row * CC + c] = x[(size_t)row * CC + c] * imp;
    }
}

// ---------------------------------------------------------------------------
// reasoned.mean(axis=1)
// ---------------------------------------------------------------------------
__global__ __launch_bounds__(256) void mean_part(
    const float* __restrict__ R, float* __restrict__ part) {
    int idx = blockIdx.x * 256 + threadIdx.x;
    int c = idx & (CC - 1);
    int chunk = (idx >> 10) & 15;
    int b = idx >> 14;
    const float* base = R + ((size_t)(b * TT + chunk * 128)) * CC + c;
    float s = 0.f;
    for (int t = 0; t < 128; ++t) s += base[(size_t)t * CC];
    part[idx] = s;
}

__global__ __launch_bounds__(256) void mean_fin(
    const float* __restrict__ part, float* __restrict__ rm) {
    int idx = blockIdx.x * 256 + threadIdx.x;
    int c = idx & (CC - 1);
    int b = idx >> 10;
    float s = 0.f;
#pragma unroll
    for (int ch = 0; ch < 16; ++ch) s += part[(size_t)(b * 16 + ch) * CC + c];
    rm[idx] = s * (1.0f / TT);
}

// ---------------------------------------------------------------------------
// temp_net
// ---------------------------------------------------------------------------
__global__ __launch_bounds__(512) void temp_net(
    const float* __restrict__ rm, const float* __restrict__ w1,
    const float* __restrict__ b1, const float* __restrict__ g,
    const float* __restrict__ beta, const float* __restrict__ w2,
    const float* __restrict__ b2, float* __restrict__ temp) {
    __shared__ float xr[CC];
    __shared__ float ht[CHALF];
    __shared__ float red[512];
    int b = blockIdx.x;
    int tid = threadIdx.x;
    xr[tid] = rm[b * CC + tid];
    xr[tid + 512] = rm[b * CC + tid + 512];
    __syncthreads();
    float acc = b1[tid];
#pragma unroll 8
    for (int i = 0; i < CC; ++i) acc = fmaf(xr[i], w1[(size_t)i * CHALF + tid], acc);
    red[tid] = acc;
    __syncthreads();
#pragma unroll
    for (int o = 256; o > 0; o >>= 1) {
        if (tid < o) red[tid] += red[tid + o];
        __syncthreads();
    }
    float mean = red[0] * (1.0f / CHALF);
    __syncthreads();
    float d = acc - mean;
    red[tid] = d * d;
    __syncthreads();
#pragma unroll
    for (int o = 256; o > 0; o >>= 1) {
        if (tid < o) red[tid] += red[tid + o];
        __syncthreads();
    }
    float inv = rsqrtf(red[0] * (1.0f / CHALF) + 1e-5f);
    ht[tid] = gelu_exact((acc - mean) * inv * g[tid] + beta[tid]);
    __syncthreads();
    if (tid < HH) {
        float s = b2[tid];
        for (int i = 0; i < CHALF; ++i) s = fmaf(ht[i], w2[i * HH + tid], s);
        float sp = fmaxf(s, 0.f) + log1pf(expf(-fabsf(s)));
        temp[b * HH + tid] = sp + 0.5f;
    }
}

// ---------------------------------------------------------------------------
// mask tile flags: 1 if the 64x64 tile (b, qt, kt) is all nonzero
// ---------------------------------------------------------------------------
__global__ __launch_bounds__(256) void mask_flags(
    const int* __restrict__ mask, int* __restrict__ flags) {
    int kt = blockIdx.x, qt = blockIdx.y, b = blockIdx.z;
    int tid = threadIdx.x;
    int r = tid >> 2;
    int c0 = (tid & 3) * 16;
    const int* base = mask + ((size_t)(b * TT + qt * 64 + r)) * TT + kt * 64 + c0;
    int all = 1;
#pragma unroll
    for (int i = 0; i < 4; ++i) {
        int4 m4 = *(const int4*)(base + i * 4);
        all &= (m4.x != 0) & (m4.y != 0) & (m4.z != 0) & (m4.w != 0);
    }
    __shared__ int red[256];
    red[tid] = all;
    __syncthreads();
#pragma unroll
    for (int o = 128; o > 0; o >>= 1) {
        if (tid < o) red[tid] &= red[tid + o];
        __syncthreads();
    }
    if (tid == 0) flags[(b * 32 + qt) * 32 + kt] = red[0];
}

// ---------------------------------------------------------------------------
// MFMA flash attention (bf16 inputs, fp32 softmax/accum).
// Block: 256 threads = 4 waves; one (b,h,64-row q-tile) per block.
// Wave w owns q-rows [q0+w*16, q0+w*16+16).
// Layouts (16x16x32 bf16 MFMA):
//   A[m][k]: m=lane&15, k=quad*8+j   B[k][n]: n=lane&15, k=quad*8+j
//   C/D:     row=quad*4+reg, col=lane&15
// ---------------------------------------------------------------------------
__global__ __launch_bounds__(256) void flash_attn_mfma(
    const short* __restrict__ q, const short* __restrict__ k,
    const short* __restrict__ v, const int* __restrict__ mask,
    const int* __restrict__ flags, const float* __restrict__ temp,
    float* __restrict__ out) {
    // 72-element row stride: rows 144B (16B-aligned), 2-way bank alias (free)
    __shared__ short Ks[64][72];   // [key][d]
    __shared__ short Vt[64][72];   // [d][key]   (transposed)
    __shared__ short Ps[64][72];   // [q-row][key], wave-private 16-row strips
    int tid = threadIdx.x;
    int wave = tid >> 6;
    int lane = tid & 63;
    int m16 = lane & 15;
    int quad = lane >> 4;
    int qt = blockIdx.x;
    int q0 = qt * 64;
    int bh = blockIdx.y;
    int b = bh >> 4, h = bh & 15;
    float tscale = temp[bh] * 0.125f;  // temp * 1/sqrt(64)

    // Q fragments (held in registers for the whole kernel)
    const short* qrow =
        q + ((size_t)(b * TT + q0 + wave * 16 + m16)) * CC + h * DD + quad * 8;
    short8 qf0 = *(const short8*)(qrow);
    short8 qf1 = *(const short8*)(qrow + 32);

    float m_run[4], l_run[4];
    f32x4 acc_o[4];
#pragma unroll
    for (int r = 0; r < 4; ++r) {
        m_run[r] = -INFINITY;
        l_run[r] = 0.f;
    }
#pragma unroll
    for (int t = 0; t < 4; ++t) acc_o[t] = (f32x4){0.f, 0.f, 0.f, 0.f};

    for (int kt = 0; kt < TT / 64; ++kt) {
        int kb = kt * 64;
        // stage K (row-major) and V (transposed) into LDS
#pragma unroll
        for (int i = 0; i < 2; ++i) {
            int idx = i * 256 + tid;       // 0..511
            int r = idx >> 3;              // key row 0..63
            int dc = (idx & 7) * 8;        // d chunk
            const short* kg = k + ((size_t)(b * TT + kb + r)) * CC + h * DD + dc;
            *(short8*)&Ks[r][dc] = *(const short8*)kg;
            const short* vg = v + ((size_t)(b * TT + kb + r)) * CC + h * DD + dc;
            short8 vv = *(const short8*)vg;
#pragma unroll
            for (int u = 0; u < 8; ++u) Vt[dc + u][r] = vv[u];
        }
        __syncthreads();

        // S = Q K^T for this wave's 16 rows x 64 keys
        f32x4 sacc[4];
#pragma unroll
        for (int t = 0; t < 4; ++t) sacc[t] = (f32x4){0.f, 0.f, 0.f, 0.f};
#pragma unroll
        for (int t = 0; t < 4; ++t) {
            short8 kf0 = *(const short8*)&Ks[t * 16 + m16][quad * 8];
            sacc[t] = __builtin_amdgcn_mfma_f32_16x16x32_bf16(qf0, kf0, sacc[t], 0, 0, 0);
            short8 kf1 = *(const short8*)&Ks[t * 16 + m16][32 + quad * 8];
            sacc[t] = __builtin_amdgcn_mfma_f32_16x16x32_bf16(qf1, kf1, sacc[t], 0, 0, 0);
        }

        // scale + (rare) mask
        float sv[4][4];
#pragma unroll
        for (int t = 0; t < 4; ++t)
#pragma unroll
            for (int r = 0; r < 4; ++r) sv[t][r] = sacc[t][r] * tscale;
        if (flags[(b * 32 + qt) * 32 + kt] == 0) {
#pragma unroll
            for (int t = 0; t < 4; ++t)
#pragma unroll
                for (int r = 0; r < 4; ++r) {
                    int qg = q0 + wave * 16 + quad * 4 + r;
                    int kg = kb + t * 16 + m16;
                    if (mask[((size_t)(b * TT + qg)) * TT + kg] == 0)
                        sv[t][r] = -INFINITY;
                }
        }

        // online softmax (per row; rows live in quad groups, reduce over 16 lanes)
        float rmax[4], rsum[4], alpha[4];
#pragma unroll
        for (int r = 0; r < 4; ++r) {
            float mx = fmaxf(fmaxf(sv[0][r], sv[1][r]), fmaxf(sv[2][r], sv[3][r]));
#pragma unroll
            for (int off = 1; off < 16; off <<= 1)
                mx = fmaxf(mx, __shfl_xor(mx, off, 64));
            float mnew = fmaxf(m_run[r], mx);
            alpha[r] = __expf(m_run[r] - mnew);
            m_run[r] = mnew;
            rmax[r] = mnew;
            rsum[r] = 0.f;
        }
#pragma unroll
        for (int t = 0; t < 4; ++t)
#pragma unroll
            for (int r = 0; r < 4; ++r) {
                float p = __expf(sv[t][r] - rmax[r]);
                rsum[r] += p;
                Ps[wave * 16 + quad * 4 + r][t * 16 + m16] = f2bf(p);
            }
#pragma unroll
        for (int r = 0; r < 4; ++r) {
#pragma unroll
            for (int off = 1; off < 16; off <<= 1)
                rsum[r] += __shfl_xor(rsum[r], off, 64);
            l_run[r] = l_run[r] * alpha[r] + rsum[r];
#pragma unroll
            for (int t = 0; t < 4; ++t) acc_o[t][r] *= alpha[r];
        }
        __syncthreads();

        // O += P @ V
        short8 pf0 = *(const short8*)&Ps[wave * 16 + m16][quad * 8];
        short8 pf1 = *(const short8*)&Ps[wave * 16 + m16][32 + quad * 8];
#pragma unroll
        for (int t = 0; t < 4; ++t) {
            short8 vf0 = *(const short8*)&Vt[t * 16 + m16][quad * 8];
            acc_o[t] = __builtin_amdgcn_mfma_f32_16x16x32_bf16(pf0, vf0, acc_o[t], 0, 0, 0);
            short8 vf1 = *(const short8*)&Vt[t * 16 + m16][32 + quad * 8];
            acc_o[t] = __builtin_amdgcn_mfma_f32_16x16x32_bf16(pf1, vf1, acc_o[t], 0, 0, 0);
        }
        __syncthreads();
    }

    // epilogue: O / l, write [B,T,C] fp32
#pragma unroll
    for (int r = 0; r < 4; ++r) {
        float inv = 1.0f / l_run[r];
        int row = b * TT + q0 + wave * 16 + quad * 4 + r;
#pragma unroll
        for (int t = 0; t < 4; ++t)
            out[(size_t)row * CC + h * DD + t * 16 + m16] = acc_o[t][r] * inv;
    }
}

// ---------------------------------------------------------------------------
// Final: out = LN(x + proj)
// ---------------------------------------------------------------------------
__global__ __launch_bounds__(256) void final_ln(
    const float* __restrict__ x, const float* __restrict__ p,
    const float* __restrict__ g, const float* __restrict__ beta,
    float* __restrict__ out) {
    int row = blockIdx.x;
    int tid = threadIdx.x;
    const float* xr = x + (size_t)row * CC;
    const float* pr = p + (size_t)row * CC;
    float v[4];
    float s = 0.f;
#pragma unroll
    for (int i = 0; i < 4; ++i) {
        int c = i * 256 + tid;
        v[i] = xr[c] + pr[c];
        s += v[i];
    }
    __shared__ float red[256];
    red[tid] = s;
    __syncthreads();
#pragma unroll
    for (int o = 128; o > 0; o >>= 1) {
        if (tid < o) red[tid] += red[tid + o];
        __syncthreads();
    }
    float mean = red[0] * (1.0f / CC);
    __syncthreads();
    s = 0.f;
#pragma unroll
    for (int i = 0; i < 4; ++i) {
        float d = v[i] - mean;
        s += d * d;
    }
    red[tid] = s;
    __syncthreads();
#pragma unroll
    for (int o = 128; o > 0; o >>= 1) {
        if (tid < o) red[tid] += red[tid + o];
        __syncthreads();
    }
    float inv = rsqrtf(red[0] * (1.0f / CC) + 1e-5f);
#pragma unroll
    for (int i = 0; i < 4; ++i) {
        int c = i * 256 + tid;
        out[(size_t)row * CC + c] = (v[i] - mean) * inv * g[c] + beta[c];
    }
}

extern "C" void kernel_launch(void* const* d_in, const int* in_sizes, int n_in,
                              void* d_out, int out_size, void* d_ws,
                              size_t ws_size, hipStream_t stream) {
    const float* x        = (const float*)d_in[0];
    const int*   mask     = (const int*)d_in[1];
    const float* imp_w1   = (const float*)d_in[2];
    const float* imp_b1   = (const float*)d_in[3];
    const float* imp_g    = (const float*)d_in[4];
    const float* imp_beta = (const float*)d_in[5];
    const float* imp_w2   = (const float*)d_in[6];
    const float* imp_b2   = (const float*)d_in[7];
    const float* rsn_w1   = (const float*)d_in[8];
    const float* rsn_b1   = (const float*)d_in[9];
    const float* rsn_g    = (const float*)d_in[10];
    const float* rsn_beta = (const float*)d_in[11];
    const float* rsn_w2   = (const float*)d_in[12];
    const float* rsn_b2   = (const float*)d_in[13];
    const float* q_w      = (const float*)d_in[14];
    const float* q_b      = (const float*)d_in[15];
    const float* k_w      = (const float*)d_in[16];
    const float* k_b      = (const float*)d_in[17];
    const float* v_w      = (const float*)d_in[18];
    const float* v_b      = (const float*)d_in[19];
    const float* o_w      = (const float*)d_in[20];
    const float* o_b      = (const float*)d_in[21];
    const float* tmp_w1   = (const float*)d_in[22];
    const float* tmp_b1   = (const float*)d_in[23];
    const float* tmp_g    = (const float*)d_in[24];
    const float* tmp_beta = (const float*)d_in[25];
    const float* tmp_w2   = (const float*)d_in[26];
    const float* tmp_b2   = (const float*)d_in[27];
    const float* norm_g   = (const float*)d_in[28];
    const float* norm_b   = (const float*)d_in[29];
    float* out = (float*)d_out;
    float* ws  = (float*)d_ws;

    // workspace layout (float offsets)
    float* h1   = ws;                 // [4096,512]
    float* xi   = ws + 2097152;       // [4096,1024]
    float* h2   = ws + 6291456;       // [4096,1024]  (later: o-proj)
    float* rs   = ws + 10485760;      // reasoned     (later: attn_out)
    __hip_bfloat16* qb = (__hip_bfloat16*)(ws + 14680064);  // q bf16
    __hip_bfloat16* kb = (__hip_bfloat16*)(ws + 18874368);  // k bf16
    __hip_bfloat16* vb = (__hip_bfloat16*)(ws + 23068672);  // v bf16
    float* rm   = ws + 27262976;      // [2,1024]
    float* tmp  = ws + 27265024;      // [2,16]
    float* part = ws + 27266048;      // [2,16,1024]
    int*   flg  = (int*)(ws + 27282432);  // [2,32,32] mask tile flags

    dim3 blk(256);
    // importance net
    gemm_bias<<<dim3(CHALF / 64, NN / 64), blk, 0, stream>>>(x, imp_w1, imp_b1, h1, NN, CHALF, CC);
    ln_gelu_kernel<CHALF><<<NN, blk, 0, stream>>>(h1, imp_g, imp_beta);
    imp_scale<<<NN, blk, 0, stream>>>(h1, imp_w2, imp_b2, x, xi);
    // reasoning net
    gemm_bias<<<dim3(CC / 64, NN / 64), blk, 0, stream>>>(xi, rsn_w1, rsn_b1, h2, NN, CC, CC);
    ln_gelu_kernel<CC><<<NN, blk, 0, stream>>>(h2, rsn_g, rsn_beta);
    gemm_bias<<<dim3(CC / 64, NN / 64), blk, 0, stream>>>(h2, rsn_w2, rsn_b2, rs, NN, CC, CC);
    // mask tile flags (independent of everything else)
    mask_flags<<<dim3(32, 32, 2), blk, 0, stream>>>(mask, flg);
    // q projection (bf16 out) + temperature net
    gemm_bias_bf16<<<dim3(CC / 64, NN / 64), blk, 0, stream>>>(rs, q_w, q_b, qb, NN, CC, CC);
    mean_part<<<128, blk, 0, stream>>>(rs, part);
    mean_fin<<<8, blk, 0, stream>>>(part, rm);
    temp_net<<<BB, dim3(512), 0, stream>>>(rm, tmp_w1, tmp_b1, tmp_g, tmp_beta, tmp_w2, tmp_b2, tmp);
    // k, v projections (bf16 out)
    gemm_bias_bf16<<<dim3(CC / 64, NN / 64), blk, 0, stream>>>(xi, k_w, k_b, kb, NN, CC, CC);
    gemm_bias_bf16<<<dim3(CC / 64, NN / 64), blk, 0, stream>>>(x, v_w, v_b, vb, NN, CC, CC);
    // MFMA flash attention (writes fp32 into rs, free now)
    flash_attn_mfma<<<dim3(TT / 64, BB * HH), blk, 0, stream>>>(
        (const short*)qb, (const short*)kb, (const short*)vb, mask, flg, tmp, rs);
    // output projection + residual LN
    gemm_bias<<<dim3(CC / 64, NN / 64), blk, 0, stream>>>(rs, o_w, o_b, h2, NN, CC, CC);
    final_ln<<<NN, blk, 0, stream>>>(x, h2, norm_g, norm_b, out);
}

// Round 3
// 638.407 us; speedup vs baseline: 2.9657x; 1.9345x over previous
//
#include <hip/hip_runtime.h>
#include <hip/hip_bf16.h>
#include <math.h>

// Problem constants
#define BB 2
#define TT 2048
#define CC 1024
#define HH 16
#define DD 64
#define CHALF 512
#define NN (BB * TT)   // 4096 rows

typedef __attribute__((ext_vector_type(8))) short short8;
typedef __attribute__((ext_vector_type(4))) float f32x4;

__device__ __forceinline__ float gelu_exact(float x) {
    return 0.5f * x * (1.0f + erff(x * 0.70710678118654752f));
}

__device__ __forceinline__ short f2bf(float f) {
    __hip_bfloat16 h = __float2bfloat16(f);
    short s;
    __builtin_memcpy(&s, &h, 2);
    return s;
}

// async global->LDS, 16 B per lane; LDS dst must be wave-uniform base
__device__ __forceinline__ void async_copy16(const void* g, void* l) {
    __builtin_amdgcn_global_load_lds(
        (const __attribute__((address_space(1))) void*)g,
        (__attribute__((address_space(3))) void*)l, 16, 0, 0);
}

// ---------------------------------------------------------------------------
// fp32 -> bf16 elementwise convert (x)
// ---------------------------------------------------------------------------
__global__ __launch_bounds__(256) void conv_bf16(
    const float* __restrict__ X, __hip_bfloat16* __restrict__ O) {
    int i = (blockIdx.x * 256 + threadIdx.x) * 8;
    float4 a = *(const float4*)&X[i];
    float4 b = *(const float4*)&X[i + 4];
    __hip_bfloat16 o[8] = {
        __float2bfloat16(a.x), __float2bfloat16(a.y),
        __float2bfloat16(a.z), __float2bfloat16(a.w),
        __float2bfloat16(b.x), __float2bfloat16(b.y),
        __float2bfloat16(b.z), __float2bfloat16(b.w)};
    *(float4*)&O[i] = *(float4*)o;
}

// ---------------------------------------------------------------------------
// W [K,N] fp32 -> Wt [N,K] bf16 (transpose for MFMA B-operand layout)
// 64x64 LDS tile, both sides coalesced, conflict-free (+1 pad)
// ---------------------------------------------------------------------------
__global__ __launch_bounds__(256) void conv_transpose_bf16(
    const float* __restrict__ W, __hip_bfloat16* __restrict__ Wt,
    int K, int N) {
    __shared__ float T[64][65];
    int n0 = blockIdx.x * 64, k0 = blockIdx.y * 64;
    int tid = threadIdx.x;
    int c = tid & 63, r4 = tid >> 6;
#pragma unroll
    for (int i = 0; i < 16; ++i) {
        int row = i * 4 + r4;
        T[row][c] = W[(size_t)(k0 + row) * N + n0 + c];
    }
    __syncthreads();
#pragma unroll
    for (int i = 0; i < 16; ++i) {
        int row = i * 4 + r4;  // n index
        Wt[(size_t)(n0 + row) * K + k0 + c] = __float2bfloat16(T[c][row]);
    }
}

// ---------------------------------------------------------------------------
// bf16 MFMA GEMM: C[M,N] = A[M,K](bf16) @ Wt[N,K](bf16)^T + bias
// m97 structure: 128x128 tile, 256 thr = 4 waves of 64x64, BK=32,
// global_load_lds 16B staging, 16 mfma_16x16x32_bf16 per wave per k-step.
// ---------------------------------------------------------------------------
template <bool BF16OUT>
__global__ __launch_bounds__(256) void gemm_mfma(
    const short* __restrict__ A, const short* __restrict__ Wt,
    const float* __restrict__ bias, float* __restrict__ Cf,
    __hip_bfloat16* __restrict__ Cb, int M, int N, int K) {
    __shared__ short As[128][32];
    __shared__ short Bs[128][32];
    int tid = threadIdx.x;
    int wave = tid >> 6, lane = tid & 63;
    int m16 = lane & 15, quad = lane >> 4;
    int wm = wave >> 1, wn = wave & 1;
    int row0 = blockIdx.y * 128, col0 = blockIdx.x * 128;
    int lr = lane >> 2;        // 0..15 row-within-16
    int kof = (lane & 3) * 8;  // k chunk

    f32x4 acc[4][4];
#pragma unroll
    for (int i = 0; i < 4; ++i)
#pragma unroll
        for (int j = 0; j < 4; ++j) acc[i][j] = (f32x4){0.f, 0.f, 0.f, 0.f};

    for (int k0 = 0; k0 < K; k0 += 32) {
#pragma unroll
        for (int j = 0; j < 2; ++j) {
            int rbase = wave * 32 + j * 16;
            async_copy16(A + (size_t)(row0 + rbase + lr) * K + k0 + kof,
                         &As[rbase][0]);
            async_copy16(Wt + (size_t)(col0 + rbase + lr) * K + k0 + kof,
                         &Bs[rbase][0]);
        }
        __syncthreads();
        short8 af[4], bfr[4];
#pragma unroll
        for (int i = 0; i < 4; ++i)
            af[i] = *(const short8*)&As[wm * 64 + i * 16 + m16][quad * 8];
#pragma unroll
        for (int j = 0; j < 4; ++j)
            bfr[j] = *(const short8*)&Bs[wn * 64 + j * 16 + m16][quad * 8];
#pragma unroll
        for (int i = 0; i < 4; ++i)
#pragma unroll
            for (int j = 0; j < 4; ++j)
                acc[i][j] = __builtin_amdgcn_mfma_f32_16x16x32_bf16(
                    af[i], bfr[j], acc[i][j], 0, 0, 0);
        __syncthreads();
    }
#pragma unroll
    for (int i = 0; i < 4; ++i) {
#pragma unroll
        for (int j = 0; j < 4; ++j) {
            int col = col0 + wn * 64 + j * 16 + m16;
            float bv = bias[col];
#pragma unroll
            for (int rr = 0; rr < 4; ++rr) {
                int row = row0 + wm * 64 + i * 16 + quad * 4 + rr;
                float val = acc[i][j][rr] + bv;
                if (BF16OUT)
                    Cb[(size_t)row * N + col] = __float2bfloat16(val);
                else
                    Cf[(size_t)row * N + col] = val;
            }
        }
    }
}

// ---------------------------------------------------------------------------
// Row-wise LayerNorm + exact GELU, in place (fp32, for h1)
// ---------------------------------------------------------------------------
template <int WIDTH>
__global__ __launch_bounds__(256) void ln_gelu_kernel(
    float* __restrict__ Y, const float* __restrict__ g,
    const float* __restrict__ beta) {
    constexpr int PT = WIDTH / 256;
    int row = blockIdx.x;
    int tid = threadIdx.x;
    float* yr = Y + (size_t)row * WIDTH;
    float v[PT];
    float s = 0.f;
#pragma unroll
    for (int i = 0; i < PT; ++i) {
        v[i] = yr[i * 256 + tid];
        s += v[i];
    }
    __shared__ float red[256];
    red[tid] = s;
    __syncthreads();
#pragma unroll
    for (int o = 128; o > 0; o >>= 1) {
        if (tid < o) red[tid] += red[tid + o];
        __syncthreads();
    }
    float mean = red[0] * (1.0f / WIDTH);
    __syncthreads();
    s = 0.f;
#pragma unroll
    for (int i = 0; i < PT; ++i) {
        float d = v[i] - mean;
        s += d * d;
    }
    red[tid] = s;
    __syncthreads();
#pragma unroll
    for (int o = 128; o > 0; o >>= 1) {
        if (tid < o) red[tid] += red[tid + o];
        __syncthreads();
    }
    float inv = rsqrtf(red[0] * (1.0f / WIDTH) + 1e-5f);
#pragma unroll
    for (int i = 0; i < PT; ++i) {
        int c = i * 256 + tid;
        yr[c] = gelu_exact((v[i] - mean) * inv * g[c] + beta[c]);
    }
}

// Same, but reads fp32 and writes bf16 out-of-place (for h2 -> h2b)
template <int WIDTH>
__global__ __launch_bounds__(256) void ln_gelu_bf16(
    const float* __restrict__ Y, const float* __restrict__ g,
    const float* __restrict__ beta, __hip_bfloat16* __restrict__ O) {
    constexpr int PT = WIDTH / 256;
    int row = blockIdx.x;
    int tid = threadIdx.x;
    const float* yr = Y + (size_t)row * WIDTH;
    float v[PT];
    float s = 0.f;
#pragma unroll
    for (int i = 0; i < PT; ++i) {
        v[i] = yr[i * 256 + tid];
        s += v[i];
    }
    __shared__ float red[256];
    red[tid] = s;
    __syncthreads();
#pragma unroll
    for (int o = 128; o > 0; o >>= 1) {
        if (tid < o) red[tid] += red[tid + o];
        __syncthreads();
    }
    float mean = red[0] * (1.0f / WIDTH);
    __syncthreads();
    s = 0.f;
#pragma unroll
    for (int i = 0; i < PT; ++i) {
        float d = v[i] - mean;
        s += d * d;
    }
    red[tid] = s;
    __syncthreads();
#pragma unroll
    for (int o = 128; o > 0; o >>= 1) {
        if (tid < o) red[tid] += red[tid + o];
        __syncthreads();
    }
    float inv = rsqrtf(red[0] * (1.0f / WIDTH) + 1e-5f);
#pragma unroll
    for (int i = 0; i < PT; ++i) {
        int c = i * 256 + tid;
        O[(size_t)row * WIDTH + c] =
            __float2bfloat16(gelu_exact((v[i] - mean) * inv * g[c] + beta[c]));
    }
}

// ---------------------------------------------------------------------------
// importance gate: xi(bf16) = x * clamp(sigmoid(h1 . w2 + b2), 1e-6)
// ---------------------------------------------------------------------------
__global__ __launch_bounds__(256) void imp_scale(
    const float* __restrict__ h1, const float* __restrict__ w2,
    const float* __restrict__ b2, const float* __restrict__ x,
    __hip_bfloat16* __restrict__ xi) {
    int row = blockIdx.x;
    int tid = threadIdx.x;
    const float* hr = h1 + (size_t)row * CHALF;
    float s = hr[tid] * w2[tid] + hr[tid + 256] * w2[tid + 256];
    __shared__ float red[256];
    red[tid] = s;
    __syncthreads();
#pragma unroll
    for (int o = 128; o > 0; o >>= 1) {
        if (tid < o) red[tid] += red[tid + o];
        __syncthreads();
    }
    float z = red[0] + b2[0];
    float sg = 1.0f / (1.0f + expf(-z));
    float imp = fmaxf(sg, 1e-6f);
#pragma unroll
    for (int i = 0; i < 4; ++i) {
        int c = i * 256 + tid;
        xi[(size_t)row * CC + c] =
            __float2bfloat16(x[(size_t)row * CC + c] * imp);
    }
}

// ---------------------------------------------------------------------------
// reasoned.mean(axis=1), reading bf16 reasoned
// ---------------------------------------------------------------------------
__global__ __launch_bounds__(256) void mean_part(
    const __hip_bfloat16* __restrict__ R, float* __restrict__ part) {
    int idx = blockIdx.x * 256 + threadIdx.x;
    int c = idx & (CC - 1);
    int chunk = (idx >> 10) & 15;
    int b = idx >> 14;
    const __hip_bfloat16* base = R + ((size_t)(b * TT + chunk * 128)) * CC + c;
    float s = 0.f;
    for (int t = 0; t < 128; ++t) s += __bfloat162float(base[(size_t)t * CC]);
    part[idx] = s;
}

__global__ __launch_bounds__(256) void mean_fin(
    const float* __restrict__ part, float* __restrict__ rm) {
    int idx = blockIdx.x * 256 + threadIdx.x;
    int c = idx & (CC - 1);
    int b = idx >> 10;
    float s = 0.f;
#pragma unroll
    for (int ch = 0; ch < 16; ++ch) s += part[(size_t)(b * 16 + ch) * CC + c];
    rm[idx] = s * (1.0f / TT);
}

// ---------------------------------------------------------------------------
// temp_net
// ---------------------------------------------------------------------------
__global__ __launch_bounds__(512) void temp_net(
    const float* __restrict__ rm, const float* __restrict__ w1,
    const float* __restrict__ b1, const float* __restrict__ g,
    const float* __restrict__ beta, const float* __restrict__ w2,
    const float* __restrict__ b2, float* __restrict__ temp) {
    __shared__ float xr[CC];
    __shared__ float ht[CHALF];
    __shared__ float red[512];
    int b = blockIdx.x;
    int tid = threadIdx.x;
    xr[tid] = rm[b * CC + tid];
    xr[tid + 512] = rm[b * CC + tid + 512];
    __syncthreads();
    float acc = b1[tid];
#pragma unroll 8
    for (int i = 0; i < CC; ++i) acc = fmaf(xr[i], w1[(size_t)i * CHALF + tid], acc);
    red[tid] = acc;
    __syncthreads();
#pragma unroll
    for (int o = 256; o > 0; o >>= 1) {
        if (tid < o) red[tid] += red[tid + o];
        __syncthreads();
    }
    float mean = red[0] * (1.0f / CHALF);
    __syncthreads();
    float d = acc - mean;
    red[tid] = d * d;
    __syncthreads();
#pragma unroll
    for (int o = 256; o > 0; o >>= 1) {
        if (tid < o) red[tid] += red[tid + o];
        __syncthreads();
    }
    float inv = rsqrtf(red[0] * (1.0f / CHALF) + 1e-5f);
    ht[tid] = gelu_exact((acc - mean) * inv * g[tid] + beta[tid]);
    __syncthreads();
    if (tid < HH) {
        float s = b2[tid];
        for (int i = 0; i < CHALF; ++i) s = fmaf(ht[i], w2[i * HH + tid], s);
        float sp = fmaxf(s, 0.f) + log1pf(expf(-fabsf(s)));
        temp[b * HH + tid] = sp + 0.5f;
    }
}

// ---------------------------------------------------------------------------
// mask tile flags
// ---------------------------------------------------------------------------
__global__ __launch_bounds__(256) void mask_flags(
    const int* __restrict__ mask, int* __restrict__ flags) {
    int kt = blockIdx.x, qt = blockIdx.y, b = blockIdx.z;
    int tid = threadIdx.x;
    int r = tid >> 2;
    int c0 = (tid & 3) * 16;
    const int* base = mask + ((size_t)(b * TT + qt * 64 + r)) * TT + kt * 64 + c0;
    int all = 1;
#pragma unroll
    for (int i = 0; i < 4; ++i) {
        int4 m4 = *(const int4*)(base + i * 4);
        all &= (m4.x != 0) & (m4.y != 0) & (m4.z != 0) & (m4.w != 0);
    }
    __shared__ int red[256];
    red[tid] = all;
    __syncthreads();
#pragma unroll
    for (int o = 128; o > 0; o >>= 1) {
        if (tid < o) red[tid] &= red[tid + o];
        __syncthreads();
    }
    if (tid == 0) flags[(b * 32 + qt) * 32 + kt] = red[0];
}

// ---------------------------------------------------------------------------
// MFMA flash attention (bf16 in, bf16 out, fp32 softmax/accum)
// ---------------------------------------------------------------------------
__global__ __launch_bounds__(256) void flash_attn_mfma(
    const short* __restrict__ q, const short* __restrict__ k,
    const short* __restrict__ v, const int* __restrict__ mask,
    const int* __restrict__ flags, const float* __restrict__ temp,
    __hip_bfloat16* __restrict__ out) {
    __shared__ short Ks[64][72];
    __shared__ short Vt[64][72];
    __shared__ short Ps[64][72];
    int tid = threadIdx.x;
    int wave = tid >> 6;
    int lane = tid & 63;
    int m16 = lane & 15;
    int quad = lane >> 4;
    int qt = blockIdx.x;
    int q0 = qt * 64;
    int bh = blockIdx.y;
    int b = bh >> 4, h = bh & 15;
    float tscale = temp[bh] * 0.125f;

    const short* qrow =
        q + ((size_t)(b * TT + q0 + wave * 16 + m16)) * CC + h * DD + quad * 8;
    short8 qf0 = *(const short8*)(qrow);
    short8 qf1 = *(const short8*)(qrow + 32);

    float m_run[4], l_run[4];
    f32x4 acc_o[4];
#pragma unroll
    for (int r = 0; r < 4; ++r) {
        m_run[r] = -INFINITY;
        l_run[r] = 0.f;
    }
#pragma unroll
    for (int t = 0; t < 4; ++t) acc_o[t] = (f32x4){0.f, 0.f, 0.f, 0.f};

    for (int kt = 0; kt < TT / 64; ++kt) {
        int kb = kt * 64;
#pragma unroll
        for (int i = 0; i < 2; ++i) {
            int idx = i * 256 + tid;
            int r = idx >> 3;
            int dc = (idx & 7) * 8;
            const short* kg = k + ((size_t)(b * TT + kb + r)) * CC + h * DD + dc;
            *(short8*)&Ks[r][dc] = *(const short8*)kg;
            const short* vg = v + ((size_t)(b * TT + kb + r)) * CC + h * DD + dc;
            short8 vv = *(const short8*)vg;
#pragma unroll
            for (int u = 0; u < 8; ++u) Vt[dc + u][r] = vv[u];
        }
        __syncthreads();

        f32x4 sacc[4];
#pragma unroll
        for (int t = 0; t < 4; ++t) sacc[t] = (f32x4){0.f, 0.f, 0.f, 0.f};
#pragma unroll
        for (int t = 0; t < 4; ++t) {
            short8 kf0 = *(const short8*)&Ks[t * 16 + m16][quad * 8];
            sacc[t] = __builtin_amdgcn_mfma_f32_16x16x32_bf16(qf0, kf0, sacc[t], 0, 0, 0);
            short8 kf1 = *(const short8*)&Ks[t * 16 + m16][32 + quad * 8];
            sacc[t] = __builtin_amdgcn_mfma_f32_16x16x32_bf16(qf1, kf1, sacc[t], 0, 0, 0);
        }

        float sv[4][4];
#pragma unroll
        for (int t = 0; t < 4; ++t)
#pragma unroll
            for (int r = 0; r < 4; ++r) sv[t][r] = sacc[t][r] * tscale;
        if (flags[(b * 32 + qt) * 32 + kt] == 0) {
#pragma unroll
            for (int t = 0; t < 4; ++t)
#pragma unroll
                for (int r = 0; r < 4; ++r) {
                    int qg = q0 + wave * 16 + quad * 4 + r;
                    int kg = kb + t * 16 + m16;
                    if (mask[((size_t)(b * TT + qg)) * TT + kg] == 0)
                        sv[t][r] = -INFINITY;
                }
        }

        float rmax[4], rsum[4], alpha[4];
#pragma unroll
        for (int r = 0; r < 4; ++r) {
            float mx = fmaxf(fmaxf(sv[0][r], sv[1][r]), fmaxf(sv[2][r], sv[3][r]));
#pragma unroll
            for (int off = 1; off < 16; off <<= 1)
                mx = fmaxf(mx, __shfl_xor(mx, off, 64));
            float mnew = fmaxf(m_run[r], mx);
            alpha[r] = __expf(m_run[r] - mnew);
            m_run[r] = mnew;
            rmax[r] = mnew;
            rsum[r] = 0.f;
        }
#pragma unroll
        for (int t = 0; t < 4; ++t)
#pragma unroll
            for (int r = 0; r < 4; ++r) {
                float p = __expf(sv[t][r] - rmax[r]);
                rsum[r] += p;
                Ps[wave * 16 + quad * 4 + r][t * 16 + m16] = f2bf(p);
            }
#pragma unroll
        for (int r = 0; r < 4; ++r) {
#pragma unroll
            for (int off = 1; off < 16; off <<= 1)
                rsum[r] += __shfl_xor(rsum[r], off, 64);
            l_run[r] = l_run[r] * alpha[r] + rsum[r];
#pragma unroll
            for (int t = 0; t < 4; ++t) acc_o[t][r] *= alpha[r];
        }
        __syncthreads();

        short8 pf0 = *(const short8*)&Ps[wave * 16 + m16][quad * 8];
        short8 pf1 = *(const short8*)&Ps[wave * 16 + m16][32 + quad * 8];
#pragma unroll
        for (int t = 0; t < 4; ++t) {
            short8 vf0 = *(const short8*)&Vt[t * 16 + m16][quad * 8];
            acc_o[t] = __builtin_amdgcn_mfma_f32_16x16x32_bf16(pf0, vf0, acc_o[t], 0, 0, 0);
            short8 vf1 = *(const short8*)&Vt[t * 16 + m16][32 + quad * 8];
            acc_o[t] = __builtin_amdgcn_mfma_f32_16x16x32_bf16(pf1, vf1, acc_o[t], 0, 0, 0);
        }
        __syncthreads();
    }

#pragma unroll
    for (int r = 0; r < 4; ++r) {
        float inv = 1.0f / l_run[r];
        int row = b * TT + q0 + wave * 16 + quad * 4 + r;
#pragma unroll
        for (int t = 0; t < 4; ++t)
            out[(size_t)row * CC + h * DD + t * 16 + m16] =
                __float2bfloat16(acc_o[t][r] * inv);
    }
}

// ---------------------------------------------------------------------------
// Final: out = LN(x + proj)
// ---------------------------------------------------------------------------
__global__ __launch_bounds__(256) void final_ln(
    const float* __restrict__ x, const float* __restrict__ p,
    const float* __restrict__ g, const float* __restrict__ beta,
    float* __restrict__ out) {
    int row = blockIdx.x;
    int tid = threadIdx.x;
    const float* xr = x + (size_t)row * CC;
    const float* pr = p + (size_t)row * CC;
    float v[4];
    float s = 0.f;
#pragma unroll
    for (int i = 0; i < 4; ++i) {
        int c = i * 256 + tid;
        v[i] = xr[c] + pr[c];
        s += v[i];
    }
    __shared__ float red[256];
    red[tid] = s;
    __syncthreads();
#pragma unroll
    for (int o = 128; o > 0; o >>= 1) {
        if (tid < o) red[tid] += red[tid + o];
        __syncthreads();
    }
    float mean = red[0] * (1.0f / CC);
    __syncthreads();
    s = 0.f;
#pragma unroll
    for (int i = 0; i < 4; ++i) {
        float d = v[i] - mean;
        s += d * d;
    }
    red[tid] = s;
    __syncthreads();
#pragma unroll
    for (int o = 128; o > 0; o >>= 1) {
        if (tid < o) red[tid] += red[tid + o];
        __syncthreads();
    }
    float inv = rsqrtf(red[0] * (1.0f / CC) + 1e-5f);
#pragma unroll
    for (int i = 0; i < 4; ++i) {
        int c = i * 256 + tid;
        out[(size_t)row * CC + c] = (v[i] - mean) * inv * g[c] + beta[c];
    }
}

extern "C" void kernel_launch(void* const* d_in, const int* in_sizes, int n_in,
                              void* d_out, int out_size, void* d_ws,
                              size_t ws_size, hipStream_t stream) {
    const float* x        = (const float*)d_in[0];
    const int*   mask     = (const int*)d_in[1];
    const float* imp_w1   = (const float*)d_in[2];
    const float* imp_b1   = (const float*)d_in[3];
    const float* imp_g    = (const float*)d_in[4];
    const float* imp_beta = (const float*)d_in[5];
    const float* imp_w2   = (const float*)d_in[6];
    const float* imp_b2   = (const float*)d_in[7];
    const float* rsn_w1   = (const float*)d_in[8];
    const float* rsn_b1   = (const float*)d_in[9];
    const float* rsn_g    = (const float*)d_in[10];
    const float* rsn_beta = (const float*)d_in[11];
    const float* rsn_w2   = (const float*)d_in[12];
    const float* rsn_b2   = (const float*)d_in[13];
    const float* q_w      = (const float*)d_in[14];
    const float* q_b      = (const float*)d_in[15];
    const float* k_w      = (const float*)d_in[16];
    const float* k_b      = (const float*)d_in[17];
    const float* v_w      = (const float*)d_in[18];
    const float* v_b      = (const float*)d_in[19];
    const float* o_w      = (const float*)d_in[20];
    const float* o_b      = (const float*)d_in[21];
    const float* tmp_w1   = (const float*)d_in[22];
    const float* tmp_b1   = (const float*)d_in[23];
    const float* tmp_g    = (const float*)d_in[24];
    const float* tmp_beta = (const float*)d_in[25];
    const float* tmp_w2   = (const float*)d_in[26];
    const float* tmp_b2   = (const float*)d_in[27];
    const float* norm_g   = (const float*)d_in[28];
    const float* norm_b   = (const float*)d_in[29];
    float* out = (float*)d_out;
    float* ws  = (float*)d_ws;

    // workspace layout (float offsets)
    float* h1  = ws;                       // [4096,512] fp32
    float* h2  = ws + 2097152;             // [4096,1024] fp32 (later o-proj out)
    __hip_bfloat16* x_bf  = (__hip_bfloat16*)(ws + 6291456);
    __hip_bfloat16* xi_bf = (__hip_bfloat16*)(ws + 8388608);
    __hip_bfloat16* h2b   = (__hip_bfloat16*)(ws + 10485760);
    __hip_bfloat16* rs_bf = (__hip_bfloat16*)(ws + 12582912);  // reasoned, later attn out
    __hip_bfloat16* qb    = (__hip_bfloat16*)(ws + 14680064);
    __hip_bfloat16* kb    = (__hip_bfloat16*)(ws + 16777216);
    __hip_bfloat16* vb    = (__hip_bfloat16*)(ws + 18874368);
    __hip_bfloat16* imp_w1t = (__hip_bfloat16*)(ws + 20971520);  // [512,1024]
    __hip_bfloat16* rsn_w1t = (__hip_bfloat16*)(ws + 21233664);  // [1024,1024]
    __hip_bfloat16* rsn_w2t = (__hip_bfloat16*)(ws + 21757952);
    __hip_bfloat16* q_wt    = (__hip_bfloat16*)(ws + 22282240);
    __hip_bfloat16* k_wt    = (__hip_bfloat16*)(ws + 22806528);
    __hip_bfloat16* v_wt    = (__hip_bfloat16*)(ws + 23330816);
    __hip_bfloat16* o_wt    = (__hip_bfloat16*)(ws + 23855104);
    float* rm   = ws + 24379392;   // [2,1024]
    float* tmp  = ws + 24381440;   // [2,16]
    float* part = ws + 24381952;   // [2,16,1024]
    int*   flg  = (int*)(ws + 24414720);  // [2,32,32]

    dim3 blk(256);
    // converts: x -> bf16; weights -> bf16 transposed [N,K]
    conv_bf16<<<NN * CC / (256 * 8), blk, 0, stream>>>(x, x_bf);
    conv_transpose_bf16<<<dim3(CHALF / 64, CC / 64), blk, 0, stream>>>(imp_w1, imp_w1t, CC, CHALF);
    conv_transpose_bf16<<<dim3(CC / 64, CC / 64), blk, 0, stream>>>(rsn_w1, rsn_w1t, CC, CC);
    conv_transpose_bf16<<<dim3(CC / 64, CC / 64), blk, 0, stream>>>(rsn_w2, rsn_w2t, CC, CC);
    conv_transpose_bf16<<<dim3(CC / 64, CC / 64), blk, 0, stream>>>(q_w, q_wt, CC, CC);
    conv_transpose_bf16<<<dim3(CC / 64, CC / 64), blk, 0, stream>>>(k_w, k_wt, CC, CC);
    conv_transpose_bf16<<<dim3(CC / 64, CC / 64), blk, 0, stream>>>(v_w, v_wt, CC, CC);
    conv_transpose_bf16<<<dim3(CC / 64, CC / 64), blk, 0, stream>>>(o_w, o_wt, CC, CC);
    // mask tile flags (independent)
    mask_flags<<<dim3(32, 32, 2), blk, 0, stream>>>(mask, flg);

    // importance net
    gemm_mfma<false><<<dim3(CHALF / 128, NN / 128), blk, 0, stream>>>(
        (const short*)x_bf, (const short*)imp_w1t, imp_b1, h1, nullptr, NN, CHALF, CC);
    ln_gelu_kernel<CHALF><<<NN, blk, 0, stream>>>(h1, imp_g, imp_beta);
    imp_scale<<<NN, blk, 0, stream>>>(h1, imp_w2, imp_b2, x, xi_bf);
    // reasoning net
    gemm_mfma<false><<<dim3(CC / 128, NN / 128), blk, 0, stream>>>(
        (const short*)xi_bf, (const short*)rsn_w1t, rsn_b1, h2, nullptr, NN, CC, CC);
    ln_gelu_bf16<CC><<<NN, blk, 0, stream>>>(h2, rsn_g, rsn_beta, h2b);
    gemm_mfma<true><<<dim3(CC / 128, NN / 128), blk, 0, stream>>>(
        (const short*)h2b, (const short*)rsn_w2t, rsn_b2, nullptr, rs_bf, NN, CC, CC);
    // q projection + temperature net
    gemm_mfma<true><<<dim3(CC / 128, NN / 128), blk, 0, stream>>>(
        (const short*)rs_bf, (const short*)q_wt, q_b, nullptr, qb, NN, CC, CC);
    mean_part<<<128, blk, 0, stream>>>(rs_bf, part);
    mean_fin<<<8, blk, 0, stream>>>(part, rm);
    temp_net<<<BB, dim3(512), 0, stream>>>(rm, tmp_w1, tmp_b1, tmp_g, tmp_beta, tmp_w2, tmp_b2, tmp);
    // k, v projections
    gemm_mfma<true><<<dim3(CC / 128, NN / 128), blk, 0, stream>>>(
        (const short*)xi_bf, (const short*)k_wt, k_b, nullptr, kb, NN, CC, CC);
    gemm_mfma<true><<<dim3(CC / 128, NN / 128), blk, 0, stream>>>(
        (const short*)x_bf, (const short*)v_wt, v_b, nullptr, vb, NN, CC, CC);
    // flash attention (writes bf16 into rs_bf region, free now)
    flash_attn_mfma<<<dim3(TT / 64, BB * HH), blk, 0, stream>>>(
        (const short*)qb, (const short*)kb, (const short*)vb, mask, flg, tmp, rs_bf);
    // output projection (fp32 into h2, free now) + residual LN
    gemm_mfma<false><<<dim3(CC / 128, NN / 128), blk, 0, stream>>>(
        (const short*)rs_bf, (const short*)o_wt, o_b, h2, nullptr, NN, CC, CC);
    final_ln<<<NN, blk, 0, stream>>>(x, h2, norm_g, norm_b, out);
}

// Round 4
// 552.446 us; speedup vs baseline: 3.4271x; 1.1556x over previous
//
#include <hip/hip_runtime.h>
#include <hip/hip_bf16.h>
#include <math.h>

// Problem constants
#define BB 2
#define TT 2048
#define CC 1024
#define HH 16
#define DD 64
#define CHALF 512
#define NN (BB * TT)   // 4096 rows

typedef __attribute__((ext_vector_type(8))) short short8;
typedef __attribute__((ext_vector_type(4))) short short4_t;
typedef __attribute__((ext_vector_type(4))) float f32x4;

__device__ __forceinline__ float gelu_exact(float x) {
    return 0.5f * x * (1.0f + erff(x * 0.70710678118654752f));
}

__device__ __forceinline__ short f2bf(float f) {
    __hip_bfloat16 h = __float2bfloat16(f);
    short s;
    __builtin_memcpy(&s, &h, 2);
    return s;
}

// async global->LDS, 16 B per lane; LDS dst must be wave-uniform base
__device__ __forceinline__ void async_copy16(const void* g, void* l) {
    __builtin_amdgcn_global_load_lds(
        (const __attribute__((address_space(1))) void*)g,
        (__attribute__((address_space(3))) void*)l, 16, 0, 0);
}

// ---------------------------------------------------------------------------
// fp32 -> bf16 elementwise convert (x)
// ---------------------------------------------------------------------------
__global__ __launch_bounds__(256) void conv_bf16(
    const float* __restrict__ X, __hip_bfloat16* __restrict__ O) {
    int i = (blockIdx.x * 256 + threadIdx.x) * 8;
    float4 a = *(const float4*)&X[i];
    float4 b = *(const float4*)&X[i + 4];
    __hip_bfloat16 o[8] = {
        __float2bfloat16(a.x), __float2bfloat16(a.y),
        __float2bfloat16(a.z), __float2bfloat16(a.w),
        __float2bfloat16(b.x), __float2bfloat16(b.y),
        __float2bfloat16(b.z), __float2bfloat16(b.w)};
    *(float4*)&O[i] = *(float4*)o;
}

// ---------------------------------------------------------------------------
// W [K,N] fp32 -> Wt [N,K] bf16 (transpose for MFMA B-operand layout)
// ---------------------------------------------------------------------------
__global__ __launch_bounds__(256) void conv_transpose_bf16(
    const float* __restrict__ W, __hip_bfloat16* __restrict__ Wt,
    int K, int N) {
    __shared__ float T[64][65];
    int n0 = blockIdx.x * 64, k0 = blockIdx.y * 64;
    int tid = threadIdx.x;
    int c = tid & 63, r4 = tid >> 6;
#pragma unroll
    for (int i = 0; i < 16; ++i) {
        int row = i * 4 + r4;
        T[row][c] = W[(size_t)(k0 + row) * N + n0 + c];
    }
    __syncthreads();
#pragma unroll
    for (int i = 0; i < 16; ++i) {
        int row = i * 4 + r4;  // n index
        Wt[(size_t)(n0 + row) * K + k0 + c] = __float2bfloat16(T[c][row]);
    }
}

// ---------------------------------------------------------------------------
// bf16 MFMA GEMM: C[M,N] = A[M,K](bf16) @ Wt[N,K](bf16)^T + bias
// ---------------------------------------------------------------------------
template <bool BF16OUT>
__global__ __launch_bounds__(256) void gemm_mfma(
    const short* __restrict__ A, const short* __restrict__ Wt,
    const float* __restrict__ bias, float* __restrict__ Cf,
    __hip_bfloat16* __restrict__ Cb, int M, int N, int K) {
    __shared__ short As[128][32];
    __shared__ short Bs[128][32];
    int tid = threadIdx.x;
    int wave = tid >> 6, lane = tid & 63;
    int m16 = lane & 15, quad = lane >> 4;
    int wm = wave >> 1, wn = wave & 1;
    int row0 = blockIdx.y * 128, col0 = blockIdx.x * 128;
    int lr = lane >> 2;
    int kof = (lane & 3) * 8;

    f32x4 acc[4][4];
#pragma unroll
    for (int i = 0; i < 4; ++i)
#pragma unroll
        for (int j = 0; j < 4; ++j) acc[i][j] = (f32x4){0.f, 0.f, 0.f, 0.f};

    for (int k0 = 0; k0 < K; k0 += 32) {
#pragma unroll
        for (int j = 0; j < 2; ++j) {
            int rbase = wave * 32 + j * 16;
            async_copy16(A + (size_t)(row0 + rbase + lr) * K + k0 + kof,
                         &As[rbase][0]);
            async_copy16(Wt + (size_t)(col0 + rbase + lr) * K + k0 + kof,
                         &Bs[rbase][0]);
        }
        __syncthreads();
        short8 af[4], bfr[4];
#pragma unroll
        for (int i = 0; i < 4; ++i)
            af[i] = *(const short8*)&As[wm * 64 + i * 16 + m16][quad * 8];
#pragma unroll
        for (int j = 0; j < 4; ++j)
            bfr[j] = *(const short8*)&Bs[wn * 64 + j * 16 + m16][quad * 8];
#pragma unroll
        for (int i = 0; i < 4; ++i)
#pragma unroll
            for (int j = 0; j < 4; ++j)
                acc[i][j] = __builtin_amdgcn_mfma_f32_16x16x32_bf16(
                    af[i], bfr[j], acc[i][j], 0, 0, 0);
        __syncthreads();
    }
#pragma unroll
    for (int i = 0; i < 4; ++i) {
#pragma unroll
        for (int j = 0; j < 4; ++j) {
            int col = col0 + wn * 64 + j * 16 + m16;
            float bv = bias[col];
#pragma unroll
            for (int rr = 0; rr < 4; ++rr) {
                int row = row0 + wm * 64 + i * 16 + quad * 4 + rr;
                float val = acc[i][j][rr] + bv;
                if (BF16OUT)
                    Cb[(size_t)row * N + col] = __float2bfloat16(val);
                else
                    Cf[(size_t)row * N + col] = val;
            }
        }
    }
}

// ---------------------------------------------------------------------------
// Row-wise LayerNorm + exact GELU, in place (fp32, for h1)
// ---------------------------------------------------------------------------
template <int WIDTH>
__global__ __launch_bounds__(256) void ln_gelu_kernel(
    float* __restrict__ Y, const float* __restrict__ g,
    const float* __restrict__ beta) {
    constexpr int PT = WIDTH / 256;
    int row = blockIdx.x;
    int tid = threadIdx.x;
    float* yr = Y + (size_t)row * WIDTH;
    float v[PT];
    float s = 0.f;
#pragma unroll
    for (int i = 0; i < PT; ++i) {
        v[i] = yr[i * 256 + tid];
        s += v[i];
    }
    __shared__ float red[256];
    red[tid] = s;
    __syncthreads();
#pragma unroll
    for (int o = 128; o > 0; o >>= 1) {
        if (tid < o) red[tid] += red[tid + o];
        __syncthreads();
    }
    float mean = red[0] * (1.0f / WIDTH);
    __syncthreads();
    s = 0.f;
#pragma unroll
    for (int i = 0; i < PT; ++i) {
        float d = v[i] - mean;
        s += d * d;
    }
    red[tid] = s;
    __syncthreads();
#pragma unroll
    for (int o = 128; o > 0; o >>= 1) {
        if (tid < o) red[tid] += red[tid + o];
        __syncthreads();
    }
    float inv = rsqrtf(red[0] * (1.0f / WIDTH) + 1e-5f);
#pragma unroll
    for (int i = 0; i < PT; ++i) {
        int c = i * 256 + tid;
        yr[c] = gelu_exact((v[i] - mean) * inv * g[c] + beta[c]);
    }
}

// Same, fp32 in, bf16 out-of-place
template <int WIDTH>
__global__ __launch_bounds__(256) void ln_gelu_bf16(
    const float* __restrict__ Y, const float* __restrict__ g,
    const float* __restrict__ beta, __hip_bfloat16* __restrict__ O) {
    constexpr int PT = WIDTH / 256;
    int row = blockIdx.x;
    int tid = threadIdx.x;
    const float* yr = Y + (size_t)row * WIDTH;
    float v[PT];
    float s = 0.f;
#pragma unroll
    for (int i = 0; i < PT; ++i) {
        v[i] = yr[i * 256 + tid];
        s += v[i];
    }
    __shared__ float red[256];
    red[tid] = s;
    __syncthreads();
#pragma unroll
    for (int o = 128; o > 0; o >>= 1) {
        if (tid < o) red[tid] += red[tid + o];
        __syncthreads();
    }
    float mean = red[0] * (1.0f / WIDTH);
    __syncthreads();
    s = 0.f;
#pragma unroll
    for (int i = 0; i < PT; ++i) {
        float d = v[i] - mean;
        s += d * d;
    }
    red[tid] = s;
    __syncthreads();
#pragma unroll
    for (int o = 128; o > 0; o >>= 1) {
        if (tid < o) red[tid] += red[tid + o];
        __syncthreads();
    }
    float inv = rsqrtf(red[0] * (1.0f / WIDTH) + 1e-5f);
#pragma unroll
    for (int i = 0; i < PT; ++i) {
        int c = i * 256 + tid;
        O[(size_t)row * WIDTH + c] =
            __float2bfloat16(gelu_exact((v[i] - mean) * inv * g[c] + beta[c]));
    }
}

// ---------------------------------------------------------------------------
// importance gate: xi(bf16) = x * clamp(sigmoid(h1 . w2 + b2), 1e-6)
// ---------------------------------------------------------------------------
__global__ __launch_bounds__(256) void imp_scale(
    const float* __restrict__ h1, const float* __restrict__ w2,
    const float* __restrict__ b2, const float* __restrict__ x,
    __hip_bfloat16* __restrict__ xi) {
    int row = blockIdx.x;
    int tid = threadIdx.x;
    const float* hr = h1 + (size_t)row * CHALF;
    float s = hr[tid] * w2[tid] + hr[tid + 256] * w2[tid + 256];
    __shared__ float red[256];
    red[tid] = s;
    __syncthreads();
#pragma unroll
    for (int o = 128; o > 0; o >>= 1) {
        if (tid < o) red[tid] += red[tid + o];
        __syncthreads();
    }
    float z = red[0] + b2[0];
    float sg = 1.0f / (1.0f + expf(-z));
    float imp = fmaxf(sg, 1e-6f);
#pragma unroll
    for (int i = 0; i < 4; ++i) {
        int c = i * 256 + tid;
        xi[(size_t)row * CC + c] =
            __float2bfloat16(x[(size_t)row * CC + c] * imp);
    }
}

// ---------------------------------------------------------------------------
// reasoned.mean(axis=1), reading bf16 reasoned
// ---------------------------------------------------------------------------
__global__ __launch_bounds__(256) void mean_part(
    const __hip_bfloat16* __restrict__ R, float* __restrict__ part) {
    int idx = blockIdx.x * 256 + threadIdx.x;
    int c = idx & (CC - 1);
    int chunk = (idx >> 10) & 15;
    int b = idx >> 14;
    const __hip_bfloat16* base = R + ((size_t)(b * TT + chunk * 128)) * CC + c;
    float s = 0.f;
    for (int t = 0; t < 128; ++t) s += __bfloat162float(base[(size_t)t * CC]);
    part[idx] = s;
}

__global__ __launch_bounds__(256) void mean_fin(
    const float* __restrict__ part, float* __restrict__ rm) {
    int idx = blockIdx.x * 256 + threadIdx.x;
    int c = idx & (CC - 1);
    int b = idx >> 10;
    float s = 0.f;
#pragma unroll
    for (int ch = 0; ch < 16; ++ch) s += part[(size_t)(b * 16 + ch) * CC + c];
    rm[idx] = s * (1.0f / TT);
}

// ---------------------------------------------------------------------------
// temp_net
// ---------------------------------------------------------------------------
__global__ __launch_bounds__(512) void temp_net(
    const float* __restrict__ rm, const float* __restrict__ w1,
    const float* __restrict__ b1, const float* __restrict__ g,
    const float* __restrict__ beta, const float* __restrict__ w2,
    const float* __restrict__ b2, float* __restrict__ temp) {
    __shared__ float xr[CC];
    __shared__ float ht[CHALF];
    __shared__ float red[512];
    int b = blockIdx.x;
    int tid = threadIdx.x;
    xr[tid] = rm[b * CC + tid];
    xr[tid + 512] = rm[b * CC + tid + 512];
    __syncthreads();
    float acc = b1[tid];
#pragma unroll 8
    for (int i = 0; i < CC; ++i) acc = fmaf(xr[i], w1[(size_t)i * CHALF + tid], acc);
    red[tid] = acc;
    __syncthreads();
#pragma unroll
    for (int o = 256; o > 0; o >>= 1) {
        if (tid < o) red[tid] += red[tid + o];
        __syncthreads();
    }
    float mean = red[0] * (1.0f / CHALF);
    __syncthreads();
    float d = acc - mean;
    red[tid] = d * d;
    __syncthreads();
#pragma unroll
    for (int o = 256; o > 0; o >>= 1) {
        if (tid < o) red[tid] += red[tid + o];
        __syncthreads();
    }
    float inv = rsqrtf(red[0] * (1.0f / CHALF) + 1e-5f);
    ht[tid] = gelu_exact((acc - mean) * inv * g[tid] + beta[tid]);
    __syncthreads();
    if (tid < HH) {
        float s = b2[tid];
        for (int i = 0; i < CHALF; ++i) s = fmaf(ht[i], w2[i * HH + tid], s);
        float sp = fmaxf(s, 0.f) + log1pf(expf(-fabsf(s)));
        temp[b * HH + tid] = sp + 0.5f;
    }
}

// ---------------------------------------------------------------------------
// mask tile flags (64x64 tiles)
// ---------------------------------------------------------------------------
__global__ __launch_bounds__(256) void mask_flags(
    const int* __restrict__ mask, int* __restrict__ flags) {
    int kt = blockIdx.x, qt = blockIdx.y, b = blockIdx.z;
    int tid = threadIdx.x;
    int r = tid >> 2;
    int c0 = (tid & 3) * 16;
    const int* base = mask + ((size_t)(b * TT + qt * 64 + r)) * TT + kt * 64 + c0;
    int all = 1;
#pragma unroll
    for (int i = 0; i < 4; ++i) {
        int4 m4 = *(const int4*)(base + i * 4);
        all &= (m4.x != 0) & (m4.y != 0) & (m4.z != 0) & (m4.w != 0);
    }
    __shared__ int red[256];
    red[tid] = all;
    __syncthreads();
#pragma unroll
    for (int o = 128; o > 0; o >>= 1) {
        if (tid < o) red[tid] &= red[tid + o];
        __syncthreads();
    }
    if (tid == 0) flags[(b * 32 + qt) * 32 + kt] = red[0];
}

// ---------------------------------------------------------------------------
// MFMA flash attention v2 (transposed-QK softmax, 128-row q-tile).
// Block: 256 thr = 4 waves; q-rows = blockIdx.x*128 + wave*32 + qg*16 + m16.
// S^T = mfma(A=Kfrag, B=Qfrag): lane holds (key=quad*4+r, q=m16) -> softmax
// reduction is in-lane + 2 shuffles. P stored b64 (4 consecutive keys).
// PV: O = mfma(A=Pfrag, B=Vtfrag), C layout (q=quad*4+r, d=m16).
// ---------------------------------------------------------------------------
__global__ __launch_bounds__(256) void flash_attn_mfma(
    const short* __restrict__ q, const short* __restrict__ k,
    const short* __restrict__ v, const int* __restrict__ mask,
    const int* __restrict__ flags, const float* __restrict__ temp,
    __hip_bfloat16* __restrict__ out) {
    __shared__ short Ks[64][72];    // [key][d]
    __shared__ short Vt[64][72];    // [d][key]
    __shared__ short Ps[128][72];   // [q-row][key], wave-private 32-row strips
    int tid = threadIdx.x;
    int wave = tid >> 6, lane = tid & 63;
    int m16 = lane & 15, quad = lane >> 4;
    int qt = blockIdx.x;            // 128-row q tile
    int q0 = qt * 128;
    int bh = blockIdx.y;
    int b = bh >> 4, h = bh & 15;
    float tscale = temp[bh] * 0.125f;

    // V staging map: lane = key row, wave = d-chunk (conflict-free Vt writes)
    int vr = tid & 63, vc2 = tid >> 6;

    // Q fragments (2 q-groups of 16 rows each)
    short8 qf[2][2];
#pragma unroll
    for (int qg = 0; qg < 2; ++qg) {
        const short* qrow = q + ((size_t)(b * TT + q0 + wave * 32 + qg * 16 + m16)) * CC +
                            h * DD + quad * 8;
        qf[qg][0] = *(const short8*)(qrow);
        qf[qg][1] = *(const short8*)(qrow + 32);
    }

    float m_run[2] = {-INFINITY, -INFINITY};
    float l_run[2] = {0.f, 0.f};
    f32x4 acc_o[2][4];
#pragma unroll
    for (int qg = 0; qg < 2; ++qg)
#pragma unroll
        for (int t = 0; t < 4; ++t) acc_o[qg][t] = (f32x4){0.f, 0.f, 0.f, 0.f};

    for (int kt = 0; kt < TT / 64; ++kt) {
        int kb = kt * 64;
        // ---- stage K row-major (coalesced) ----
#pragma unroll
        for (int i = 0; i < 2; ++i) {
            int idx = i * 256 + tid;
            int r = idx >> 3;
            int dc = (idx & 7) * 8;
            *(short8*)&Ks[r][dc] =
                *(const short8*)(k + ((size_t)(b * TT + kb + r)) * CC + h * DD + dc);
        }
        // ---- stage V transposed (lane=key -> all lanes same Vt row per u) ----
        {
            const short* vg = v + ((size_t)(b * TT + kb + vr)) * CC + h * DD + vc2 * 16;
            short8 v0 = *(const short8*)(vg);
            short8 v1 = *(const short8*)(vg + 8);
#pragma unroll
            for (int u = 0; u < 8; ++u) Vt[vc2 * 16 + u][vr] = v0[u];
#pragma unroll
            for (int u = 0; u < 8; ++u) Vt[vc2 * 16 + 8 + u][vr] = v1[u];
        }
        __syncthreads();

        // K fragments (shared by both q-groups)
        short8 kf[4][2];
#pragma unroll
        for (int t = 0; t < 4; ++t) {
            kf[t][0] = *(const short8*)&Ks[t * 16 + m16][quad * 8];
            kf[t][1] = *(const short8*)&Ks[t * 16 + m16][32 + quad * 8];
        }
        int fl = flags[(b * 32 + 2 * qt + (wave >> 1)) * 32 + kt];
        float alpha_v[2];

#pragma unroll
        for (int qg = 0; qg < 2; ++qg) {
            // S^T tiles: lane holds key = t*16 + quad*4 + r, q = m16
            f32x4 sacc[4];
#pragma unroll
            for (int t = 0; t < 4; ++t) sacc[t] = (f32x4){0.f, 0.f, 0.f, 0.f};
#pragma unroll
            for (int t = 0; t < 4; ++t) {
                sacc[t] = __builtin_amdgcn_mfma_f32_16x16x32_bf16(kf[t][0], qf[qg][0], sacc[t], 0, 0, 0);
                sacc[t] = __builtin_amdgcn_mfma_f32_16x16x32_bf16(kf[t][1], qf[qg][1], sacc[t], 0, 0, 0);
            }
            float sv[4][4];
#pragma unroll
            for (int t = 0; t < 4; ++t)
#pragma unroll
                for (int r = 0; r < 4; ++r) sv[t][r] = sacc[t][r] * tscale;
            if (fl == 0) {
                int qrow = q0 + wave * 32 + qg * 16 + m16;
#pragma unroll
                for (int t = 0; t < 4; ++t)
#pragma unroll
                    for (int r = 0; r < 4; ++r) {
                        int kg = kb + t * 16 + quad * 4 + r;
                        if (mask[((size_t)(b * TT + qrow)) * TT + kg] == 0)
                            sv[t][r] = -INFINITY;
                    }
            }
            // max over 64 keys: 16 in-lane + cross-quad shuffles
            float mx = sv[0][0];
#pragma unroll
            for (int t = 0; t < 4; ++t)
#pragma unroll
                for (int r = 0; r < 4; ++r) mx = fmaxf(mx, sv[t][r]);
            mx = fmaxf(mx, __shfl_xor(mx, 16, 64));
            mx = fmaxf(mx, __shfl_xor(mx, 32, 64));
            float mnew = fmaxf(m_run[qg], mx);
            float alpha = __expf(m_run[qg] - mnew);
            m_run[qg] = mnew;
            alpha_v[qg] = alpha;
            // exp + P store (b64: 4 consecutive keys) + sum
            int prow = wave * 32 + qg * 16 + m16;
            float psum = 0.f;
#pragma unroll
            for (int t = 0; t < 4; ++t) {
                short4_t pk;
#pragma unroll
                for (int r = 0; r < 4; ++r) {
                    float p = __expf(sv[t][r] - mnew);
                    psum += p;
                    pk[r] = f2bf(p);
                }
                *(short4_t*)&Ps[prow][t * 16 + quad * 4] = pk;
            }
            psum += __shfl_xor(psum, 16, 64);
            psum += __shfl_xor(psum, 32, 64);
            l_run[qg] = l_run[qg] * alpha + psum;
            // rescale O accumulator (alpha redistributed to C-layout lanes)
#pragma unroll
            for (int r = 0; r < 4; ++r) {
                float ar = __shfl(alpha, (lane & 48) | (quad * 4 + r), 64);
#pragma unroll
                for (int td = 0; td < 4; ++td) acc_o[qg][td][r] *= ar;
            }
        }

        // PV: V fragments shared across q-groups
#pragma unroll
        for (int kc = 0; kc < 2; ++kc) {
            short8 vf[4];
#pragma unroll
            for (int td = 0; td < 4; ++td)
                vf[td] = *(const short8*)&Vt[td * 16 + m16][kc * 32 + quad * 8];
#pragma unroll
            for (int qg = 0; qg < 2; ++qg) {
                short8 pf = *(const short8*)&Ps[wave * 32 + qg * 16 + m16][kc * 32 + quad * 8];
#pragma unroll
                for (int td = 0; td < 4; ++td)
                    acc_o[qg][td] = __builtin_amdgcn_mfma_f32_16x16x32_bf16(
                        pf, vf[td], acc_o[qg][td], 0, 0, 0);
            }
        }
        __syncthreads();
    }

    // epilogue
#pragma unroll
    for (int qg = 0; qg < 2; ++qg) {
#pragma unroll
        for (int r = 0; r < 4; ++r) {
            float lr = __shfl(l_run[qg], (lane & 48) | (quad * 4 + r), 64);
            float inv = 1.0f / lr;
            int row = b * TT + q0 + wave * 32 + qg * 16 + quad * 4 + r;
#pragma unroll
            for (int td = 0; td < 4; ++td)
                out[(size_t)row * CC + h * DD + td * 16 + m16] =
                    __float2bfloat16(acc_o[qg][td][r] * inv);
        }
    }
}

// ---------------------------------------------------------------------------
// Final: out = LN(x + proj)
// ---------------------------------------------------------------------------
__global__ __launch_bounds__(256) void final_ln(
    const float* __restrict__ x, const float* __restrict__ p,
    const float* __restrict__ g, const float* __restrict__ beta,
    float* __restrict__ out) {
    int row = blockIdx.x;
    int tid = threadIdx.x;
    const float* xr = x + (size_t)row * CC;
    const float* pr = p + (size_t)row * CC;
    float v[4];
    float s = 0.f;
#pragma unroll
    for (int i = 0; i < 4; ++i) {
        int c = i * 256 + tid;
        v[i] = xr[c] + pr[c];
        s += v[i];
    }
    __shared__ float red[256];
    red[tid] = s;
    __syncthreads();
#pragma unroll
    for (int o = 128; o > 0; o >>= 1) {
        if (tid < o) red[tid] += red[tid + o];
        __syncthreads();
    }
    float mean = red[0] * (1.0f / CC);
    __syncthreads();
    s = 0.f;
#pragma unroll
    for (int i = 0; i < 4; ++i) {
        float d = v[i] - mean;
        s += d * d;
    }
    red[tid] = s;
    __syncthreads();
#pragma unroll
    for (int o = 128; o > 0; o >>= 1) {
        if (tid < o) red[tid] += red[tid + o];
        __syncthreads();
    }
    float inv = rsqrtf(red[0] * (1.0f / CC) + 1e-5f);
#pragma unroll
    for (int i = 0; i < 4; ++i) {
        int c = i * 256 + tid;
        out[(size_t)row * CC + c] = (v[i] - mean) * inv * g[c] + beta[c];
    }
}

extern "C" void kernel_launch(void* const* d_in, const int* in_sizes, int n_in,
                              void* d_out, int out_size, void* d_ws,
                              size_t ws_size, hipStream_t stream) {
    const float* x        = (const float*)d_in[0];
    const int*   mask     = (const int*)d_in[1];
    const float* imp_w1   = (const float*)d_in[2];
    const float* imp_b1   = (const float*)d_in[3];
    const float* imp_g    = (const float*)d_in[4];
    const float* imp_beta = (const float*)d_in[5];
    const float* imp_w2   = (const float*)d_in[6];
    const float* imp_b2   = (const float*)d_in[7];
    const float* rsn_w1   = (const float*)d_in[8];
    const float* rsn_b1   = (const float*)d_in[9];
    const float* rsn_g    = (const float*)d_in[10];
    const float* rsn_beta = (const float*)d_in[11];
    const float* rsn_w2   = (const float*)d_in[12];
    const float* rsn_b2   = (const float*)d_in[13];
    const float* q_w      = (const float*)d_in[14];
    const float* q_b      = (const float*)d_in[15];
    const float* k_w      = (const float*)d_in[16];
    const float* k_b      = (const float*)d_in[17];
    const float* v_w      = (const float*)d_in[18];
    const float* v_b      = (const float*)d_in[19];
    const float* o_w      = (const float*)d_in[20];
    const float* o_b      = (const float*)d_in[21];
    const float* tmp_w1   = (const float*)d_in[22];
    const float* tmp_b1   = (const float*)d_in[23];
    const float* tmp_g    = (const float*)d_in[24];
    const float* tmp_beta = (const float*)d_in[25];
    const float* tmp_w2   = (const float*)d_in[26];
    const float* tmp_b2   = (const float*)d_in[27];
    const float* norm_g   = (const float*)d_in[28];
    const float* norm_b   = (const float*)d_in[29];
    float* out = (float*)d_out;
    float* ws  = (float*)d_ws;

    // workspace layout (float offsets)
    float* h1  = ws;                       // [4096,512] fp32
    float* h2  = ws + 2097152;             // [4096,1024] fp32 (later o-proj out)
    __hip_bfloat16* x_bf  = (__hip_bfloat16*)(ws + 6291456);
    __hip_bfloat16* xi_bf = (__hip_bfloat16*)(ws + 8388608);
    __hip_bfloat16* h2b   = (__hip_bfloat16*)(ws + 10485760);
    __hip_bfloat16* rs_bf = (__hip_bfloat16*)(ws + 12582912);  // reasoned, later attn out
    __hip_bfloat16* qb    = (__hip_bfloat16*)(ws + 14680064);
    __hip_bfloat16* kb    = (__hip_bfloat16*)(ws + 16777216);
    __hip_bfloat16* vb    = (__hip_bfloat16*)(ws + 18874368);
    __hip_bfloat16* imp_w1t = (__hip_bfloat16*)(ws + 20971520);  // [512,1024]
    __hip_bfloat16* rsn_w1t = (__hip_bfloat16*)(ws + 21233664);  // [1024,1024]
    __hip_bfloat16* rsn_w2t = (__hip_bfloat16*)(ws + 21757952);
    __hip_bfloat16* q_wt    = (__hip_bfloat16*)(ws + 22282240);
    __hip_bfloat16* k_wt    = (__hip_bfloat16*)(ws + 22806528);
    __hip_bfloat16* v_wt    = (__hip_bfloat16*)(ws + 23330816);
    __hip_bfloat16* o_wt    = (__hip_bfloat16*)(ws + 23855104);
    float* rm   = ws + 24379392;   // [2,1024]
    float* tmp  = ws + 24381440;   // [2,16]
    float* part = ws + 24381952;   // [2,16,1024]
    int*   flg  = (int*)(ws + 24414720);  // [2,32,32]

    dim3 blk(256);
    // converts: x -> bf16; weights -> bf16 transposed [N,K]
    conv_bf16<<<NN * CC / (256 * 8), blk, 0, stream>>>(x, x_bf);
    conv_transpose_bf16<<<dim3(CHALF / 64, CC / 64), blk, 0, stream>>>(imp_w1, imp_w1t, CC, CHALF);
    conv_transpose_bf16<<<dim3(CC / 64, CC / 64), blk, 0, stream>>>(rsn_w1, rsn_w1t, CC, CC);
    conv_transpose_bf16<<<dim3(CC / 64, CC / 64), blk, 0, stream>>>(rsn_w2, rsn_w2t, CC, CC);
    conv_transpose_bf16<<<dim3(CC / 64, CC / 64), blk, 0, stream>>>(q_w, q_wt, CC, CC);
    conv_transpose_bf16<<<dim3(CC / 64, CC / 64), blk, 0, stream>>>(k_w, k_wt, CC, CC);
    conv_transpose_bf16<<<dim3(CC / 64, CC / 64), blk, 0, stream>>>(v_w, v_wt, CC, CC);
    conv_transpose_bf16<<<dim3(CC / 64, CC / 64), blk, 0, stream>>>(o_w, o_wt, CC, CC);
    // mask tile flags (independent)
    mask_flags<<<dim3(32, 32, 2), blk, 0, stream>>>(mask, flg);

    // importance net
    gemm_mfma<false><<<dim3(CHALF / 128, NN / 128), blk, 0, stream>>>(
        (const short*)x_bf, (const short*)imp_w1t, imp_b1, h1, nullptr, NN, CHALF, CC);
    ln_gelu_kernel<CHALF><<<NN, blk, 0, stream>>>(h1, imp_g, imp_beta);
    imp_scale<<<NN, blk, 0, stream>>>(h1, imp_w2, imp_b2, x, xi_bf);
    // reasoning net
    gemm_mfma<false><<<dim3(CC / 128, NN / 128), blk, 0, stream>>>(
        (const short*)xi_bf, (const short*)rsn_w1t, rsn_b1, h2, nullptr, NN, CC, CC);
    ln_gelu_bf16<CC><<<NN, blk, 0, stream>>>(h2, rsn_g, rsn_beta, h2b);
    gemm_mfma<true><<<dim3(CC / 128, NN / 128), blk, 0, stream>>>(
        (const short*)h2b, (const short*)rsn_w2t, rsn_b2, nullptr, rs_bf, NN, CC, CC);
    // q projection + temperature net
    gemm_mfma<true><<<dim3(CC / 128, NN / 128), blk, 0, stream>>>(
        (const short*)rs_bf, (const short*)q_wt, q_b, nullptr, qb, NN, CC, CC);
    mean_part<<<128, blk, 0, stream>>>(rs_bf, part);
    mean_fin<<<8, blk, 0, stream>>>(part, rm);
    temp_net<<<BB, dim3(512), 0, stream>>>(rm, tmp_w1, tmp_b1, tmp_g, tmp_beta, tmp_w2, tmp_b2, tmp);
    // k, v projections
    gemm_mfma<true><<<dim3(CC / 128, NN / 128), blk, 0, stream>>>(
        (const short*)xi_bf, (const short*)k_wt, k_b, nullptr, kb, NN, CC, CC);
    gemm_mfma<true><<<dim3(CC / 128, NN / 128), blk, 0, stream>>>(
        (const short*)x_bf, (const short*)v_wt, v_b, nullptr, vb, NN, CC, CC);
    // flash attention v2 (128-row q-tiles)
    flash_attn_mfma<<<dim3(TT / 128, BB * HH), blk, 0, stream>>>(
        (const short*)qb, (const short*)kb, (const short*)vb, mask, flg, tmp, rs_bf);
    // output projection (fp32 into h2, free now) + residual LN
    gemm_mfma<false><<<dim3(CC / 128, NN / 128), blk, 0, stream>>>(
        (const short*)rs_bf, (const short*)o_wt, o_b, h2, nullptr, NN, CC, CC);
    final_ln<<<NN, blk, 0, stream>>>(x, h2, norm_g, norm_b, out);
}

// Round 5
// 513.570 us; speedup vs baseline: 3.6866x; 1.0757x over previous
//
#include <hip/hip_runtime.h>
#include <hip/hip_bf16.h>
#include <math.h>

// Problem constants
#define BB 2
#define TT 2048
#define CC 1024
#define HH 16
#define DD 64
#define CHALF 512
#define NN (BB * TT)   // 4096 rows

typedef __attribute__((ext_vector_type(8))) short short8;
typedef __attribute__((ext_vector_type(4))) short short4_t;
typedef __attribute__((ext_vector_type(4))) float f32x4;

__device__ __forceinline__ float gelu_exact(float x) {
    return 0.5f * x * (1.0f + erff(x * 0.70710678118654752f));
}

__device__ __forceinline__ short f2bf(float f) {
    __hip_bfloat16 h = __float2bfloat16(f);
    short s;
    __builtin_memcpy(&s, &h, 2);
    return s;
}

// async global->LDS, 16 B per lane; LDS dst must be wave-uniform base
__device__ __forceinline__ void async_copy16(const void* g, void* l) {
    __builtin_amdgcn_global_load_lds(
        (const __attribute__((address_space(1))) void*)g,
        (__attribute__((address_space(3))) void*)l, 16, 0, 0);
}

// ---------------------------------------------------------------------------
// fp32 -> bf16 elementwise convert (x)
// ---------------------------------------------------------------------------
__global__ __launch_bounds__(256) void conv_bf16(
    const float* __restrict__ X, __hip_bfloat16* __restrict__ O) {
    int i = (blockIdx.x * 256 + threadIdx.x) * 8;
    float4 a = *(const float4*)&X[i];
    float4 b = *(const float4*)&X[i + 4];
    __hip_bfloat16 o[8] = {
        __float2bfloat16(a.x), __float2bfloat16(a.y),
        __float2bfloat16(a.z), __float2bfloat16(a.w),
        __float2bfloat16(b.x), __float2bfloat16(b.y),
        __float2bfloat16(b.z), __float2bfloat16(b.w)};
    *(float4*)&O[i] = *(float4*)o;
}

// ---------------------------------------------------------------------------
// All 7 weight transposes in ONE launch: W [1024,N] fp32 -> Wt [N,1024] bf16
// z selects the weight; z=0 (imp_w1) has N=512, others N=1024.
// ---------------------------------------------------------------------------
__global__ __launch_bounds__(256) void conv_transpose_all(
    const float* w0, const float* w1, const float* w2, const float* w3,
    const float* w4, const float* w5, const float* w6,
    __hip_bfloat16* t0, __hip_bfloat16* t1, __hip_bfloat16* t2,
    __hip_bfloat16* t3, __hip_bfloat16* t4, __hip_bfloat16* t5,
    __hip_bfloat16* t6) {
    const float* W;
    __hip_bfloat16* Wt;
    int N = 1024;
    switch (blockIdx.z) {
        case 0: W = w0; Wt = t0; N = 512; break;
        case 1: W = w1; Wt = t1; break;
        case 2: W = w2; Wt = t2; break;
        case 3: W = w3; Wt = t3; break;
        case 4: W = w4; Wt = t4; break;
        case 5: W = w5; Wt = t5; break;
        default: W = w6; Wt = t6; break;
    }
    int n0 = blockIdx.x * 64, k0 = blockIdx.y * 64;
    if (n0 >= N) return;
    __shared__ float T[64][65];
    int tid = threadIdx.x;
    int c = tid & 63, r4 = tid >> 6;
#pragma unroll
    for (int i = 0; i < 16; ++i) {
        int row = i * 4 + r4;
        T[row][c] = W[(size_t)(k0 + row) * N + n0 + c];
    }
    __syncthreads();
#pragma unroll
    for (int i = 0; i < 16; ++i) {
        int row = i * 4 + r4;  // n index
        Wt[(size_t)(n0 + row) * CC + k0 + c] = __float2bfloat16(T[c][row]);
    }
}

// ---------------------------------------------------------------------------
// bf16 MFMA GEMM: C[M,N] = A[M,K](bf16) @ Wt[N,K](bf16)^T + bias
// ---------------------------------------------------------------------------
template <bool BF16OUT>
__global__ __launch_bounds__(256) void gemm_mfma(
    const short* __restrict__ A, const short* __restrict__ Wt,
    const float* __restrict__ bias, float* __restrict__ Cf,
    __hip_bfloat16* __restrict__ Cb, int M, int N, int K) {
    __shared__ short As[128][32];
    __shared__ short Bs[128][32];
    int tid = threadIdx.x;
    int wave = tid >> 6, lane = tid & 63;
    int m16 = lane & 15, quad = lane >> 4;
    int wm = wave >> 1, wn = wave & 1;
    int row0 = blockIdx.y * 128, col0 = blockIdx.x * 128;
    int lr = lane >> 2;
    int kof = (lane & 3) * 8;

    f32x4 acc[4][4];
#pragma unroll
    for (int i = 0; i < 4; ++i)
#pragma unroll
        for (int j = 0; j < 4; ++j) acc[i][j] = (f32x4){0.f, 0.f, 0.f, 0.f};

    for (int k0 = 0; k0 < K; k0 += 32) {
#pragma unroll
        for (int j = 0; j < 2; ++j) {
            int rbase = wave * 32 + j * 16;
            async_copy16(A + (size_t)(row0 + rbase + lr) * K + k0 + kof,
                         &As[rbase][0]);
            async_copy16(Wt + (size_t)(col0 + rbase + lr) * K + k0 + kof,
                         &Bs[rbase][0]);
        }
        __syncthreads();
        short8 af[4], bfr[4];
#pragma unroll
        for (int i = 0; i < 4; ++i)
            af[i] = *(const short8*)&As[wm * 64 + i * 16 + m16][quad * 8];
#pragma unroll
        for (int j = 0; j < 4; ++j)
            bfr[j] = *(const short8*)&Bs[wn * 64 + j * 16 + m16][quad * 8];
#pragma unroll
        for (int i = 0; i < 4; ++i)
#pragma unroll
            for (int j = 0; j < 4; ++j)
                acc[i][j] = __builtin_amdgcn_mfma_f32_16x16x32_bf16(
                    af[i], bfr[j], acc[i][j], 0, 0, 0);
        __syncthreads();
    }
#pragma unroll
    for (int i = 0; i < 4; ++i) {
#pragma unroll
        for (int j = 0; j < 4; ++j) {
            int col = col0 + wn * 64 + j * 16 + m16;
            float bv = bias[col];
#pragma unroll
            for (int rr = 0; rr < 4; ++rr) {
                int row = row0 + wm * 64 + i * 16 + quad * 4 + rr;
                float val = acc[i][j][rr] + bv;
                if (BF16OUT)
                    Cb[(size_t)row * N + col] = __float2bfloat16(val);
                else
                    Cf[(size_t)row * N + col] = val;
            }
        }
    }
}

// ---------------------------------------------------------------------------
// Batched q/k/v projection GEMMs (grid.z selects). All M=4096,N=1024,K=1024.
// z=0: q = rs@q_w + q_b, scaled by temp[b,h]/8 (folded attention scale)
// z=1: k = xi@k_w + k_b      z=2: v = x@v_w + v_b
// ---------------------------------------------------------------------------
__global__ __launch_bounds__(256) void gemm_qkv(
    const short* __restrict__ Aq, const short* __restrict__ Ak,
    const short* __restrict__ Av, const short* __restrict__ Wq,
    const short* __restrict__ Wk, const short* __restrict__ Wv,
    const float* __restrict__ bq, const float* __restrict__ bk,
    const float* __restrict__ bv, __hip_bfloat16* __restrict__ Cq,
    __hip_bfloat16* __restrict__ Ck, __hip_bfloat16* __restrict__ Cv,
    const float* __restrict__ tmp) {
    int z = blockIdx.z;
    const short* A = (z == 0) ? Aq : (z == 1) ? Ak : Av;
    const short* Wt = (z == 0) ? Wq : (z == 1) ? Wk : Wv;
    const float* bias = (z == 0) ? bq : (z == 1) ? bk : bv;
    __hip_bfloat16* C = (z == 0) ? Cq : (z == 1) ? Ck : Cv;

    __shared__ short As[128][32];
    __shared__ short Bs[128][32];
    int tid = threadIdx.x;
    int wave = tid >> 6, lane = tid & 63;
    int m16 = lane & 15, quad = lane >> 4;
    int wm = wave >> 1, wn = wave & 1;
    int row0 = blockIdx.y * 128, col0 = blockIdx.x * 128;
    int lr = lane >> 2;
    int kof = (lane & 3) * 8;

    // q-scale: temp[b, head]*0.125; head = col0/64 + wn (uniform per wave)
    float scale = 1.0f;
    if (z == 0) scale = tmp[(row0 >> 11) * HH + (col0 >> 6) + wn] * 0.125f;

    f32x4 acc[4][4];
#pragma unroll
    for (int i = 0; i < 4; ++i)
#pragma unroll
        for (int j = 0; j < 4; ++j) acc[i][j] = (f32x4){0.f, 0.f, 0.f, 0.f};

    for (int k0 = 0; k0 < CC; k0 += 32) {
#pragma unroll
        for (int j = 0; j < 2; ++j) {
            int rbase = wave * 32 + j * 16;
            async_copy16(A + (size_t)(row0 + rbase + lr) * CC + k0 + kof,
                         &As[rbase][0]);
            async_copy16(Wt + (size_t)(col0 + rbase + lr) * CC + k0 + kof,
                         &Bs[rbase][0]);
        }
        __syncthreads();
        short8 af[4], bfr[4];
#pragma unroll
        for (int i = 0; i < 4; ++i)
            af[i] = *(const short8*)&As[wm * 64 + i * 16 + m16][quad * 8];
#pragma unroll
        for (int j = 0; j < 4; ++j)
            bfr[j] = *(const short8*)&Bs[wn * 64 + j * 16 + m16][quad * 8];
#pragma unroll
        for (int i = 0; i < 4; ++i)
#pragma unroll
            for (int j = 0; j < 4; ++j)
                acc[i][j] = __builtin_amdgcn_mfma_f32_16x16x32_bf16(
                    af[i], bfr[j], acc[i][j], 0, 0, 0);
        __syncthreads();
    }
#pragma unroll
    for (int i = 0; i < 4; ++i) {
#pragma unroll
        for (int j = 0; j < 4; ++j) {
            int col = col0 + wn * 64 + j * 16 + m16;
            float bv2 = bias[col];
#pragma unroll
            for (int rr = 0; rr < 4; ++rr) {
                int row = row0 + wm * 64 + i * 16 + quad * 4 + rr;
                C[(size_t)row * CC + col] =
                    __float2bfloat16((acc[i][j][rr] + bv2) * scale);
            }
        }
    }
}

// ---------------------------------------------------------------------------
// Row-wise LayerNorm + exact GELU, in place (fp32, for h1)
// ---------------------------------------------------------------------------
template <int WIDTH>
__global__ __launch_bounds__(256) void ln_gelu_kernel(
    float* __restrict__ Y, const float* __restrict__ g,
    const float* __restrict__ beta) {
    constexpr int PT = WIDTH / 256;
    int row = blockIdx.x;
    int tid = threadIdx.x;
    float* yr = Y + (size_t)row * WIDTH;
    float v[PT];
    float s = 0.f;
#pragma unroll
    for (int i = 0; i < PT; ++i) {
        v[i] = yr[i * 256 + tid];
        s += v[i];
    }
    __shared__ float red[256];
    red[tid] = s;
    __syncthreads();
#pragma unroll
    for (int o = 128; o > 0; o >>= 1) {
        if (tid < o) red[tid] += red[tid + o];
        __syncthreads();
    }
    float mean = red[0] * (1.0f / WIDTH);
    __syncthreads();
    s = 0.f;
#pragma unroll
    for (int i = 0; i < PT; ++i) {
        float d = v[i] - mean;
        s += d * d;
    }
    red[tid] = s;
    __syncthreads();
#pragma unroll
    for (int o = 128; o > 0; o >>= 1) {
        if (tid < o) red[tid] += red[tid + o];
        __syncthreads();
    }
    float inv = rsqrtf(red[0] * (1.0f / WIDTH) + 1e-5f);
#pragma unroll
    for (int i = 0; i < PT; ++i) {
        int c = i * 256 + tid;
        yr[c] = gelu_exact((v[i] - mean) * inv * g[c] + beta[c]);
    }
}

// Same, fp32 in, bf16 out-of-place
template <int WIDTH>
__global__ __launch_bounds__(256) void ln_gelu_bf16(
    const float* __restrict__ Y, const float* __restrict__ g,
    const float* __restrict__ beta, __hip_bfloat16* __restrict__ O) {
    constexpr int PT = WIDTH / 256;
    int row = blockIdx.x;
    int tid = threadIdx.x;
    const float* yr = Y + (size_t)row * WIDTH;
    float v[PT];
    float s = 0.f;
#pragma unroll
    for (int i = 0; i < PT; ++i) {
        v[i] = yr[i * 256 + tid];
        s += v[i];
    }
    __shared__ float red[256];
    red[tid] = s;
    __syncthreads();
#pragma unroll
    for (int o = 128; o > 0; o >>= 1) {
        if (tid < o) red[tid] += red[tid + o];
        __syncthreads();
    }
    float mean = red[0] * (1.0f / WIDTH);
    __syncthreads();
    s = 0.f;
#pragma unroll
    for (int i = 0; i < PT; ++i) {
        float d = v[i] - mean;
        s += d * d;
    }
    red[tid] = s;
    __syncthreads();
#pragma unroll
    for (int o = 128; o > 0; o >>= 1) {
        if (tid < o) red[tid] += red[tid + o];
        __syncthreads();
    }
    float inv = rsqrtf(red[0] * (1.0f / WIDTH) + 1e-5f);
#pragma unroll
    for (int i = 0; i < PT; ++i) {
        int c = i * 256 + tid;
        O[(size_t)row * WIDTH + c] =
            __float2bfloat16(gelu_exact((v[i] - mean) * inv * g[c] + beta[c]));
    }
}

// ---------------------------------------------------------------------------
// importance gate: xi(bf16) = x * clamp(sigmoid(h1 . w2 + b2), 1e-6)
// ---------------------------------------------------------------------------
__global__ __launch_bounds__(256) void imp_scale(
    const float* __restrict__ h1, const float* __restrict__ w2,
    const float* __restrict__ b2, const float* __restrict__ x,
    __hip_bfloat16* __restrict__ xi) {
    int row = blockIdx.x;
    int tid = threadIdx.x;
    const float* hr = h1 + (size_t)row * CHALF;
    float s = hr[tid] * w2[tid] + hr[tid + 256] * w2[tid + 256];
    __shared__ float red[256];
    red[tid] = s;
    __syncthreads();
#pragma unroll
    for (int o = 128; o > 0; o >>= 1) {
        if (tid < o) red[tid] += red[tid + o];
        __syncthreads();
    }
    float z = red[0] + b2[0];
    float sg = 1.0f / (1.0f + expf(-z));
    float imp = fmaxf(sg, 1e-6f);
#pragma unroll
    for (int i = 0; i < 4; ++i) {
        int c = i * 256 + tid;
        xi[(size_t)row * CC + c] =
            __float2bfloat16(x[(size_t)row * CC + c] * imp);
    }
}

// ---------------------------------------------------------------------------
// reasoned.mean(axis=1), reading bf16 reasoned
// ---------------------------------------------------------------------------
__global__ __launch_bounds__(256) void mean_part(
    const __hip_bfloat16* __restrict__ R, float* __restrict__ part) {
    int idx = blockIdx.x * 256 + threadIdx.x;
    int c = idx & (CC - 1);
    int chunk = (idx >> 10) & 15;
    int b = idx >> 14;
    const __hip_bfloat16* base = R + ((size_t)(b * TT + chunk * 128)) * CC + c;
    float s = 0.f;
    for (int t = 0; t < 128; ++t) s += __bfloat162float(base[(size_t)t * CC]);
    part[idx] = s;
}

__global__ __launch_bounds__(256) void mean_fin(
    const float* __restrict__ part, float* __restrict__ rm) {
    int idx = blockIdx.x * 256 + threadIdx.x;
    int c = idx & (CC - 1);
    int b = idx >> 10;
    float s = 0.f;
#pragma unroll
    for (int ch = 0; ch < 16; ++ch) s += part[(size_t)(b * 16 + ch) * CC + c];
    rm[idx] = s * (1.0f / TT);
}

// ---------------------------------------------------------------------------
// temp_net
// ---------------------------------------------------------------------------
__global__ __launch_bounds__(512) void temp_net(
    const float* __restrict__ rm, const float* __restrict__ w1,
    const float* __restrict__ b1, const float* __restrict__ g,
    const float* __restrict__ beta, const float* __restrict__ w2,
    const float* __restrict__ b2, float* __restrict__ temp) {
    __shared__ float xr[CC];
    __shared__ float ht[CHALF];
    __shared__ float red[512];
    int b = blockIdx.x;
    int tid = threadIdx.x;
    xr[tid] = rm[b * CC + tid];
    xr[tid + 512] = rm[b * CC + tid + 512];
    __syncthreads();
    float acc = b1[tid];
#pragma unroll 8
    for (int i = 0; i < CC; ++i) acc = fmaf(xr[i], w1[(size_t)i * CHALF + tid], acc);
    red[tid] = acc;
    __syncthreads();
#pragma unroll
    for (int o = 256; o > 0; o >>= 1) {
        if (tid < o) red[tid] += red[tid + o];
        __syncthreads();
    }
    float mean = red[0] * (1.0f / CHALF);
    __syncthreads();
    float d = acc - mean;
    red[tid] = d * d;
    __syncthreads();
#pragma unroll
    for (int o = 256; o > 0; o >>= 1) {
        if (tid < o) red[tid] += red[tid + o];
        __syncthreads();
    }
    float inv = rsqrtf(red[0] * (1.0f / CHALF) + 1e-5f);
    ht[tid] = gelu_exact((acc - mean) * inv * g[tid] + beta[tid]);
    __syncthreads();
    if (tid < HH) {
        float s = b2[tid];
        for (int i = 0; i < CHALF; ++i) s = fmaf(ht[i], w2[i * HH + tid], s);
        float sp = fmaxf(s, 0.f) + log1pf(expf(-fabsf(s)));
        temp[b * HH + tid] = sp + 0.5f;
    }
}

// ---------------------------------------------------------------------------
// mask tile flags (64x64 tiles)
// ---------------------------------------------------------------------------
__global__ __launch_bounds__(256) void mask_flags(
    const int* __restrict__ mask, int* __restrict__ flags) {
    int kt = blockIdx.x, qt = blockIdx.y, b = blockIdx.z;
    int tid = threadIdx.x;
    int r = tid >> 2;
    int c0 = (tid & 3) * 16;
    const int* base = mask + ((size_t)(b * TT + qt * 64 + r)) * TT + kt * 64 + c0;
    int all = 1;
#pragma unroll
    for (int i = 0; i < 4; ++i) {
        int4 m4 = *(const int4*)(base + i * 4);
        all &= (m4.x != 0) & (m4.y != 0) & (m4.z != 0) & (m4.w != 0);
    }
    __shared__ int red[256];
    red[tid] = all;
    __syncthreads();
#pragma unroll
    for (int o = 128; o > 0; o >>= 1) {
        if (tid < o) red[tid] &= red[tid + o];
        __syncthreads();
    }
    if (tid == 0) flags[(b * 32 + qt) * 32 + kt] = red[0];
}

// ---------------------------------------------------------------------------
// V global transpose: vb[b*T+t][h*64+d] -> vt[(b*16+h)*64+d][t]
// One-time 8 MB pass; removes the per-iter in-flash transpose.
// ---------------------------------------------------------------------------
__global__ __launch_bounds__(256) void transpose_v(
    const short* __restrict__ vb, short* __restrict__ vt) {
    __shared__ short T[64][72];  // [t][d]
    int t0 = blockIdx.x * 64;
    int bh = blockIdx.y;
    int b = bh >> 4, h = bh & 15;
    int tid = threadIdx.x;
#pragma unroll
    for (int p = 0; p < 2; ++p) {
        int idx = p * 256 + tid;
        int r = idx >> 3, c = (idx & 7) * 8;
        *(short8*)&T[r][c] =
            *(const short8*)&vb[(size_t)(b * TT + t0 + r) * CC + h * DD + c];
    }
    __syncthreads();
#pragma unroll
    for (int p = 0; p < 2; ++p) {
        int idx = p * 256 + tid;
        int d = idx >> 3, c = (idx & 7) * 8;
        short8 o;
#pragma unroll
        for (int u = 0; u < 8; ++u) o[u] = T[c + u][d];
        *(short8*)&vt[((size_t)bh * DD + d) * TT + t0 + c] = o;
    }
}

// ---------------------------------------------------------------------------
// MFMA flash attention v3 (q pre-scaled by temp/8; V pre-transposed).
// Block: 256 thr = 4 waves; 128-row q-tile.
// S^T = mfma(A=K, B=Q): lane holds (key=quad*4+r, q=m16).
// ---------------------------------------------------------------------------
__global__ __launch_bounds__(256) void flash_attn_mfma(
    const short* __restrict__ q, const short* __restrict__ k,
    const short* __restrict__ vt, const int* __restrict__ mask,
    const int* __restrict__ flags, __hip_bfloat16* __restrict__ out) {
    __shared__ short Ks[64][72];    // [key][d]
    __shared__ short Vt[64][72];    // [d][key]
    __shared__ short Ps[128][72];   // [q-row][key], wave-private strips
    int tid = threadIdx.x;
    int wave = tid >> 6, lane = tid & 63;
    int m16 = lane & 15, quad = lane >> 4;
    int qt = blockIdx.x;
    int q0 = qt * 128;
    int bh = blockIdx.y;
    int b = bh >> 4, h = bh & 15;

    short8 qf[2][2];
#pragma unroll
    for (int qg = 0; qg < 2; ++qg) {
        const short* qrow = q + ((size_t)(b * TT + q0 + wave * 32 + qg * 16 + m16)) * CC +
                            h * DD + quad * 8;
        qf[qg][0] = *(const short8*)(qrow);
        qf[qg][1] = *(const short8*)(qrow + 32);
    }

    float m_run[2] = {-INFINITY, -INFINITY};
    float l_run[2] = {0.f, 0.f};
    f32x4 acc_o[2][4];
#pragma unroll
    for (int qg = 0; qg < 2; ++qg)
#pragma unroll
        for (int t = 0; t < 4; ++t) acc_o[qg][t] = (f32x4){0.f, 0.f, 0.f, 0.f};

    for (int kt = 0; kt < TT / 64; ++kt) {
        int kb = kt * 64;
        // stage K rows and Vt rows (both coalesced b128)
#pragma unroll
        for (int i = 0; i < 2; ++i) {
            int idx = i * 256 + tid;
            int r = idx >> 3;
            int dc = (idx & 7) * 8;
            *(short8*)&Ks[r][dc] =
                *(const short8*)(k + ((size_t)(b * TT + kb + r)) * CC + h * DD + dc);
            *(short8*)&Vt[r][dc] =
                *(const short8*)(vt + ((size_t)bh * DD + r) * TT + kb + dc);
        }
        __syncthreads();

        short8 kf[4][2];
#pragma unroll
        for (int t = 0; t < 4; ++t) {
            kf[t][0] = *(const short8*)&Ks[t * 16 + m16][quad * 8];
            kf[t][1] = *(const short8*)&Ks[t * 16 + m16][32 + quad * 8];
        }
        int fl = flags[(b * 32 + 2 * qt + (wave >> 1)) * 32 + kt];

#pragma unroll
        for (int qg = 0; qg < 2; ++qg) {
            f32x4 sacc[4];
#pragma unroll
            for (int t = 0; t < 4; ++t) sacc[t] = (f32x4){0.f, 0.f, 0.f, 0.f};
#pragma unroll
            for (int t = 0; t < 4; ++t) {
                sacc[t] = __builtin_amdgcn_mfma_f32_16x16x32_bf16(kf[t][0], qf[qg][0], sacc[t], 0, 0, 0);
                sacc[t] = __builtin_amdgcn_mfma_f32_16x16x32_bf16(kf[t][1], qf[qg][1], sacc[t], 0, 0, 0);
            }
            float sv[4][4];
#pragma unroll
            for (int t = 0; t < 4; ++t)
#pragma unroll
                for (int r = 0; r < 4; ++r) sv[t][r] = sacc[t][r];
            if (fl == 0) {
                int qrow = q0 + wave * 32 + qg * 16 + m16;
#pragma unroll
                for (int t = 0; t < 4; ++t)
#pragma unroll
                    for (int r = 0; r < 4; ++r) {
                        int kg = kb + t * 16 + quad * 4 + r;
                        if (mask[((size_t)(b * TT + qrow)) * TT + kg] == 0)
                            sv[t][r] = -INFINITY;
                    }
            }
            float mx = sv[0][0];
#pragma unroll
            for (int t = 0; t < 4; ++t)
#pragma unroll
                for (int r = 0; r < 4; ++r) mx = fmaxf(mx, sv[t][r]);
            mx = fmaxf(mx, __shfl_xor(mx, 16, 64));
            mx = fmaxf(mx, __shfl_xor(mx, 32, 64));
            float mnew = fmaxf(m_run[qg], mx);
            float alpha = __expf(m_run[qg] - mnew);
            m_run[qg] = mnew;
            int prow = wave * 32 + qg * 16 + m16;
            float psum = 0.f;
#pragma unroll
            for (int t = 0; t < 4; ++t) {
                short4_t pk;
#pragma unroll
                for (int r = 0; r < 4; ++r) {
                    float p = __expf(sv[t][r] - mnew);
                    psum += p;
                    pk[r] = f2bf(p);
                }
                *(short4_t*)&Ps[prow][t * 16 + quad * 4] = pk;
            }
            psum += __shfl_xor(psum, 16, 64);
            psum += __shfl_xor(psum, 32, 64);
            l_run[qg] = l_run[qg] * alpha + psum;
#pragma unroll
            for (int r = 0; r < 4; ++r) {
                float ar = __shfl(alpha, (lane & 48) | (quad * 4 + r), 64);
#pragma unroll
                for (int td = 0; td < 4; ++td) acc_o[qg][td][r] *= ar;
            }
        }

#pragma unroll
        for (int kc = 0; kc < 2; ++kc) {
            short8 vf[4];
#pragma unroll
            for (int td = 0; td < 4; ++td)
                vf[td] = *(const short8*)&Vt[td * 16 + m16][kc * 32 + quad * 8];
#pragma unroll
            for (int qg = 0; qg < 2; ++qg) {
                short8 pf = *(const short8*)&Ps[wave * 32 + qg * 16 + m16][kc * 32 + quad * 8];
#pragma unroll
                for (int td = 0; td < 4; ++td)
                    acc_o[qg][td] = __builtin_amdgcn_mfma_f32_16x16x32_bf16(
                        pf, vf[td], acc_o[qg][td], 0, 0, 0);
            }
        }
        __syncthreads();
    }

#pragma unroll
    for (int qg = 0; qg < 2; ++qg) {
#pragma unroll
        for (int r = 0; r < 4; ++r) {
            float lr = __shfl(l_run[qg], (lane & 48) | (quad * 4 + r), 64);
            float inv = 1.0f / lr;
            int row = b * TT + q0 + wave * 32 + qg * 16 + quad * 4 + r;
#pragma unroll
            for (int td = 0; td < 4; ++td)
                out[(size_t)row * CC + h * DD + td * 16 + m16] =
                    __float2bfloat16(acc_o[qg][td][r] * inv);
        }
    }
}

// ---------------------------------------------------------------------------
// Final: out = LN(x + proj)
// ---------------------------------------------------------------------------
__global__ __launch_bounds__(256) void final_ln(
    const float* __restrict__ x, const float* __restrict__ p,
    const float* __restrict__ g, const float* __restrict__ beta,
    float* __restrict__ out) {
    int row = blockIdx.x;
    int tid = threadIdx.x;
    const float* xr = x + (size_t)row * CC;
    const float* pr = p + (size_t)row * CC;
    float v[4];
    float s = 0.f;
#pragma unroll
    for (int i = 0; i < 4; ++i) {
        int c = i * 256 + tid;
        v[i] = xr[c] + pr[c];
        s += v[i];
    }
    __shared__ float red[256];
    red[tid] = s;
    __syncthreads();
#pragma unroll
    for (int o = 128; o > 0; o >>= 1) {
        if (tid < o) red[tid] += red[tid + o];
        __syncthreads();
    }
    float mean = red[0] * (1.0f / CC);
    __syncthreads();
    s = 0.f;
#pragma unroll
    for (int i = 0; i < 4; ++i) {
        float d = v[i] - mean;
        s += d * d;
    }
    red[tid] = s;
    __syncthreads();
#pragma unroll
    for (int o = 128; o > 0; o >>= 1) {
        if (tid < o) red[tid] += red[tid + o];
        __syncthreads();
    }
    float inv = rsqrtf(red[0] * (1.0f / CC) + 1e-5f);
#pragma unroll
    for (int i = 0; i < 4; ++i) {
        int c = i * 256 + tid;
        out[(size_t)row * CC + c] = (v[i] - mean) * inv * g[c] + beta[c];
    }
}

extern "C" void kernel_launch(void* const* d_in, const int* in_sizes, int n_in,
                              void* d_out, int out_size, void* d_ws,
                              size_t ws_size, hipStream_t stream) {
    const float* x        = (const float*)d_in[0];
    const int*   mask     = (const int*)d_in[1];
    const float* imp_w1   = (const float*)d_in[2];
    const float* imp_b1   = (const float*)d_in[3];
    const float* imp_g    = (const float*)d_in[4];
    const float* imp_beta = (const float*)d_in[5];
    const float* imp_w2   = (const float*)d_in[6];
    const float* imp_b2   = (const float*)d_in[7];
    const float* rsn_w1   = (const float*)d_in[8];
    const float* rsn_b1   = (const float*)d_in[9];
    const float* rsn_g    = (const float*)d_in[10];
    const float* rsn_beta = (const float*)d_in[11];
    const float* rsn_w2   = (const float*)d_in[12];
    const float* rsn_b2   = (const float*)d_in[13];
    const float* q_w      = (const float*)d_in[14];
    const float* q_b      = (const float*)d_in[15];
    const float* k_w      = (const float*)d_in[16];
    const float* k_b      = (const float*)d_in[17];
    const float* v_w      = (const float*)d_in[18];
    const float* v_b      = (const float*)d_in[19];
    const float* o_w      = (const float*)d_in[20];
    const float* o_b      = (const float*)d_in[21];
    const float* tmp_w1   = (const float*)d_in[22];
    const float* tmp_b1   = (const float*)d_in[23];
    const float* tmp_g    = (const float*)d_in[24];
    const float* tmp_beta = (const float*)d_in[25];
    const float* tmp_w2   = (const float*)d_in[26];
    const float* tmp_b2   = (const float*)d_in[27];
    const float* norm_g   = (const float*)d_in[28];
    const float* norm_b   = (const float*)d_in[29];
    float* out = (float*)d_out;
    float* ws  = (float*)d_ws;

    // workspace layout (float offsets)
    float* h1  = ws;                       // [4096,512] fp32
    float* h2  = ws + 2097152;             // [4096,1024] fp32 (later o-proj out)
    __hip_bfloat16* x_bf  = (__hip_bfloat16*)(ws + 6291456);
    __hip_bfloat16* xi_bf = (__hip_bfloat16*)(ws + 8388608);
    __hip_bfloat16* h2b   = (__hip_bfloat16*)(ws + 10485760);
    __hip_bfloat16* rs_bf = (__hip_bfloat16*)(ws + 12582912);  // reasoned, later attn out
    __hip_bfloat16* qb    = (__hip_bfloat16*)(ws + 14680064);
    __hip_bfloat16* kb    = (__hip_bfloat16*)(ws + 16777216);
    __hip_bfloat16* vb    = (__hip_bfloat16*)(ws + 18874368);
    __hip_bfloat16* vtb   = (__hip_bfloat16*)(ws + 20971520);  // [32,64,2048]
    __hip_bfloat16* imp_w1t = (__hip_bfloat16*)(ws + 23068672);  // [512,1024]
    __hip_bfloat16* rsn_w1t = (__hip_bfloat16*)(ws + 23330816);  // [1024,1024]
    __hip_bfloat16* rsn_w2t = (__hip_bfloat16*)(ws + 23855104);
    __hip_bfloat16* q_wt    = (__hip_bfloat16*)(ws + 24379392);
    __hip_bfloat16* k_wt    = (__hip_bfloat16*)(ws + 24903680);
    __hip_bfloat16* v_wt    = (__hip_bfloat16*)(ws + 25427968);
    __hip_bfloat16* o_wt    = (__hip_bfloat16*)(ws + 25952256);
    float* rm   = ws + 26476544;   // [2,1024]
    float* tmp  = ws + 26478592;   // [2,16]
    float* part = ws + 26479104;   // [2,16,1024]
    int*   flg  = (int*)(ws + 26511872);  // [2,32,32]

    dim3 blk(256);
    // converts: x -> bf16; all 7 weights -> bf16 transposed [N,K] in one launch
    conv_bf16<<<NN * CC / (256 * 8), blk, 0, stream>>>(x, x_bf);
    conv_transpose_all<<<dim3(16, 16, 7), blk, 0, stream>>>(
        imp_w1, rsn_w1, rsn_w2, q_w, k_w, v_w, o_w,
        imp_w1t, rsn_w1t, rsn_w2t, q_wt, k_wt, v_wt, o_wt);
    // mask tile flags (independent)
    mask_flags<<<dim3(32, 32, 2), blk, 0, stream>>>(mask, flg);

    // importance net
    gemm_mfma<false><<<dim3(CHALF / 128, NN / 128), blk, 0, stream>>>(
        (const short*)x_bf, (const short*)imp_w1t, imp_b1, h1, nullptr, NN, CHALF, CC);
    ln_gelu_kernel<CHALF><<<NN, blk, 0, stream>>>(h1, imp_g, imp_beta);
    imp_scale<<<NN, blk, 0, stream>>>(h1, imp_w2, imp_b2, x, xi_bf);
    // reasoning net
    gemm_mfma<false><<<dim3(CC / 128, NN / 128), blk, 0, stream>>>(
        (const short*)xi_bf, (const short*)rsn_w1t, rsn_b1, h2, nullptr, NN, CC, CC);
    ln_gelu_bf16<CC><<<NN, blk, 0, stream>>>(h2, rsn_g, rsn_beta, h2b);
    gemm_mfma<true><<<dim3(CC / 128, NN / 128), blk, 0, stream>>>(
        (const short*)h2b, (const short*)rsn_w2t, rsn_b2, nullptr, rs_bf, NN, CC, CC);
    // temperature net (before q projection so temp folds into its epilogue)
    mean_part<<<128, blk, 0, stream>>>(rs_bf, part);
    mean_fin<<<8, blk, 0, stream>>>(part, rm);
    temp_net<<<BB, dim3(512), 0, stream>>>(rm, tmp_w1, tmp_b1, tmp_g, tmp_beta, tmp_w2, tmp_b2, tmp);
    // q/k/v projections batched (768 blocks = 3/CU); q scaled by temp/8
    gemm_qkv<<<dim3(CC / 128, NN / 128, 3), blk, 0, stream>>>(
        (const short*)rs_bf, (const short*)xi_bf, (const short*)x_bf,
        (const short*)q_wt, (const short*)k_wt, (const short*)v_wt,
        q_b, k_b, v_b, qb, kb, vb, tmp);
    // V transpose for flash B-operand staging
    transpose_v<<<dim3(TT / 64, BB * HH), blk, 0, stream>>>(
        (const short*)vb, (short*)vtb);
    // flash attention v3
    flash_attn_mfma<<<dim3(TT / 128, BB * HH), blk, 0, stream>>>(
        (const short*)qb, (const short*)kb, (const short*)vtb, mask, flg, rs_bf);
    // output projection (fp32 into h2, free now) + residual LN
    gemm_mfma<false><<<dim3(CC / 128, NN / 128), blk, 0, stream>>>(
        (const short*)rs_bf, (const short*)o_wt, o_b, h2, nullptr, NN, CC, CC);
    final_ln<<<NN, blk, 0, stream>>>(x, h2, norm_g, norm_b, out);
}

// Round 6
// 444.817 us; speedup vs baseline: 4.2564x; 1.1546x over previous
//
#include <hip/hip_runtime.h>
#include <hip/hip_bf16.h>
#include <math.h>

// Problem constants
#define BB 2
#define TT 2048
#define CC 1024
#define HH 16
#define DD 64
#define CHALF 512
#define NN (BB * TT)   // 4096 rows

typedef __attribute__((ext_vector_type(8))) short short8;
typedef __attribute__((ext_vector_type(4))) short short4_t;
typedef __attribute__((ext_vector_type(4))) float f32x4;

__device__ __forceinline__ float gelu_exact(float x) {
    return 0.5f * x * (1.0f + erff(x * 0.70710678118654752f));
}

__device__ __forceinline__ short f2bf(float f) {
    __hip_bfloat16 h = __float2bfloat16(f);
    short s;
    __builtin_memcpy(&s, &h, 2);
    return s;
}

// async global->LDS, 16 B per lane; LDS dst must be wave-uniform base
__device__ __forceinline__ void async_copy16(const void* g, void* l) {
    __builtin_amdgcn_global_load_lds(
        (const __attribute__((address_space(1))) void*)g,
        (__attribute__((address_space(3))) void*)l, 16, 0, 0);
}

// ---------------------------------------------------------------------------
// fp32 -> bf16 elementwise convert (x)
// ---------------------------------------------------------------------------
__global__ __launch_bounds__(256) void conv_bf16(
    const float* __restrict__ X, __hip_bfloat16* __restrict__ O) {
    int i = (blockIdx.x * 256 + threadIdx.x) * 8;
    float4 a = *(const float4*)&X[i];
    float4 b = *(const float4*)&X[i + 4];
    __hip_bfloat16 o[8] = {
        __float2bfloat16(a.x), __float2bfloat16(a.y),
        __float2bfloat16(a.z), __float2bfloat16(a.w),
        __float2bfloat16(b.x), __float2bfloat16(b.y),
        __float2bfloat16(b.z), __float2bfloat16(b.w)};
    *(float4*)&O[i] = *(float4*)o;
}

// ---------------------------------------------------------------------------
// All 7 weight transposes in ONE launch: W [1024,N] fp32 -> Wt [N,1024] bf16
// ---------------------------------------------------------------------------
__global__ __launch_bounds__(256) void conv_transpose_all(
    const float* w0, const float* w1, const float* w2, const float* w3,
    const float* w4, const float* w5, const float* w6,
    __hip_bfloat16* t0, __hip_bfloat16* t1, __hip_bfloat16* t2,
    __hip_bfloat16* t3, __hip_bfloat16* t4, __hip_bfloat16* t5,
    __hip_bfloat16* t6) {
    const float* W;
    __hip_bfloat16* Wt;
    int N = 1024;
    switch (blockIdx.z) {
        case 0: W = w0; Wt = t0; N = 512; break;
        case 1: W = w1; Wt = t1; break;
        case 2: W = w2; Wt = t2; break;
        case 3: W = w3; Wt = t3; break;
        case 4: W = w4; Wt = t4; break;
        case 5: W = w5; Wt = t5; break;
        default: W = w6; Wt = t6; break;
    }
    int n0 = blockIdx.x * 64, k0 = blockIdx.y * 64;
    if (n0 >= N) return;
    __shared__ float T[64][65];
    int tid = threadIdx.x;
    int c = tid & 63, r4 = tid >> 6;
#pragma unroll
    for (int i = 0; i < 16; ++i) {
        int row = i * 4 + r4;
        T[row][c] = W[(size_t)(k0 + row) * N + n0 + c];
    }
    __syncthreads();
#pragma unroll
    for (int i = 0; i < 16; ++i) {
        int row = i * 4 + r4;  // n index
        Wt[(size_t)(n0 + row) * CC + k0 + c] = __float2bfloat16(T[c][row]);
    }
}

// ---------------------------------------------------------------------------
// bf16 MFMA GEMM, 64x128 tile (2 blocks/CU at N=1024): C = A @ Wt^T + bias
// 4 waves: wave tile 32x64 (wm=wave>>1, wn=wave&1), 8 mfma/k-step.
// ---------------------------------------------------------------------------
template <bool BF16OUT>
__global__ __launch_bounds__(256) void gemm_mfma64(
    const short* __restrict__ A, const short* __restrict__ Wt,
    const float* __restrict__ bias, float* __restrict__ Cf,
    __hip_bfloat16* __restrict__ Cb, int M, int N, int K) {
    __shared__ short As[64][32];
    __shared__ short Bs[128][32];
    int tid = threadIdx.x;
    int wave = tid >> 6, lane = tid & 63;
    int m16 = lane & 15, quad = lane >> 4;
    int wm = wave >> 1, wn = wave & 1;
    int row0 = blockIdx.y * 64, col0 = blockIdx.x * 128;
    int lr = lane >> 2;
    int kof = (lane & 3) * 8;

    f32x4 acc[2][4];
#pragma unroll
    for (int i = 0; i < 2; ++i)
#pragma unroll
        for (int j = 0; j < 4; ++j) acc[i][j] = (f32x4){0.f, 0.f, 0.f, 0.f};

    for (int k0 = 0; k0 < K; k0 += 32) {
        // A: 64 rows, one wave-copy each (wave w -> rows w*16..)
        async_copy16(A + (size_t)(row0 + wave * 16 + lr) * K + k0 + kof,
                     &As[wave * 16][0]);
        // B: 128 rows, two wave-copies each (wave w -> rows w*32..)
#pragma unroll
        for (int j = 0; j < 2; ++j) {
            int rbase = wave * 32 + j * 16;
            async_copy16(Wt + (size_t)(col0 + rbase + lr) * K + k0 + kof,
                         &Bs[rbase][0]);
        }
        __syncthreads();
        short8 af[2], bfr[4];
#pragma unroll
        for (int i = 0; i < 2; ++i)
            af[i] = *(const short8*)&As[wm * 32 + i * 16 + m16][quad * 8];
#pragma unroll
        for (int j = 0; j < 4; ++j)
            bfr[j] = *(const short8*)&Bs[wn * 64 + j * 16 + m16][quad * 8];
#pragma unroll
        for (int i = 0; i < 2; ++i)
#pragma unroll
            for (int j = 0; j < 4; ++j)
                acc[i][j] = __builtin_amdgcn_mfma_f32_16x16x32_bf16(
                    af[i], bfr[j], acc[i][j], 0, 0, 0);
        __syncthreads();
    }
#pragma unroll
    for (int i = 0; i < 2; ++i) {
#pragma unroll
        for (int j = 0; j < 4; ++j) {
            int col = col0 + wn * 64 + j * 16 + m16;
            float bv = bias[col];
#pragma unroll
            for (int rr = 0; rr < 4; ++rr) {
                int row = row0 + wm * 32 + i * 16 + quad * 4 + rr;
                float val = acc[i][j][rr] + bv;
                if (BF16OUT)
                    Cb[(size_t)row * N + col] = __float2bfloat16(val);
                else
                    Cf[(size_t)row * N + col] = val;
            }
        }
    }
}

// ---------------------------------------------------------------------------
// Batched q/k/v projection GEMMs, 128x128 tile (768 blocks = 3/CU).
// z=0: q scaled by temp[b,h]/8; z=1: k; z=2: v
// ---------------------------------------------------------------------------
__global__ __launch_bounds__(256) void gemm_qkv(
    const short* __restrict__ Aq, const short* __restrict__ Ak,
    const short* __restrict__ Av, const short* __restrict__ Wq,
    const short* __restrict__ Wk, const short* __restrict__ Wv,
    const float* __restrict__ bq, const float* __restrict__ bk,
    const float* __restrict__ bv, __hip_bfloat16* __restrict__ Cq,
    __hip_bfloat16* __restrict__ Ck, __hip_bfloat16* __restrict__ Cv,
    const float* __restrict__ tmp) {
    int z = blockIdx.z;
    const short* A = (z == 0) ? Aq : (z == 1) ? Ak : Av;
    const short* Wt = (z == 0) ? Wq : (z == 1) ? Wk : Wv;
    const float* bias = (z == 0) ? bq : (z == 1) ? bk : bv;
    __hip_bfloat16* C = (z == 0) ? Cq : (z == 1) ? Ck : Cv;

    __shared__ short As[128][32];
    __shared__ short Bs[128][32];
    int tid = threadIdx.x;
    int wave = tid >> 6, lane = tid & 63;
    int m16 = lane & 15, quad = lane >> 4;
    int wm = wave >> 1, wn = wave & 1;
    int row0 = blockIdx.y * 128, col0 = blockIdx.x * 128;
    int lr = lane >> 2;
    int kof = (lane & 3) * 8;

    float scale = 1.0f;
    if (z == 0) scale = tmp[(row0 >> 11) * HH + (col0 >> 6) + wn] * 0.125f;

    f32x4 acc[4][4];
#pragma unroll
    for (int i = 0; i < 4; ++i)
#pragma unroll
        for (int j = 0; j < 4; ++j) acc[i][j] = (f32x4){0.f, 0.f, 0.f, 0.f};

    for (int k0 = 0; k0 < CC; k0 += 32) {
#pragma unroll
        for (int j = 0; j < 2; ++j) {
            int rbase = wave * 32 + j * 16;
            async_copy16(A + (size_t)(row0 + rbase + lr) * CC + k0 + kof,
                         &As[rbase][0]);
            async_copy16(Wt + (size_t)(col0 + rbase + lr) * CC + k0 + kof,
                         &Bs[rbase][0]);
        }
        __syncthreads();
        short8 af[4], bfr[4];
#pragma unroll
        for (int i = 0; i < 4; ++i)
            af[i] = *(const short8*)&As[wm * 64 + i * 16 + m16][quad * 8];
#pragma unroll
        for (int j = 0; j < 4; ++j)
            bfr[j] = *(const short8*)&Bs[wn * 64 + j * 16 + m16][quad * 8];
#pragma unroll
        for (int i = 0; i < 4; ++i)
#pragma unroll
            for (int j = 0; j < 4; ++j)
                acc[i][j] = __builtin_amdgcn_mfma_f32_16x16x32_bf16(
                    af[i], bfr[j], acc[i][j], 0, 0, 0);
        __syncthreads();
    }
#pragma unroll
    for (int i = 0; i < 4; ++i) {
#pragma unroll
        for (int j = 0; j < 4; ++j) {
            int col = col0 + wn * 64 + j * 16 + m16;
            float bv2 = bias[col];
#pragma unroll
            for (int rr = 0; rr < 4; ++rr) {
                int row = row0 + wm * 64 + i * 16 + quad * 4 + rr;
                C[(size_t)row * CC + col] =
                    __float2bfloat16((acc[i][j][rr] + bv2) * scale);
            }
        }
    }
}

// ---------------------------------------------------------------------------
// Row-wise LayerNorm + exact GELU, in place (fp32, for h1)
// ---------------------------------------------------------------------------
template <int WIDTH>
__global__ __launch_bounds__(256) void ln_gelu_kernel(
    float* __restrict__ Y, const float* __restrict__ g,
    const float* __restrict__ beta) {
    constexpr int PT = WIDTH / 256;
    int row = blockIdx.x;
    int tid = threadIdx.x;
    float* yr = Y + (size_t)row * WIDTH;
    float v[PT];
    float s = 0.f;
#pragma unroll
    for (int i = 0; i < PT; ++i) {
        v[i] = yr[i * 256 + tid];
        s += v[i];
    }
    __shared__ float red[256];
    red[tid] = s;
    __syncthreads();
#pragma unroll
    for (int o = 128; o > 0; o >>= 1) {
        if (tid < o) red[tid] += red[tid + o];
        __syncthreads();
    }
    float mean = red[0] * (1.0f / WIDTH);
    __syncthreads();
    s = 0.f;
#pragma unroll
    for (int i = 0; i < PT; ++i) {
        float d = v[i] - mean;
        s += d * d;
    }
    red[tid] = s;
    __syncthreads();
#pragma unroll
    for (int o = 128; o > 0; o >>= 1) {
        if (tid < o) red[tid] += red[tid + o];
        __syncthreads();
    }
    float inv = rsqrtf(red[0] * (1.0f / WIDTH) + 1e-5f);
#pragma unroll
    for (int i = 0; i < PT; ++i) {
        int c = i * 256 + tid;
        yr[c] = gelu_exact((v[i] - mean) * inv * g[c] + beta[c]);
    }
}

// Same, fp32 in, bf16 out-of-place
template <int WIDTH>
__global__ __launch_bounds__(256) void ln_gelu_bf16(
    const float* __restrict__ Y, const float* __restrict__ g,
    const float* __restrict__ beta, __hip_bfloat16* __restrict__ O) {
    constexpr int PT = WIDTH / 256;
    int row = blockIdx.x;
    int tid = threadIdx.x;
    const float* yr = Y + (size_t)row * WIDTH;
    float v[PT];
    float s = 0.f;
#pragma unroll
    for (int i = 0; i < PT; ++i) {
        v[i] = yr[i * 256 + tid];
        s += v[i];
    }
    __shared__ float red[256];
    red[tid] = s;
    __syncthreads();
#pragma unroll
    for (int o = 128; o > 0; o >>= 1) {
        if (tid < o) red[tid] += red[tid + o];
        __syncthreads();
    }
    float mean = red[0] * (1.0f / WIDTH);
    __syncthreads();
    s = 0.f;
#pragma unroll
    for (int i = 0; i < PT; ++i) {
        float d = v[i] - mean;
        s += d * d;
    }
    red[tid] = s;
    __syncthreads();
#pragma unroll
    for (int o = 128; o > 0; o >>= 1) {
        if (tid < o) red[tid] += red[tid + o];
        __syncthreads();
    }
    float inv = rsqrtf(red[0] * (1.0f / WIDTH) + 1e-5f);
#pragma unroll
    for (int i = 0; i < PT; ++i) {
        int c = i * 256 + tid;
        O[(size_t)row * WIDTH + c] =
            __float2bfloat16(gelu_exact((v[i] - mean) * inv * g[c] + beta[c]));
    }
}

// ---------------------------------------------------------------------------
// importance gate: xi(bf16) = x * clamp(sigmoid(h1 . w2 + b2), 1e-6)
// ---------------------------------------------------------------------------
__global__ __launch_bounds__(256) void imp_scale(
    const float* __restrict__ h1, const float* __restrict__ w2,
    const float* __restrict__ b2, const float* __restrict__ x,
    __hip_bfloat16* __restrict__ xi) {
    int row = blockIdx.x;
    int tid = threadIdx.x;
    const float* hr = h1 + (size_t)row * CHALF;
    float s = hr[tid] * w2[tid] + hr[tid + 256] * w2[tid + 256];
    __shared__ float red[256];
    red[tid] = s;
    __syncthreads();
#pragma unroll
    for (int o = 128; o > 0; o >>= 1) {
        if (tid < o) red[tid] += red[tid + o];
        __syncthreads();
    }
    float z = red[0] + b2[0];
    float sg = 1.0f / (1.0f + expf(-z));
    float imp = fmaxf(sg, 1e-6f);
#pragma unroll
    for (int i = 0; i < 4; ++i) {
        int c = i * 256 + tid;
        xi[(size_t)row * CC + c] =
            __float2bfloat16(x[(size_t)row * CC + c] * imp);
    }
}

// ---------------------------------------------------------------------------
// reasoned.mean(axis=1), reading bf16 reasoned
// ---------------------------------------------------------------------------
__global__ __launch_bounds__(256) void mean_part(
    const __hip_bfloat16* __restrict__ R, float* __restrict__ part) {
    int idx = blockIdx.x * 256 + threadIdx.x;
    int c = idx & (CC - 1);
    int chunk = (idx >> 10) & 15;
    int b = idx >> 14;
    const __hip_bfloat16* base = R + ((size_t)(b * TT + chunk * 128)) * CC + c;
    float s = 0.f;
    for (int t = 0; t < 128; ++t) s += __bfloat162float(base[(size_t)t * CC]);
    part[idx] = s;
}

__global__ __launch_bounds__(256) void mean_fin(
    const float* __restrict__ part, float* __restrict__ rm) {
    int idx = blockIdx.x * 256 + threadIdx.x;
    int c = idx & (CC - 1);
    int b = idx >> 10;
    float s = 0.f;
#pragma unroll
    for (int ch = 0; ch < 16; ++ch) s += part[(size_t)(b * 16 + ch) * CC + c];
    rm[idx] = s * (1.0f / TT);
}

// ---------------------------------------------------------------------------
// temp_net stage 1: acc1[b,col] = rm[b,:] @ w1[:,col] + b1[col]
// grid (CHALF/64, BB), 256 thr: 64 cols x 4-way K split, coalesced w1 reads.
// ---------------------------------------------------------------------------
__global__ __launch_bounds__(256) void temp_gemv1(
    const float* __restrict__ rm, const float* __restrict__ w1,
    const float* __restrict__ b1, float* __restrict__ acc1) {
    int b = blockIdx.y;
    int c0 = blockIdx.x * 64;
    int tid = threadIdx.x;
    int col = c0 + (tid & 63);
    int kq = tid >> 6;  // 0..3
    const float* rmb = rm + b * CC;
    float s = 0.f;
#pragma unroll 8
    for (int i = kq * 256; i < kq * 256 + 256; ++i)
        s = fmaf(rmb[i], w1[(size_t)i * CHALF + col], s);
    __shared__ float red[256];
    red[tid] = s;
    __syncthreads();
    if (tid < 64) {
        float t = red[tid] + red[tid + 64] + red[tid + 128] + red[tid + 192];
        acc1[b * CHALF + tid + c0] = t + b1[col];
    }
}

// ---------------------------------------------------------------------------
// temp_net stage 2: LN(acc1) -> GELU -> @w2[512,16] + b2 -> softplus + 0.5
// 2 blocks x 512 thr; second GEMV via lane partials + wave shuffle reduce.
// ---------------------------------------------------------------------------
__global__ __launch_bounds__(512) void temp_fin(
    const float* __restrict__ acc1, const float* __restrict__ g,
    const float* __restrict__ beta, const float* __restrict__ w2,
    const float* __restrict__ b2, float* __restrict__ temp) {
    __shared__ float red[512];
    __shared__ float wred[8][16];
    int b = blockIdx.x;
    int tid = threadIdx.x;
    int wave = tid >> 6, lane = tid & 63;
    float acc = acc1[b * CHALF + tid];
    red[tid] = acc;
    __syncthreads();
#pragma unroll
    for (int o = 256; o > 0; o >>= 1) {
        if (tid < o) red[tid] += red[tid + o];
        __syncthreads();
    }
    float mean = red[0] * (1.0f / CHALF);
    __syncthreads();
    float d = acc - mean;
    red[tid] = d * d;
    __syncthreads();
#pragma unroll
    for (int o = 256; o > 0; o >>= 1) {
        if (tid < o) red[tid] += red[tid + o];
        __syncthreads();
    }
    float inv = rsqrtf(red[0] * (1.0f / CHALF) + 1e-5f);
    float ht = gelu_exact((acc - mean) * inv * g[tid] + beta[tid]);
    float p[16];
#pragma unroll
    for (int j = 0; j < 16; ++j) p[j] = ht * w2[tid * HH + j];
#pragma unroll
    for (int off = 1; off < 64; off <<= 1)
#pragma unroll
        for (int j = 0; j < 16; ++j) p[j] += __shfl_xor(p[j], off, 64);
    if (lane == 0)
#pragma unroll
        for (int j = 0; j < 16; ++j) wred[wave][j] = p[j];
    __syncthreads();
    if (tid < HH) {
        float s = b2[tid];
#pragma unroll
        for (int w = 0; w < 8; ++w) s += wred[w][tid];
        float sp = fmaxf(s, 0.f) + log1pf(expf(-fabsf(s)));
        temp[b * HH + tid] = sp + 0.5f;
    }
}

// ---------------------------------------------------------------------------
// mask tile flags (64x64 tiles)
// ---------------------------------------------------------------------------
__global__ __launch_bounds__(256) void mask_flags(
    const int* __restrict__ mask, int* __restrict__ flags) {
    int kt = blockIdx.x, qt = blockIdx.y, b = blockIdx.z;
    int tid = threadIdx.x;
    int r = tid >> 2;
    int c0 = (tid & 3) * 16;
    const int* base = mask + ((size_t)(b * TT + qt * 64 + r)) * TT + kt * 64 + c0;
    int all = 1;
#pragma unroll
    for (int i = 0; i < 4; ++i) {
        int4 m4 = *(const int4*)(base + i * 4);
        all &= (m4.x != 0) & (m4.y != 0) & (m4.z != 0) & (m4.w != 0);
    }
    __shared__ int red[256];
    red[tid] = all;
    __syncthreads();
#pragma unroll
    for (int o = 128; o > 0; o >>= 1) {
        if (tid < o) red[tid] &= red[tid + o];
        __syncthreads();
    }
    if (tid == 0) flags[(b * 32 + qt) * 32 + kt] = red[0];
}

// ---------------------------------------------------------------------------
// V global transpose: vb[b*T+t][h*64+d] -> vt[(b*16+h)*64+d][t]
// ---------------------------------------------------------------------------
__global__ __launch_bounds__(256) void transpose_v(
    const short* __restrict__ vb, short* __restrict__ vt) {
    __shared__ short T[64][72];  // [t][d]
    int t0 = blockIdx.x * 64;
    int bh = blockIdx.y;
    int b = bh >> 4, h = bh & 15;
    int tid = threadIdx.x;
#pragma unroll
    for (int p = 0; p < 2; ++p) {
        int idx = p * 256 + tid;
        int r = idx >> 3, c = (idx & 7) * 8;
        *(short8*)&T[r][c] =
            *(const short8*)&vb[(size_t)(b * TT + t0 + r) * CC + h * DD + c];
    }
    __syncthreads();
#pragma unroll
    for (int p = 0; p < 2; ++p) {
        int idx = p * 256 + tid;
        int d = idx >> 3, c = (idx & 7) * 8;
        short8 o;
#pragma unroll
        for (int u = 0; u < 8; ++u) o[u] = T[c + u][d];
        *(short8*)&vt[((size_t)bh * DD + d) * TT + t0 + c] = o;
    }
}

// ---------------------------------------------------------------------------
// MFMA flash attention v3 (q pre-scaled by temp/8; V pre-transposed).
// ---------------------------------------------------------------------------
__global__ __launch_bounds__(256) void flash_attn_mfma(
    const short* __restrict__ q, const short* __restrict__ k,
    const short* __restrict__ vt, const int* __restrict__ mask,
    const int* __restrict__ flags, __hip_bfloat16* __restrict__ out) {
    __shared__ short Ks[64][72];    // [key][d]
    __shared__ short Vt[64][72];    // [d][key]
    __shared__ short Ps[128][72];   // [q-row][key], wave-private strips
    int tid = threadIdx.x;
    int wave = tid >> 6, lane = tid & 63;
    int m16 = lane & 15, quad = lane >> 4;
    int qt = blockIdx.x;
    int q0 = qt * 128;
    int bh = blockIdx.y;
    int b = bh >> 4, h = bh & 15;

    short8 qf[2][2];
#pragma unroll
    for (int qg = 0; qg < 2; ++qg) {
        const short* qrow = q + ((size_t)(b * TT + q0 + wave * 32 + qg * 16 + m16)) * CC +
                            h * DD + quad * 8;
        qf[qg][0] = *(const short8*)(qrow);
        qf[qg][1] = *(const short8*)(qrow + 32);
    }

    float m_run[2] = {-INFINITY, -INFINITY};
    float l_run[2] = {0.f, 0.f};
    f32x4 acc_o[2][4];
#pragma unroll
    for (int qg = 0; qg < 2; ++qg)
#pragma unroll
        for (int t = 0; t < 4; ++t) acc_o[qg][t] = (f32x4){0.f, 0.f, 0.f, 0.f};

    for (int kt = 0; kt < TT / 64; ++kt) {
        int kb = kt * 64;
#pragma unroll
        for (int i = 0; i < 2; ++i) {
            int idx = i * 256 + tid;
            int r = idx >> 3;
            int dc = (idx & 7) * 8;
            *(short8*)&Ks[r][dc] =
                *(const short8*)(k + ((size_t)(b * TT + kb + r)) * CC + h * DD + dc);
            *(short8*)&Vt[r][dc] =
                *(const short8*)(vt + ((size_t)bh * DD + r) * TT + kb + dc);
        }
        __syncthreads();

        short8 kf[4][2];
#pragma unroll
        for (int t = 0; t < 4; ++t) {
            kf[t][0] = *(const short8*)&Ks[t * 16 + m16][quad * 8];
            kf[t][1] = *(const short8*)&Ks[t * 16 + m16][32 + quad * 8];
        }
        int fl = flags[(b * 32 + 2 * qt + (wave >> 1)) * 32 + kt];

#pragma unroll
        for (int qg = 0; qg < 2; ++qg) {
            f32x4 sacc[4];
#pragma unroll
            for (int t = 0; t < 4; ++t) sacc[t] = (f32x4){0.f, 0.f, 0.f, 0.f};
#pragma unroll
            for (int t = 0; t < 4; ++t) {
                sacc[t] = __builtin_amdgcn_mfma_f32_16x16x32_bf16(kf[t][0], qf[qg][0], sacc[t], 0, 0, 0);
                sacc[t] = __builtin_amdgcn_mfma_f32_16x16x32_bf16(kf[t][1], qf[qg][1], sacc[t], 0, 0, 0);
            }
            float sv[4][4];
#pragma unroll
            for (int t = 0; t < 4; ++t)
#pragma unroll
                for (int r = 0; r < 4; ++r) sv[t][r] = sacc[t][r];
            if (fl == 0) {
                int qrow = q0 + wave * 32 + qg * 16 + m16;
#pragma unroll
                for (int t = 0; t < 4; ++t)
#pragma unroll
                    for (int r = 0; r < 4; ++r) {
                        int kg = kb + t * 16 + quad * 4 + r;
                        if (mask[((size_t)(b * TT + qrow)) * TT + kg] == 0)
                            sv[t][r] = -INFINITY;
                    }
            }
            float mx = sv[0][0];
#pragma unroll
            for (int t = 0; t < 4; ++t)
#pragma unroll
                for (int r = 0; r < 4; ++r) mx = fmaxf(mx, sv[t][r]);
            mx = fmaxf(mx, __shfl_xor(mx, 16, 64));
            mx = fmaxf(mx, __shfl_xor(mx, 32, 64));
            float mnew = fmaxf(m_run[qg], mx);
            float alpha = __expf(m_run[qg] - mnew);
            m_run[qg] = mnew;
            int prow = wave * 32 + qg * 16 + m16;
            float psum = 0.f;
#pragma unroll
            for (int t = 0; t < 4; ++t) {
                short4_t pk;
#pragma unroll
                for (int r = 0; r < 4; ++r) {
                    float p = __expf(sv[t][r] - mnew);
                    psum += p;
                    pk[r] = f2bf(p);
                }
                *(short4_t*)&Ps[prow][t * 16 + quad * 4] = pk;
            }
            psum += __shfl_xor(psum, 16, 64);
            psum += __shfl_xor(psum, 32, 64);
            l_run[qg] = l_run[qg] * alpha + psum;
#pragma unroll
            for (int r = 0; r < 4; ++r) {
                float ar = __shfl(alpha, (lane & 48) | (quad * 4 + r), 64);
#pragma unroll
                for (int td = 0; td < 4; ++td) acc_o[qg][td][r] *= ar;
            }
        }

#pragma unroll
        for (int kc = 0; kc < 2; ++kc) {
            short8 vf[4];
#pragma unroll
            for (int td = 0; td < 4; ++td)
                vf[td] = *(const short8*)&Vt[td * 16 + m16][kc * 32 + quad * 8];
#pragma unroll
            for (int qg = 0; qg < 2; ++qg) {
                short8 pf = *(const short8*)&Ps[wave * 32 + qg * 16 + m16][kc * 32 + quad * 8];
#pragma unroll
                for (int td = 0; td < 4; ++td)
                    acc_o[qg][td] = __builtin_amdgcn_mfma_f32_16x16x32_bf16(
                        pf, vf[td], acc_o[qg][td], 0, 0, 0);
            }
        }
        __syncthreads();
    }

#pragma unroll
    for (int qg = 0; qg < 2; ++qg) {
#pragma unroll
        for (int r = 0; r < 4; ++r) {
            float lr = __shfl(l_run[qg], (lane & 48) | (quad * 4 + r), 64);
            float inv = 1.0f / lr;
            int row = b * TT + q0 + wave * 32 + qg * 16 + quad * 4 + r;
#pragma unroll
            for (int td = 0; td < 4; ++td)
                out[(size_t)row * CC + h * DD + td * 16 + m16] =
                    __float2bfloat16(acc_o[qg][td][r] * inv);
        }
    }
}

// ---------------------------------------------------------------------------
// Final: out = LN(x + proj)
// ---------------------------------------------------------------------------
__global__ __launch_bounds__(256) void final_ln(
    const float* __restrict__ x, const float* __restrict__ p,
    const float* __restrict__ g, const float* __restrict__ beta,
    float* __restrict__ out) {
    int row = blockIdx.x;
    int tid = threadIdx.x;
    const float* xr = x + (size_t)row * CC;
    const float* pr = p + (size_t)row * CC;
    float v[4];
    float s = 0.f;
#pragma unroll
    for (int i = 0; i < 4; ++i) {
        int c = i * 256 + tid;
        v[i] = xr[c] + pr[c];
        s += v[i];
    }
    __shared__ float red[256];
    red[tid] = s;
    __syncthreads();
#pragma unroll
    for (int o = 128; o > 0; o >>= 1) {
        if (tid < o) red[tid] += red[tid + o];
        __syncthreads();
    }
    float mean = red[0] * (1.0f / CC);
    __syncthreads();
    s = 0.f;
#pragma unroll
    for (int i = 0; i < 4; ++i) {
        float d = v[i] - mean;
        s += d * d;
    }
    red[tid] = s;
    __syncthreads();
#pragma unroll
    for (int o = 128; o > 0; o >>= 1) {
        if (tid < o) red[tid] += red[tid + o];
        __syncthreads();
    }
    float inv = rsqrtf(red[0] * (1.0f / CC) + 1e-5f);
#pragma unroll
    for (int i = 0; i < 4; ++i) {
        int c = i * 256 + tid;
        out[(size_t)row * CC + c] = (v[i] - mean) * inv * g[c] + beta[c];
    }
}

extern "C" void kernel_launch(void* const* d_in, const int* in_sizes, int n_in,
                              void* d_out, int out_size, void* d_ws,
                              size_t ws_size, hipStream_t stream) {
    const float* x        = (const float*)d_in[0];
    const int*   mask     = (const int*)d_in[1];
    const float* imp_w1   = (const float*)d_in[2];
    const float* imp_b1   = (const float*)d_in[3];
    const float* imp_g    = (const float*)d_in[4];
    const float* imp_beta = (const float*)d_in[5];
    const float* imp_w2   = (const float*)d_in[6];
    const float* imp_b2   = (const float*)d_in[7];
    const float* rsn_w1   = (const float*)d_in[8];
    const float* rsn_b1   = (const float*)d_in[9];
    const float* rsn_g    = (const float*)d_in[10];
    const float* rsn_beta = (const float*)d_in[11];
    const float* rsn_w2   = (const float*)d_in[12];
    const float* rsn_b2   = (const float*)d_in[13];
    const float* q_w      = (const float*)d_in[14];
    const float* q_b      = (const float*)d_in[15];
    const float* k_w      = (const float*)d_in[16];
    const float* k_b      = (const float*)d_in[17];
    const float* v_w      = (const float*)d_in[18];
    const float* v_b      = (const float*)d_in[19];
    const float* o_w      = (const float*)d_in[20];
    const float* o_b      = (const float*)d_in[21];
    const float* tmp_w1   = (const float*)d_in[22];
    const float* tmp_b1   = (const float*)d_in[23];
    const float* tmp_g    = (const float*)d_in[24];
    const float* tmp_beta = (const float*)d_in[25];
    const float* tmp_w2   = (const float*)d_in[26];
    const float* tmp_b2   = (const float*)d_in[27];
    const float* norm_g   = (const float*)d_in[28];
    const float* norm_b   = (const float*)d_in[29];
    float* out = (float*)d_out;
    float* ws  = (float*)d_ws;

    // workspace layout (float offsets)
    float* h1  = ws;                       // [4096,512] fp32
    float* h2  = ws + 2097152;             // [4096,1024] fp32 (later o-proj out)
    __hip_bfloat16* x_bf  = (__hip_bfloat16*)(ws + 6291456);
    __hip_bfloat16* xi_bf = (__hip_bfloat16*)(ws + 8388608);
    __hip_bfloat16* h2b   = (__hip_bfloat16*)(ws + 10485760);
    __hip_bfloat16* rs_bf = (__hip_bfloat16*)(ws + 12582912);  // reasoned, later attn out
    __hip_bfloat16* qb    = (__hip_bfloat16*)(ws + 14680064);
    __hip_bfloat16* kb    = (__hip_bfloat16*)(ws + 16777216);
    __hip_bfloat16* vb    = (__hip_bfloat16*)(ws + 18874368);
    __hip_bfloat16* vtb   = (__hip_bfloat16*)(ws + 20971520);  // [32,64,2048]
    __hip_bfloat16* imp_w1t = (__hip_bfloat16*)(ws + 23068672);  // [512,1024]
    __hip_bfloat16* rsn_w1t = (__hip_bfloat16*)(ws + 23330816);  // [1024,1024]
    __hip_bfloat16* rsn_w2t = (__hip_bfloat16*)(ws + 23855104);
    __hip_bfloat16* q_wt    = (__hip_bfloat16*)(ws + 24379392);
    __hip_bfloat16* k_wt    = (__hip_bfloat16*)(ws + 24903680);
    __hip_bfloat16* v_wt    = (__hip_bfloat16*)(ws + 25427968);
    __hip_bfloat16* o_wt    = (__hip_bfloat16*)(ws + 25952256);
    float* rm   = ws + 26476544;   // [2,1024]
    float* tmp  = ws + 26478592;   // [2,16]
    float* part = ws + 26479104;   // [2,16,1024]
    int*   flg  = (int*)(ws + 26511872);  // [2,32,32]
    float* acc1 = ws + 26513920;   // [2,512]

    dim3 blk(256);
    // converts: x -> bf16; all 7 weights -> bf16 transposed [N,K] in one launch
    conv_bf16<<<NN * CC / (256 * 8), blk, 0, stream>>>(x, x_bf);
    conv_transpose_all<<<dim3(16, 16, 7), blk, 0, stream>>>(
        imp_w1, rsn_w1, rsn_w2, q_w, k_w, v_w, o_w,
        imp_w1t, rsn_w1t, rsn_w2t, q_wt, k_wt, v_wt, o_wt);
    // mask tile flags (independent)
    mask_flags<<<dim3(32, 32, 2), blk, 0, stream>>>(mask, flg);

    // importance net
    gemm_mfma64<false><<<dim3(CHALF / 128, NN / 64), blk, 0, stream>>>(
        (const short*)x_bf, (const short*)imp_w1t, imp_b1, h1, nullptr, NN, CHALF, CC);
    ln_gelu_kernel<CHALF><<<NN, blk, 0, stream>>>(h1, imp_g, imp_beta);
    imp_scale<<<NN, blk, 0, stream>>>(h1, imp_w2, imp_b2, x, xi_bf);
    // reasoning net
    gemm_mfma64<false><<<dim3(CC / 128, NN / 64), blk, 0, stream>>>(
        (const short*)xi_bf, (const short*)rsn_w1t, rsn_b1, h2, nullptr, NN, CC, CC);
    ln_gelu_bf16<CC><<<NN, blk, 0, stream>>>(h2, rsn_g, rsn_beta, h2b);
    gemm_mfma64<true><<<dim3(CC / 128, NN / 64), blk, 0, stream>>>(
        (const short*)h2b, (const short*)rsn_w2t, rsn_b2, nullptr, rs_bf, NN, CC, CC);
    // temperature net (parallelized)
    mean_part<<<128, blk, 0, stream>>>(rs_bf, part);
    mean_fin<<<8, blk, 0, stream>>>(part, rm);
    temp_gemv1<<<dim3(CHALF / 64, BB), blk, 0, stream>>>(rm, tmp_w1, tmp_b1, acc1);
    temp_fin<<<BB, dim3(512), 0, stream>>>(acc1, tmp_g, tmp_beta, tmp_w2, tmp_b2, tmp);
    // q/k/v projections batched (768 blocks = 3/CU); q scaled by temp/8
    gemm_qkv<<<dim3(CC / 128, NN / 128, 3), blk, 0, stream>>>(
        (const short*)rs_bf, (const short*)xi_bf, (const short*)x_bf,
        (const short*)q_wt, (const short*)k_wt, (const short*)v_wt,
        q_b, k_b, v_b, qb, kb, vb, tmp);
    // V transpose for flash B-operand staging
    transpose_v<<<dim3(TT / 64, BB * HH), blk, 0, stream>>>(
        (const short*)vb, (short*)vtb);
    // flash attention v3
    flash_attn_mfma<<<dim3(TT / 128, BB * HH), blk, 0, stream>>>(
        (const short*)qb, (const short*)kb, (const short*)vtb, mask, flg, rs_bf);
    // output projection (fp32 into h2, free now) + residual LN
    gemm_mfma64<false><<<dim3(CC / 128, NN / 64), blk, 0, stream>>>(
        (const short*)rs_bf, (const short*)o_wt, o_b, h2, nullptr, NN, CC, CC);
    final_ln<<<NN, blk, 0, stream>>>(x, h2, norm_g, norm_b, out);
}

// Round 7
// 443.191 us; speedup vs baseline: 4.2720x; 1.0037x over previous
//
#include <hip/hip_runtime.h>
#include <hip/hip_bf16.h>
#include <math.h>

// Problem constants
#define BB 2
#define TT 2048
#define CC 1024
#define HH 16
#define DD 64
#define CHALF 512
#define NN (BB * TT)   // 4096 rows
#define LOG2E 1.44269504088896340736f

typedef __attribute__((ext_vector_type(8))) short short8;
typedef __attribute__((ext_vector_type(4))) short short4_t;
typedef __attribute__((ext_vector_type(4))) float f32x4;

__device__ __forceinline__ float gelu_exact(float x) {
    return 0.5f * x * (1.0f + erff(x * 0.70710678118654752f));
}

__device__ __forceinline__ short f2bf(float f) {
    __hip_bfloat16 h = __float2bfloat16(f);
    short s;
    __builtin_memcpy(&s, &h, 2);
    return s;
}

// async global->LDS, 16 B per lane; LDS dst must be wave-uniform base
__device__ __forceinline__ void async_copy16(const void* g, void* l) {
    __builtin_amdgcn_global_load_lds(
        (const __attribute__((address_space(1))) void*)g,
        (__attribute__((address_space(3))) void*)l, 16, 0, 0);
}

// ---------------------------------------------------------------------------
// prep: one launch for x->bf16 convert, mask tile flags, 7 weight transposes.
// blocks [0,2048): conv_bf16; [2048,4096): mask flags; [4096,5760): transposes
// ---------------------------------------------------------------------------
__global__ __launch_bounds__(256) void prep(
    const float* __restrict__ x, __hip_bfloat16* __restrict__ x_bf,
    const int* __restrict__ mask, int* __restrict__ flags,
    const float* w0, const float* w1, const float* w2, const float* w3,
    const float* w4, const float* w5, const float* w6,
    __hip_bfloat16* t0, __hip_bfloat16* t1, __hip_bfloat16* t2,
    __hip_bfloat16* t3, __hip_bfloat16* t4, __hip_bfloat16* t5,
    __hip_bfloat16* t6) {
    __shared__ float T[64][65];
    int blk = blockIdx.x;
    int tid = threadIdx.x;
    if (blk < 2048) {
        int i = (blk * 256 + tid) * 8;
        float4 a = *(const float4*)&x[i];
        float4 b = *(const float4*)&x[i + 4];
        __hip_bfloat16 o[8] = {
            __float2bfloat16(a.x), __float2bfloat16(a.y),
            __float2bfloat16(a.z), __float2bfloat16(a.w),
            __float2bfloat16(b.x), __float2bfloat16(b.y),
            __float2bfloat16(b.z), __float2bfloat16(b.w)};
        *(float4*)&x_bf[i] = *(float4*)o;
    } else if (blk < 4096) {
        int idx = blk - 2048;
        int kt = idx & 31, qt = (idx >> 5) & 31, b = idx >> 10;
        int* red = (int*)T;
        int r = tid >> 2;
        int c0 = (tid & 3) * 16;
        const int* base =
            mask + ((size_t)(b * TT + qt * 64 + r)) * TT + kt * 64 + c0;
        int all = 1;
#pragma unroll
        for (int i = 0; i < 4; ++i) {
            int4 m4 = *(const int4*)(base + i * 4);
            all &= (m4.x != 0) & (m4.y != 0) & (m4.z != 0) & (m4.w != 0);
        }
        red[tid] = all;
        __syncthreads();
#pragma unroll
        for (int o = 128; o > 0; o >>= 1) {
            if (tid < o) red[tid] &= red[tid + o];
            __syncthreads();
        }
        if (tid == 0) flags[(b * 32 + qt) * 32 + kt] = red[0];
    } else {
        int idx = blk - 4096;
        const float* W;
        __hip_bfloat16* Wt;
        int N, n0, k0;
        if (idx < 128) {
            W = w0; Wt = t0; N = 512;
            n0 = (idx & 7) * 64;
            k0 = (idx >> 3) * 64;
        } else {
            idx -= 128;
            int w = idx >> 8;
            int r = idx & 255;
            N = 1024;
            n0 = (r & 15) * 64;
            k0 = (r >> 4) * 64;
            switch (w) {
                case 0: W = w1; Wt = t1; break;
                case 1: W = w2; Wt = t2; break;
                case 2: W = w3; Wt = t3; break;
                case 3: W = w4; Wt = t4; break;
                case 4: W = w5; Wt = t5; break;
                default: W = w6; Wt = t6; break;
            }
        }
        int c = tid & 63, r4 = tid >> 6;
#pragma unroll
        for (int i = 0; i < 16; ++i) {
            int row = i * 4 + r4;
            T[row][c] = W[(size_t)(k0 + row) * N + n0 + c];
        }
        __syncthreads();
#pragma unroll
        for (int i = 0; i < 16; ++i) {
            int row = i * 4 + r4;  // n index
            Wt[(size_t)(n0 + row) * CC + k0 + c] = __float2bfloat16(T[c][row]);
        }
    }
}

// ---------------------------------------------------------------------------
// bf16 MFMA GEMM, 64x128 tile: C = A @ Wt^T + bias
// ---------------------------------------------------------------------------
template <bool BF16OUT>
__global__ __launch_bounds__(256) void gemm_mfma64(
    const short* __restrict__ A, const short* __restrict__ Wt,
    const float* __restrict__ bias, float* __restrict__ Cf,
    __hip_bfloat16* __restrict__ Cb, int M, int N, int K) {
    __shared__ short As[64][32];
    __shared__ short Bs[128][32];
    int tid = threadIdx.x;
    int wave = tid >> 6, lane = tid & 63;
    int m16 = lane & 15, quad = lane >> 4;
    int wm = wave >> 1, wn = wave & 1;
    int row0 = blockIdx.y * 64, col0 = blockIdx.x * 128;
    int lr = lane >> 2;
    int kof = (lane & 3) * 8;

    f32x4 acc[2][4];
#pragma unroll
    for (int i = 0; i < 2; ++i)
#pragma unroll
        for (int j = 0; j < 4; ++j) acc[i][j] = (f32x4){0.f, 0.f, 0.f, 0.f};

    for (int k0 = 0; k0 < K; k0 += 32) {
        async_copy16(A + (size_t)(row0 + wave * 16 + lr) * K + k0 + kof,
                     &As[wave * 16][0]);
#pragma unroll
        for (int j = 0; j < 2; ++j) {
            int rbase = wave * 32 + j * 16;
            async_copy16(Wt + (size_t)(col0 + rbase + lr) * K + k0 + kof,
                         &Bs[rbase][0]);
        }
        __syncthreads();
        short8 af[2], bfr[4];
#pragma unroll
        for (int i = 0; i < 2; ++i)
            af[i] = *(const short8*)&As[wm * 32 + i * 16 + m16][quad * 8];
#pragma unroll
        for (int j = 0; j < 4; ++j)
            bfr[j] = *(const short8*)&Bs[wn * 64 + j * 16 + m16][quad * 8];
#pragma unroll
        for (int i = 0; i < 2; ++i)
#pragma unroll
            for (int j = 0; j < 4; ++j)
                acc[i][j] = __builtin_amdgcn_mfma_f32_16x16x32_bf16(
                    af[i], bfr[j], acc[i][j], 0, 0, 0);
        __syncthreads();
    }
#pragma unroll
    for (int i = 0; i < 2; ++i) {
#pragma unroll
        for (int j = 0; j < 4; ++j) {
            int col = col0 + wn * 64 + j * 16 + m16;
            float bv = bias[col];
#pragma unroll
            for (int rr = 0; rr < 4; ++rr) {
                int row = row0 + wm * 32 + i * 16 + quad * 4 + rr;
                float val = acc[i][j][rr] + bv;
                if (BF16OUT)
                    Cb[(size_t)row * N + col] = __float2bfloat16(val);
                else
                    Cf[(size_t)row * N + col] = val;
            }
        }
    }
}

// ---------------------------------------------------------------------------
// Batched q/k/v projections, 128x128 tile. z=0: q scaled by temp/8*log2e.
// ---------------------------------------------------------------------------
__global__ __launch_bounds__(256) void gemm_qkv(
    const short* __restrict__ Aq, const short* __restrict__ Ak,
    const short* __restrict__ Av, const short* __restrict__ Wq,
    const short* __restrict__ Wk, const short* __restrict__ Wv,
    const float* __restrict__ bq, const float* __restrict__ bk,
    const float* __restrict__ bv, __hip_bfloat16* __restrict__ Cq,
    __hip_bfloat16* __restrict__ Ck, __hip_bfloat16* __restrict__ Cv,
    const float* __restrict__ tmp) {
    int z = blockIdx.z;
    const short* A = (z == 0) ? Aq : (z == 1) ? Ak : Av;
    const short* Wt = (z == 0) ? Wq : (z == 1) ? Wk : Wv;
    const float* bias = (z == 0) ? bq : (z == 1) ? bk : bv;
    __hip_bfloat16* C = (z == 0) ? Cq : (z == 1) ? Ck : Cv;

    __shared__ short As[128][32];
    __shared__ short Bs[128][32];
    int tid = threadIdx.x;
    int wave = tid >> 6, lane = tid & 63;
    int m16 = lane & 15, quad = lane >> 4;
    int wm = wave >> 1, wn = wave & 1;
    int row0 = blockIdx.y * 128, col0 = blockIdx.x * 128;
    int lr = lane >> 2;
    int kof = (lane & 3) * 8;

    float scale = 1.0f;
    if (z == 0)
        scale = tmp[(row0 >> 11) * HH + (col0 >> 6) + wn] * 0.125f * LOG2E;

    f32x4 acc[4][4];
#pragma unroll
    for (int i = 0; i < 4; ++i)
#pragma unroll
        for (int j = 0; j < 4; ++j) acc[i][j] = (f32x4){0.f, 0.f, 0.f, 0.f};

    for (int k0 = 0; k0 < CC; k0 += 32) {
#pragma unroll
        for (int j = 0; j < 2; ++j) {
            int rbase = wave * 32 + j * 16;
            async_copy16(A + (size_t)(row0 + rbase + lr) * CC + k0 + kof,
                         &As[rbase][0]);
            async_copy16(Wt + (size_t)(col0 + rbase + lr) * CC + k0 + kof,
                         &Bs[rbase][0]);
        }
        __syncthreads();
        short8 af[4], bfr[4];
#pragma unroll
        for (int i = 0; i < 4; ++i)
            af[i] = *(const short8*)&As[wm * 64 + i * 16 + m16][quad * 8];
#pragma unroll
        for (int j = 0; j < 4; ++j)
            bfr[j] = *(const short8*)&Bs[wn * 64 + j * 16 + m16][quad * 8];
#pragma unroll
        for (int i = 0; i < 4; ++i)
#pragma unroll
            for (int j = 0; j < 4; ++j)
                acc[i][j] = __builtin_amdgcn_mfma_f32_16x16x32_bf16(
                    af[i], bfr[j], acc[i][j], 0, 0, 0);
        __syncthreads();
    }
#pragma unroll
    for (int i = 0; i < 4; ++i) {
#pragma unroll
        for (int j = 0; j < 4; ++j) {
            int col = col0 + wn * 64 + j * 16 + m16;
            float bv2 = bias[col];
#pragma unroll
            for (int rr = 0; rr < 4; ++rr) {
                int row = row0 + wm * 64 + i * 16 + quad * 4 + rr;
                C[(size_t)row * CC + col] =
                    __float2bfloat16((acc[i][j][rr] + bv2) * scale);
            }
        }
    }
}

// ---------------------------------------------------------------------------
// fused importance epilogue: LN(h1)+GELU -> dot w2 -> sigmoid -> xi = x*imp
// ---------------------------------------------------------------------------
__global__ __launch_bounds__(256) void imp_fused(
    const float* __restrict__ h1, const float* __restrict__ g,
    const float* __restrict__ beta, const float* __restrict__ w2,
    const float* __restrict__ b2, const float* __restrict__ x,
    __hip_bfloat16* __restrict__ xi) {
    int row = blockIdx.x;
    int tid = threadIdx.x;
    const float* hr = h1 + (size_t)row * CHALF;
    float v0 = hr[tid], v1 = hr[tid + 256];
    __shared__ float red[256];
    red[tid] = v0 + v1;
    __syncthreads();
#pragma unroll
    for (int o = 128; o > 0; o >>= 1) {
        if (tid < o) red[tid] += red[tid + o];
        __syncthreads();
    }
    float mean = red[0] * (1.0f / CHALF);
    __syncthreads();
    float d0 = v0 - mean, d1 = v1 - mean;
    red[tid] = d0 * d0 + d1 * d1;
    __syncthreads();
#pragma unroll
    for (int o = 128; o > 0; o >>= 1) {
        if (tid < o) red[tid] += red[tid + o];
        __syncthreads();
    }
    float inv = rsqrtf(red[0] * (1.0f / CHALF) + 1e-5f);
    __syncthreads();
    float ge0 = gelu_exact(d0 * inv * g[tid] + beta[tid]);
    float ge1 = gelu_exact(d1 * inv * g[tid + 256] + beta[tid + 256]);
    red[tid] = ge0 * w2[tid] + ge1 * w2[tid + 256];
    __syncthreads();
#pragma unroll
    for (int o = 128; o > 0; o >>= 1) {
        if (tid < o) red[tid] += red[tid + o];
        __syncthreads();
    }
    float z = red[0] + b2[0];
    float sg = 1.0f / (1.0f + expf(-z));
    float imp = fmaxf(sg, 1e-6f);
#pragma unroll
    for (int i = 0; i < 4; ++i) {
        int c = i * 256 + tid;
        xi[(size_t)row * CC + c] =
            __float2bfloat16(x[(size_t)row * CC + c] * imp);
    }
}

// ---------------------------------------------------------------------------
// LN + GELU fp32 in -> bf16 out (for h2 -> h2b)
// ---------------------------------------------------------------------------
template <int WIDTH>
__global__ __launch_bounds__(256) void ln_gelu_bf16(
    const float* __restrict__ Y, const float* __restrict__ g,
    const float* __restrict__ beta, __hip_bfloat16* __restrict__ O) {
    constexpr int PT = WIDTH / 256;
    int row = blockIdx.x;
    int tid = threadIdx.x;
    const float* yr = Y + (size_t)row * WIDTH;
    float v[PT];
    float s = 0.f;
#pragma unroll
    for (int i = 0; i < PT; ++i) {
        v[i] = yr[i * 256 + tid];
        s += v[i];
    }
    __shared__ float red[256];
    red[tid] = s;
    __syncthreads();
#pragma unroll
    for (int o = 128; o > 0; o >>= 1) {
        if (tid < o) red[tid] += red[tid + o];
        __syncthreads();
    }
    float mean = red[0] * (1.0f / WIDTH);
    __syncthreads();
    s = 0.f;
#pragma unroll
    for (int i = 0; i < PT; ++i) {
        float d = v[i] - mean;
        s += d * d;
    }
    red[tid] = s;
    __syncthreads();
#pragma unroll
    for (int o = 128; o > 0; o >>= 1) {
        if (tid < o) red[tid] += red[tid + o];
        __syncthreads();
    }
    float inv = rsqrtf(red[0] * (1.0f / WIDTH) + 1e-5f);
#pragma unroll
    for (int i = 0; i < PT; ++i) {
        int c = i * 256 + tid;
        O[(size_t)row * WIDTH + c] =
            __float2bfloat16(gelu_exact((v[i] - mean) * inv * g[c] + beta[c]));
    }
}

// ---------------------------------------------------------------------------
// reasoned.mean(axis=1), stage 1 (partials over 128-row chunks)
// ---------------------------------------------------------------------------
__global__ __launch_bounds__(256) void mean_part(
    const __hip_bfloat16* __restrict__ R, float* __restrict__ part) {
    int idx = blockIdx.x * 256 + threadIdx.x;
    int c = idx & (CC - 1);
    int chunk = (idx >> 10) & 15;
    int b = idx >> 14;
    const __hip_bfloat16* base = R + ((size_t)(b * TT + chunk * 128)) * CC + c;
    float s = 0.f;
    for (int t = 0; t < 128; ++t) s += __bfloat162float(base[(size_t)t * CC]);
    part[idx] = s;
}

// ---------------------------------------------------------------------------
// temp_net stage 1 (+ fused mean finalize): acc1[b,col] = rm @ w1 + b1
// ---------------------------------------------------------------------------
__global__ __launch_bounds__(256) void temp_gemv1(
    const float* __restrict__ part, const float* __restrict__ w1,
    const float* __restrict__ b1, float* __restrict__ acc1) {
    __shared__ float rm_l[CC];
    __shared__ float red[256];
    int b = blockIdx.y;
    int c0 = blockIdx.x * 64;
    int tid = threadIdx.x;
    for (int cc = tid; cc < CC; cc += 256) {
        float s = 0.f;
#pragma unroll
        for (int ch = 0; ch < 16; ++ch)
            s += part[(size_t)(b * 16 + ch) * CC + cc];
        rm_l[cc] = s * (1.0f / TT);
    }
    __syncthreads();
    int col = c0 + (tid & 63);
    int kq = tid >> 6;  // 0..3
    float s = 0.f;
#pragma unroll 8
    for (int i = kq * 256; i < kq * 256 + 256; ++i)
        s = fmaf(rm_l[i], w1[(size_t)i * CHALF + col], s);
    red[tid] = s;
    __syncthreads();
    if (tid < 64) {
        float t = red[tid] + red[tid + 64] + red[tid + 128] + red[tid + 192];
        acc1[b * CHALF + tid + c0] = t + b1[col];
    }
}

// ---------------------------------------------------------------------------
// temp_net stage 2: LN(acc1) -> GELU -> @w2 + b2 -> softplus + 0.5
// ---------------------------------------------------------------------------
__global__ __launch_bounds__(512) void temp_fin(
    const float* __restrict__ acc1, const float* __restrict__ g,
    const float* __restrict__ beta, const float* __restrict__ w2,
    const float* __restrict__ b2, float* __restrict__ temp) {
    __shared__ float red[512];
    __shared__ float wred[8][16];
    int b = blockIdx.x;
    int tid = threadIdx.x;
    int wave = tid >> 6, lane = tid & 63;
    float acc = acc1[b * CHALF + tid];
    red[tid] = acc;
    __syncthreads();
#pragma unroll
    for (int o = 256; o > 0; o >>= 1) {
        if (tid < o) red[tid] += red[tid + o];
        __syncthreads();
    }
    float mean = red[0] * (1.0f / CHALF);
    __syncthreads();
    float d = acc - mean;
    red[tid] = d * d;
    __syncthreads();
#pragma unroll
    for (int o = 256; o > 0; o >>= 1) {
        if (tid < o) red[tid] += red[tid + o];
        __syncthreads();
    }
    float inv = rsqrtf(red[0] * (1.0f / CHALF) + 1e-5f);
    float ht = gelu_exact((acc - mean) * inv * g[tid] + beta[tid]);
    float p[16];
#pragma unroll
    for (int j = 0; j < 16; ++j) p[j] = ht * w2[tid * HH + j];
#pragma unroll
    for (int off = 1; off < 64; off <<= 1)
#pragma unroll
        for (int j = 0; j < 16; ++j) p[j] += __shfl_xor(p[j], off, 64);
    if (lane == 0)
#pragma unroll
        for (int j = 0; j < 16; ++j) wred[wave][j] = p[j];
    __syncthreads();
    if (tid < HH) {
        float s = b2[tid];
#pragma unroll
        for (int w = 0; w < 8; ++w) s += wred[w][tid];
        float sp = fmaxf(s, 0.f) + log1pf(expf(-fabsf(s)));
        temp[b * HH + tid] = sp + 0.5f;
    }
}

// ---------------------------------------------------------------------------
// V global transpose: vb[b*T+t][h*64+d] -> vt[(b*16+h)*64+d][t]
// ---------------------------------------------------------------------------
__global__ __launch_bounds__(256) void transpose_v(
    const short* __restrict__ vb, short* __restrict__ vt) {
    __shared__ short T[64][72];  // [t][d]
    int t0 = blockIdx.x * 64;
    int bh = blockIdx.y;
    int b = bh >> 4, h = bh & 15;
    int tid = threadIdx.x;
#pragma unroll
    for (int p = 0; p < 2; ++p) {
        int idx = p * 256 + tid;
        int r = idx >> 3, c = (idx & 7) * 8;
        *(short8*)&T[r][c] =
            *(const short8*)&vb[(size_t)(b * TT + t0 + r) * CC + h * DD + c];
    }
    __syncthreads();
#pragma unroll
    for (int p = 0; p < 2; ++p) {
        int idx = p * 256 + tid;
        int d = idx >> 3, c = (idx & 7) * 8;
        short8 o;
#pragma unroll
        for (int u = 0; u < 8; ++u) o[u] = T[c + u][d];
        *(short8*)&vt[((size_t)bh * DD + d) * TT + t0 + c] = o;
    }
}

// ---------------------------------------------------------------------------
// MFMA flash attention v4: 64-row q-tile (1024 blocks = 4/CU), transposed-QK
// softmax in exp2 domain (q pre-scaled by temp/8*log2e), V pre-transposed.
// ---------------------------------------------------------------------------
__global__ __launch_bounds__(256) void flash_attn_mfma(
    const short* __restrict__ q, const short* __restrict__ k,
    const short* __restrict__ vt, const int* __restrict__ mask,
    const int* __restrict__ flags, __hip_bfloat16* __restrict__ out) {
    __shared__ short Ks[64][72];   // [key][d]
    __shared__ short Vt[64][72];   // [d][key]
    __shared__ short Ps[64][72];   // [q-row][key], wave-private 16-row strips
    int tid = threadIdx.x;
    int wave = tid >> 6, lane = tid & 63;
    int m16 = lane & 15, quad = lane >> 4;
    int qt = blockIdx.x;
    int q0 = qt * 64;
    int bh = blockIdx.y;
    int b = bh >> 4, h = bh & 15;

    const short* qrow =
        q + ((size_t)(b * TT + q0 + wave * 16 + m16)) * CC + h * DD + quad * 8;
    short8 qf0 = *(const short8*)(qrow);
    short8 qf1 = *(const short8*)(qrow + 32);

    float m_run = -INFINITY, l_run = 0.f;
    f32x4 acc_o[4];
#pragma unroll
    for (int t = 0; t < 4; ++t) acc_o[t] = (f32x4){0.f, 0.f, 0.f, 0.f};

    for (int kt = 0; kt < TT / 64; ++kt) {
        int kb = kt * 64;
#pragma unroll
        for (int i = 0; i < 2; ++i) {
            int idx = i * 256 + tid;
            int r = idx >> 3;
            int dc = (idx & 7) * 8;
            *(short8*)&Ks[r][dc] =
                *(const short8*)(k + ((size_t)(b * TT + kb + r)) * CC + h * DD + dc);
            *(short8*)&Vt[r][dc] =
                *(const short8*)(vt + ((size_t)bh * DD + r) * TT + kb + dc);
        }
        __syncthreads();

        // S^T: lane holds (key = t*16 + quad*4 + r, q = m16), in log2 domain
        f32x4 sacc[4];
#pragma unroll
        for (int t = 0; t < 4; ++t) sacc[t] = (f32x4){0.f, 0.f, 0.f, 0.f};
#pragma unroll
        for (int t = 0; t < 4; ++t) {
            short8 kf0 = *(const short8*)&Ks[t * 16 + m16][quad * 8];
            sacc[t] = __builtin_amdgcn_mfma_f32_16x16x32_bf16(kf0, qf0, sacc[t], 0, 0, 0);
            short8 kf1 = *(const short8*)&Ks[t * 16 + m16][32 + quad * 8];
            sacc[t] = __builtin_amdgcn_mfma_f32_16x16x32_bf16(kf1, qf1, sacc[t], 0, 0, 0);
        }
        float sv[4][4];
#pragma unroll
        for (int t = 0; t < 4; ++t)
#pragma unroll
            for (int r = 0; r < 4; ++r) sv[t][r] = sacc[t][r];
        if (flags[(b * 32 + qt) * 32 + kt] == 0) {
            int qrg = q0 + wave * 16 + m16;
#pragma unroll
            for (int t = 0; t < 4; ++t)
#pragma unroll
                for (int r = 0; r < 4; ++r) {
                    int kg = kb + t * 16 + quad * 4 + r;
                    if (mask[((size_t)(b * TT + qrg)) * TT + kg] == 0)
                        sv[t][r] = -INFINITY;
                }
        }
        float mx = sv[0][0];
#pragma unroll
        for (int t = 0; t < 4; ++t)
#pragma unroll
            for (int r = 0; r < 4; ++r) mx = fmaxf(mx, sv[t][r]);
        mx = fmaxf(mx, __shfl_xor(mx, 16, 64));
        mx = fmaxf(mx, __shfl_xor(mx, 32, 64));
        float mnew = fmaxf(m_run, mx);
        float alpha = exp2f(m_run - mnew);
        m_run = mnew;
        int prow = wave * 16 + m16;
        float psum = 0.f;
#pragma unroll
        for (int t = 0; t < 4; ++t) {
            short4_t pk;
#pragma unroll
            for (int r = 0; r < 4; ++r) {
                float p = exp2f(sv[t][r] - mnew);
                psum += p;
                pk[r] = f2bf(p);
            }
            *(short4_t*)&Ps[prow][t * 16 + quad * 4] = pk;
        }
        psum += __shfl_xor(psum, 16, 64);
        psum += __shfl_xor(psum, 32, 64);
        l_run = l_run * alpha + psum;
#pragma unroll
        for (int r = 0; r < 4; ++r) {
            float ar = __shfl(alpha, (lane & 48) | (quad * 4 + r), 64);
#pragma unroll
            for (int td = 0; td < 4; ++td) acc_o[td][r] *= ar;
        }

        // PV
#pragma unroll
        for (int kc = 0; kc < 2; ++kc) {
            short8 pf = *(const short8*)&Ps[wave * 16 + m16][kc * 32 + quad * 8];
#pragma unroll
            for (int td = 0; td < 4; ++td) {
                short8 vf = *(const short8*)&Vt[td * 16 + m16][kc * 32 + quad * 8];
                acc_o[td] = __builtin_amdgcn_mfma_f32_16x16x32_bf16(
                    pf, vf, acc_o[td], 0, 0, 0);
            }
        }
        __syncthreads();
    }

#pragma unroll
    for (int r = 0; r < 4; ++r) {
        float lr = __shfl(l_run, (lane & 48) | (quad * 4 + r), 64);
        float inv = 1.0f / lr;
        int row = b * TT + q0 + wave * 16 + quad * 4 + r;
#pragma unroll
        for (int td = 0; td < 4; ++td)
            out[(size_t)row * CC + h * DD + td * 16 + m16] =
                __float2bfloat16(acc_o[td][r] * inv);
    }
}

// ---------------------------------------------------------------------------
// Final: out = LN(x + proj)
// ---------------------------------------------------------------------------
__global__ __launch_bounds__(256) void final_ln(
    const float* __restrict__ x, const float* __restrict__ p,
    const float* __restrict__ g, const float* __restrict__ beta,
    float* __restrict__ out) {
    int row = blockIdx.x;
    int tid = threadIdx.x;
    const float* xr = x + (size_t)row * CC;
    const float* pr = p + (size_t)row * CC;
    float v[4];
    float s = 0.f;
#pragma unroll
    for (int i = 0; i < 4; ++i) {
        int c = i * 256 + tid;
        v[i] = xr[c] + pr[c];
        s += v[i];
    }
    __shared__ float red[256];
    red[tid] = s;
    __syncthreads();
#pragma unroll
    for (int o = 128; o > 0; o >>= 1) {
        if (tid < o) red[tid] += red[tid + o];
        __syncthreads();
    }
    float mean = red[0] * (1.0f / CC);
    __syncthreads();
    s = 0.f;
#pragma unroll
    for (int i = 0; i < 4; ++i) {
        float d = v[i] - mean;
        s += d * d;
    }
    red[tid] = s;
    __syncthreads();
#pragma unroll
    for (int o = 128; o > 0; o >>= 1) {
        if (tid < o) red[tid] += red[tid + o];
        __syncthreads();
    }
    float inv = rsqrtf(red[0] * (1.0f / CC) + 1e-5f);
#pragma unroll
    for (int i = 0; i < 4; ++i) {
        int c = i * 256 + tid;
        out[(size_t)row * CC + c] = (v[i] - mean) * inv * g[c] + beta[c];
    }
}

extern "C" void kernel_launch(void* const* d_in, const int* in_sizes, int n_in,
                              void* d_out, int out_size, void* d_ws,
                              size_t ws_size, hipStream_t stream) {
    const float* x        = (const float*)d_in[0];
    const int*   mask     = (const int*)d_in[1];
    const float* imp_w1   = (const float*)d_in[2];
    const float* imp_b1   = (const float*)d_in[3];
    const float* imp_g    = (const float*)d_in[4];
    const float* imp_beta = (const float*)d_in[5];
    const float* imp_w2   = (const float*)d_in[6];
    const float* imp_b2   = (const float*)d_in[7];
    const float* rsn_w1   = (const float*)d_in[8];
    const float* rsn_b1   = (const float*)d_in[9];
    const float* rsn_g    = (const float*)d_in[10];
    const float* rsn_beta = (const float*)d_in[11];
    const float* rsn_w2   = (const float*)d_in[12];
    const float* rsn_b2   = (const float*)d_in[13];
    const float* q_w      = (const float*)d_in[14];
    const float* q_b      = (const float*)d_in[15];
    const float* k_w      = (const float*)d_in[16];
    const float* k_b      = (const float*)d_in[17];
    const float* v_w      = (const float*)d_in[18];
    const float* v_b      = (const float*)d_in[19];
    const float* o_w      = (const float*)d_in[20];
    const float* o_b      = (const float*)d_in[21];
    const float* tmp_w1   = (const float*)d_in[22];
    const float* tmp_b1   = (const float*)d_in[23];
    const float* tmp_g    = (const float*)d_in[24];
    const float* tmp_beta = (const float*)d_in[25];
    const float* tmp_w2   = (const float*)d_in[26];
    const float* tmp_b2   = (const float*)d_in[27];
    const float* norm_g   = (const float*)d_in[28];
    const float* norm_b   = (const float*)d_in[29];
    float* out = (float*)d_out;
    float* ws  = (float*)d_ws;

    // workspace layout (float offsets)
    float* h1  = ws;                       // [4096,512] fp32
    float* h2  = ws + 2097152;             // [4096,1024] fp32 (later o-proj out)
    __hip_bfloat16* x_bf  = (__hip_bfloat16*)(ws + 6291456);
    __hip_bfloat16* xi_bf = (__hip_bfloat16*)(ws + 8388608);
    __hip_bfloat16* h2b   = (__hip_bfloat16*)(ws + 10485760);
    __hip_bfloat16* rs_bf = (__hip_bfloat16*)(ws + 12582912);  // reasoned, later attn out
    __hip_bfloat16* qb    = (__hip_bfloat16*)(ws + 14680064);
    __hip_bfloat16* kb    = (__hip_bfloat16*)(ws + 16777216);
    __hip_bfloat16* vb    = (__hip_bfloat16*)(ws + 18874368);
    __hip_bfloat16* vtb   = (__hip_bfloat16*)(ws + 20971520);  // [32,64,2048]
    __hip_bfloat16* imp_w1t = (__hip_bfloat16*)(ws + 23068672);  // [512,1024]
    __hip_bfloat16* rsn_w1t = (__hip_bfloat16*)(ws + 23330816);  // [1024,1024]
    __hip_bfloat16* rsn_w2t = (__hip_bfloat16*)(ws + 23855104);
    __hip_bfloat16* q_wt    = (__hip_bfloat16*)(ws + 24379392);
    __hip_bfloat16* k_wt    = (__hip_bfloat16*)(ws + 24903680);
    __hip_bfloat16* v_wt    = (__hip_bfloat16*)(ws + 25427968);
    __hip_bfloat16* o_wt    = (__hip_bfloat16*)(ws + 25952256);
    float* tmp  = ws + 26478592;   // [2,16]
    float* part = ws + 26479104;   // [2,16,1024]
    int*   flg  = (int*)(ws + 26511872);  // [2,32,32]
    float* acc1 = ws + 26513920;   // [2,512]

    dim3 blk(256);
    // fused prep: x->bf16, mask flags, 7 weight transposes
    prep<<<5760, blk, 0, stream>>>(
        x, x_bf, mask, flg,
        imp_w1, rsn_w1, rsn_w2, q_w, k_w, v_w, o_w,
        imp_w1t, rsn_w1t, rsn_w2t, q_wt, k_wt, v_wt, o_wt);

    // importance net (GEMM + fused LN/GELU/gate)
    gemm_mfma64<false><<<dim3(CHALF / 128, NN / 64), blk, 0, stream>>>(
        (const short*)x_bf, (const short*)imp_w1t, imp_b1, h1, nullptr, NN, CHALF, CC);
    imp_fused<<<NN, blk, 0, stream>>>(h1, imp_g, imp_beta, imp_w2, imp_b2, x, xi_bf);
    // reasoning net
    gemm_mfma64<false><<<dim3(CC / 128, NN / 64), blk, 0, stream>>>(
        (const short*)xi_bf, (const short*)rsn_w1t, rsn_b1, h2, nullptr, NN, CC, CC);
    ln_gelu_bf16<CC><<<NN, blk, 0, stream>>>(h2, rsn_g, rsn_beta, h2b);
    gemm_mfma64<true><<<dim3(CC / 128, NN / 64), blk, 0, stream>>>(
        (const short*)h2b, (const short*)rsn_w2t, rsn_b2, nullptr, rs_bf, NN, CC, CC);
    // temperature net
    mean_part<<<128, blk, 0, stream>>>(rs_bf, part);
    temp_gemv1<<<dim3(CHALF / 64, BB), blk, 0, stream>>>(part, tmp_w1, tmp_b1, acc1);
    temp_fin<<<BB, dim3(512), 0, stream>>>(acc1, tmp_g, tmp_beta, tmp_w2, tmp_b2, tmp);
    // q/k/v projections batched; q scaled by temp/8*log2e
    gemm_qkv<<<dim3(CC / 128, NN / 128, 3), blk, 0, stream>>>(
        (const short*)rs_bf, (const short*)xi_bf, (const short*)x_bf,
        (const short*)q_wt, (const short*)k_wt, (const short*)v_wt,
        q_b, k_b, v_b, qb, kb, vb, tmp);
    // V transpose
    transpose_v<<<dim3(TT / 64, BB * HH), blk, 0, stream>>>(
        (const short*)vb, (short*)vtb);
    // flash attention v4 (64-row q-tiles, 1024 blocks)
    flash_attn_mfma<<<dim3(TT / 64, BB * HH), blk, 0, stream>>>(
        (const short*)qb, (const short*)kb, (const short*)vtb, mask, flg, rs_bf);
    // output projection + residual LN
    gemm_mfma64<false><<<dim3(CC / 128, NN / 64), blk, 0, stream>>>(
        (const short*)rs_bf, (const short*)o_wt, o_b, h2, nullptr, NN, CC, CC);
    final_ln<<<NN, blk, 0, stream>>>(x, h2, norm_g, norm_b, out);
}

// Round 8
// 441.657 us; speedup vs baseline: 4.2868x; 1.0035x over previous
//
#include <hip/hip_runtime.h>
#include <hip/hip_bf16.h>
#include <math.h>

// Problem constants
#define BB 2
#define TT 2048
#define CC 1024
#define HH 16
#define DD 64
#define CHALF 512
#define NN (BB * TT)   // 4096 rows
#define LOG2E 1.44269504088896340736f

typedef __attribute__((ext_vector_type(8))) short short8;
typedef __attribute__((ext_vector_type(4))) short short4_t;
typedef __attribute__((ext_vector_type(4))) float f32x4;

__device__ __forceinline__ float gelu_exact(float x) {
    return 0.5f * x * (1.0f + erff(x * 0.70710678118654752f));
}

__device__ __forceinline__ short f2bf(float f) {
    __hip_bfloat16 h = __float2bfloat16(f);
    short s;
    __builtin_memcpy(&s, &h, 2);
    return s;
}

// packed f32x4 -> bf16x4 (v_cvt_pk_bf16_f32 x2)
__device__ __forceinline__ short4_t pack_bf16x4(float a, float b, float c,
                                                float d) {
    union {
        __hip_bfloat162 h2[2];
        short4_t s4;
    } u;
    u.h2[0] = __float22bfloat162_rn(make_float2(a, b));
    u.h2[1] = __float22bfloat162_rn(make_float2(c, d));
    return u.s4;
}

// async global->LDS, 16 B per lane; LDS dst must be wave-uniform base
__device__ __forceinline__ void async_copy16(const void* g, void* l) {
    __builtin_amdgcn_global_load_lds(
        (const __attribute__((address_space(1))) void*)g,
        (__attribute__((address_space(3))) void*)l, 16, 0, 0);
}

// ---------------------------------------------------------------------------
// prep: one launch for x->bf16 convert, mask tile flags, 7 weight transposes.
// ---------------------------------------------------------------------------
__global__ __launch_bounds__(256) void prep(
    const float* __restrict__ x, __hip_bfloat16* __restrict__ x_bf,
    const int* __restrict__ mask, int* __restrict__ flags,
    const float* w0, const float* w1, const float* w2, const float* w3,
    const float* w4, const float* w5, const float* w6,
    __hip_bfloat16* t0, __hip_bfloat16* t1, __hip_bfloat16* t2,
    __hip_bfloat16* t3, __hip_bfloat16* t4, __hip_bfloat16* t5,
    __hip_bfloat16* t6) {
    __shared__ float T[64][65];
    int blk = blockIdx.x;
    int tid = threadIdx.x;
    if (blk < 2048) {
        int i = (blk * 256 + tid) * 8;
        float4 a = *(const float4*)&x[i];
        float4 b = *(const float4*)&x[i + 4];
        __hip_bfloat16 o[8] = {
            __float2bfloat16(a.x), __float2bfloat16(a.y),
            __float2bfloat16(a.z), __float2bfloat16(a.w),
            __float2bfloat16(b.x), __float2bfloat16(b.y),
            __float2bfloat16(b.z), __float2bfloat16(b.w)};
        *(float4*)&x_bf[i] = *(float4*)o;
    } else if (blk < 4096) {
        int idx = blk - 2048;
        int kt = idx & 31, qt = (idx >> 5) & 31, b = idx >> 10;
        int* red = (int*)T;
        int r = tid >> 2;
        int c0 = (tid & 3) * 16;
        const int* base =
            mask + ((size_t)(b * TT + qt * 64 + r)) * TT + kt * 64 + c0;
        int all = 1;
#pragma unroll
        for (int i = 0; i < 4; ++i) {
            int4 m4 = *(const int4*)(base + i * 4);
            all &= (m4.x != 0) & (m4.y != 0) & (m4.z != 0) & (m4.w != 0);
        }
        red[tid] = all;
        __syncthreads();
#pragma unroll
        for (int o = 128; o > 0; o >>= 1) {
            if (tid < o) red[tid] &= red[tid + o];
            __syncthreads();
        }
        if (tid == 0) flags[(b * 32 + qt) * 32 + kt] = red[0];
    } else {
        int idx = blk - 4096;
        const float* W;
        __hip_bfloat16* Wt;
        int N, n0, k0;
        if (idx < 128) {
            W = w0; Wt = t0; N = 512;
            n0 = (idx & 7) * 64;
            k0 = (idx >> 3) * 64;
        } else {
            idx -= 128;
            int w = idx >> 8;
            int r = idx & 255;
            N = 1024;
            n0 = (r & 15) * 64;
            k0 = (r >> 4) * 64;
            switch (w) {
                case 0: W = w1; Wt = t1; break;
                case 1: W = w2; Wt = t2; break;
                case 2: W = w3; Wt = t3; break;
                case 3: W = w4; Wt = t4; break;
                case 4: W = w5; Wt = t5; break;
                default: W = w6; Wt = t6; break;
            }
        }
        int c = tid & 63, r4 = tid >> 6;
#pragma unroll
        for (int i = 0; i < 16; ++i) {
            int row = i * 4 + r4;
            T[row][c] = W[(size_t)(k0 + row) * N + n0 + c];
        }
        __syncthreads();
#pragma unroll
        for (int i = 0; i < 16; ++i) {
            int row = i * 4 + r4;  // n index
            Wt[(size_t)(n0 + row) * CC + k0 + c] = __float2bfloat16(T[c][row]);
        }
    }
}

// ---------------------------------------------------------------------------
// bf16 MFMA GEMM, 64x128 tile: C = A @ Wt^T + bias
// ---------------------------------------------------------------------------
template <bool BF16OUT>
__global__ __launch_bounds__(256) void gemm_mfma64(
    const short* __restrict__ A, const short* __restrict__ Wt,
    const float* __restrict__ bias, float* __restrict__ Cf,
    __hip_bfloat16* __restrict__ Cb, int M, int N, int K) {
    __shared__ short As[64][32];
    __shared__ short Bs[128][32];
    int tid = threadIdx.x;
    int wave = tid >> 6, lane = tid & 63;
    int m16 = lane & 15, quad = lane >> 4;
    int wm = wave >> 1, wn = wave & 1;
    int row0 = blockIdx.y * 64, col0 = blockIdx.x * 128;
    int lr = lane >> 2;
    int kof = (lane & 3) * 8;

    f32x4 acc[2][4];
#pragma unroll
    for (int i = 0; i < 2; ++i)
#pragma unroll
        for (int j = 0; j < 4; ++j) acc[i][j] = (f32x4){0.f, 0.f, 0.f, 0.f};

    for (int k0 = 0; k0 < K; k0 += 32) {
        async_copy16(A + (size_t)(row0 + wave * 16 + lr) * K + k0 + kof,
                     &As[wave * 16][0]);
#pragma unroll
        for (int j = 0; j < 2; ++j) {
            int rbase = wave * 32 + j * 16;
            async_copy16(Wt + (size_t)(col0 + rbase + lr) * K + k0 + kof,
                         &Bs[rbase][0]);
        }
        __syncthreads();
        short8 af[2], bfr[4];
#pragma unroll
        for (int i = 0; i < 2; ++i)
            af[i] = *(const short8*)&As[wm * 32 + i * 16 + m16][quad * 8];
#pragma unroll
        for (int j = 0; j < 4; ++j)
            bfr[j] = *(const short8*)&Bs[wn * 64 + j * 16 + m16][quad * 8];
#pragma unroll
        for (int i = 0; i < 2; ++i)
#pragma unroll
            for (int j = 0; j < 4; ++j)
                acc[i][j] = __builtin_amdgcn_mfma_f32_16x16x32_bf16(
                    af[i], bfr[j], acc[i][j], 0, 0, 0);
        __syncthreads();
    }
#pragma unroll
    for (int i = 0; i < 2; ++i) {
#pragma unroll
        for (int j = 0; j < 4; ++j) {
            int col = col0 + wn * 64 + j * 16 + m16;
            float bv = bias[col];
#pragma unroll
            for (int rr = 0; rr < 4; ++rr) {
                int row = row0 + wm * 32 + i * 16 + quad * 4 + rr;
                float val = acc[i][j][rr] + bv;
                if (BF16OUT)
                    Cb[(size_t)row * N + col] = __float2bfloat16(val);
                else
                    Cf[(size_t)row * N + col] = val;
            }
        }
    }
}

// ---------------------------------------------------------------------------
// Batched q/k/v projections, 128x128 tile.
// z=0: q scaled by temp/8*log2e -> Cq [row][col]
// z=1: k -> Ck [row][col]
// z=2: v -> written TRANSPOSED into Cv = vt[(b*16+h)*64+d][t] (b64 stores)
// ---------------------------------------------------------------------------
__global__ __launch_bounds__(256) void gemm_qkv(
    const short* __restrict__ Aq, const short* __restrict__ Ak,
    const short* __restrict__ Av, const short* __restrict__ Wq,
    const short* __restrict__ Wk, const short* __restrict__ Wv,
    const float* __restrict__ bq, const float* __restrict__ bk,
    const float* __restrict__ bv, __hip_bfloat16* __restrict__ Cq,
    __hip_bfloat16* __restrict__ Ck, __hip_bfloat16* __restrict__ Cv,
    const float* __restrict__ tmp) {
    int z = blockIdx.z;
    const short* A = (z == 0) ? Aq : (z == 1) ? Ak : Av;
    const short* Wt = (z == 0) ? Wq : (z == 1) ? Wk : Wv;
    const float* bias = (z == 0) ? bq : (z == 1) ? bk : bv;

    __shared__ short As[128][32];
    __shared__ short Bs[128][32];
    int tid = threadIdx.x;
    int wave = tid >> 6, lane = tid & 63;
    int m16 = lane & 15, quad = lane >> 4;
    int wm = wave >> 1, wn = wave & 1;
    int row0 = blockIdx.y * 128, col0 = blockIdx.x * 128;
    int lr = lane >> 2;
    int kof = (lane & 3) * 8;

    float scale = 1.0f;
    if (z == 0)
        scale = tmp[(row0 >> 11) * HH + (col0 >> 6) + wn] * 0.125f * LOG2E;

    f32x4 acc[4][4];
#pragma unroll
    for (int i = 0; i < 4; ++i)
#pragma unroll
        for (int j = 0; j < 4; ++j) acc[i][j] = (f32x4){0.f, 0.f, 0.f, 0.f};

    for (int k0 = 0; k0 < CC; k0 += 32) {
#pragma unroll
        for (int j = 0; j < 2; ++j) {
            int rbase = wave * 32 + j * 16;
            async_copy16(A + (size_t)(row0 + rbase + lr) * CC + k0 + kof,
                         &As[rbase][0]);
            async_copy16(Wt + (size_t)(col0 + rbase + lr) * CC + k0 + kof,
                         &Bs[rbase][0]);
        }
        __syncthreads();
        short8 af[4], bfr[4];
#pragma unroll
        for (int i = 0; i < 4; ++i)
            af[i] = *(const short8*)&As[wm * 64 + i * 16 + m16][quad * 8];
#pragma unroll
        for (int j = 0; j < 4; ++j)
            bfr[j] = *(const short8*)&Bs[wn * 64 + j * 16 + m16][quad * 8];
#pragma unroll
        for (int i = 0; i < 4; ++i)
#pragma unroll
            for (int j = 0; j < 4; ++j)
                acc[i][j] = __builtin_amdgcn_mfma_f32_16x16x32_bf16(
                    af[i], bfr[j], acc[i][j], 0, 0, 0);
        __syncthreads();
    }
    if (z == 2) {
        // transposed V write: 4 consecutive t per lane -> one b64 store
        int b = row0 >> 11;
        int t0r = (row0 & (TT - 1)) + wm * 64 + quad * 4;
#pragma unroll
        for (int i = 0; i < 4; ++i) {
#pragma unroll
            for (int j = 0; j < 4; ++j) {
                int col = col0 + wn * 64 + j * 16 + m16;
                int h = col >> 6, d = col & 63;
                float bv2 = bias[col];
                short4_t pk = pack_bf16x4(
                    acc[i][j][0] + bv2, acc[i][j][1] + bv2,
                    acc[i][j][2] + bv2, acc[i][j][3] + bv2);
                *(short4_t*)&Cv[(((size_t)(b * HH + h) * DD) + d) * TT + t0r +
                                i * 16] = pk;
            }
        }
    } else {
        __hip_bfloat16* C = (z == 0) ? Cq : Ck;
#pragma unroll
        for (int i = 0; i < 4; ++i) {
#pragma unroll
            for (int j = 0; j < 4; ++j) {
                int col = col0 + wn * 64 + j * 16 + m16;
                float bv2 = bias[col];
#pragma unroll
                for (int rr = 0; rr < 4; ++rr) {
                    int row = row0 + wm * 64 + i * 16 + quad * 4 + rr;
                    C[(size_t)row * CC + col] =
                        __float2bfloat16((acc[i][j][rr] + bv2) * scale);
                }
            }
        }
    }
}

// ---------------------------------------------------------------------------
// fused importance epilogue: LN(h1)+GELU -> dot w2 -> sigmoid -> xi = x*imp
// ---------------------------------------------------------------------------
__global__ __launch_bounds__(256) void imp_fused(
    const float* __restrict__ h1, const float* __restrict__ g,
    const float* __restrict__ beta, const float* __restrict__ w2,
    const float* __restrict__ b2, const float* __restrict__ x,
    __hip_bfloat16* __restrict__ xi) {
    int row = blockIdx.x;
    int tid = threadIdx.x;
    const float* hr = h1 + (size_t)row * CHALF;
    float v0 = hr[tid], v1 = hr[tid + 256];
    __shared__ float red[256];
    red[tid] = v0 + v1;
    __syncthreads();
#pragma unroll
    for (int o = 128; o > 0; o >>= 1) {
        if (tid < o) red[tid] += red[tid + o];
        __syncthreads();
    }
    float mean = red[0] * (1.0f / CHALF);
    __syncthreads();
    float d0 = v0 - mean, d1 = v1 - mean;
    red[tid] = d0 * d0 + d1 * d1;
    __syncthreads();
#pragma unroll
    for (int o = 128; o > 0; o >>= 1) {
        if (tid < o) red[tid] += red[tid + o];
        __syncthreads();
    }
    float inv = rsqrtf(red[0] * (1.0f / CHALF) + 1e-5f);
    __syncthreads();
    float ge0 = gelu_exact(d0 * inv * g[tid] + beta[tid]);
    float ge1 = gelu_exact(d1 * inv * g[tid + 256] + beta[tid + 256]);
    red[tid] = ge0 * w2[tid] + ge1 * w2[tid + 256];
    __syncthreads();
#pragma unroll
    for (int o = 128; o > 0; o >>= 1) {
        if (tid < o) red[tid] += red[tid + o];
        __syncthreads();
    }
    float z = red[0] + b2[0];
    float sg = 1.0f / (1.0f + expf(-z));
    float imp = fmaxf(sg, 1e-6f);
#pragma unroll
    for (int i = 0; i < 4; ++i) {
        int c = i * 256 + tid;
        xi[(size_t)row * CC + c] =
            __float2bfloat16(x[(size_t)row * CC + c] * imp);
    }
}

// ---------------------------------------------------------------------------
// LN + GELU fp32 in -> bf16 out (for h2 -> h2b)
// ---------------------------------------------------------------------------
template <int WIDTH>
__global__ __launch_bounds__(256) void ln_gelu_bf16(
    const float* __restrict__ Y, const float* __restrict__ g,
    const float* __restrict__ beta, __hip_bfloat16* __restrict__ O) {
    constexpr int PT = WIDTH / 256;
    int row = blockIdx.x;
    int tid = threadIdx.x;
    const float* yr = Y + (size_t)row * WIDTH;
    float v[PT];
    float s = 0.f;
#pragma unroll
    for (int i = 0; i < PT; ++i) {
        v[i] = yr[i * 256 + tid];
        s += v[i];
    }
    __shared__ float red[256];
    red[tid] = s;
    __syncthreads();
#pragma unroll
    for (int o = 128; o > 0; o >>= 1) {
        if (tid < o) red[tid] += red[tid + o];
        __syncthreads();
    }
    float mean = red[0] * (1.0f / WIDTH);
    __syncthreads();
    s = 0.f;
#pragma unroll
    for (int i = 0; i < PT; ++i) {
        float d = v[i] - mean;
        s += d * d;
    }
    red[tid] = s;
    __syncthreads();
#pragma unroll
    for (int o = 128; o > 0; o >>= 1) {
        if (tid < o) red[tid] += red[tid + o];
        __syncthreads();
    }
    float inv = rsqrtf(red[0] * (1.0f / WIDTH) + 1e-5f);
#pragma unroll
    for (int i = 0; i < PT; ++i) {
        int c = i * 256 + tid;
        O[(size_t)row * WIDTH + c] =
            __float2bfloat16(gelu_exact((v[i] - mean) * inv * g[c] + beta[c]));
    }
}

// ---------------------------------------------------------------------------
// reasoned.mean(axis=1), stage 1 (partials over 128-row chunks)
// ---------------------------------------------------------------------------
__global__ __launch_bounds__(256) void mean_part(
    const __hip_bfloat16* __restrict__ R, float* __restrict__ part) {
    int idx = blockIdx.x * 256 + threadIdx.x;
    int c = idx & (CC - 1);
    int chunk = (idx >> 10) & 15;
    int b = idx >> 14;
    const __hip_bfloat16* base = R + ((size_t)(b * TT + chunk * 128)) * CC + c;
    float s = 0.f;
    for (int t = 0; t < 128; ++t) s += __bfloat162float(base[(size_t)t * CC]);
    part[idx] = s;
}

// ---------------------------------------------------------------------------
// temp_net stage 1 (+ fused mean finalize): acc1[b,col] = rm @ w1 + b1
// ---------------------------------------------------------------------------
__global__ __launch_bounds__(256) void temp_gemv1(
    const float* __restrict__ part, const float* __restrict__ w1,
    const float* __restrict__ b1, float* __restrict__ acc1) {
    __shared__ float rm_l[CC];
    __shared__ float red[256];
    int b = blockIdx.y;
    int c0 = blockIdx.x * 64;
    int tid = threadIdx.x;
    for (int cc = tid; cc < CC; cc += 256) {
        float s = 0.f;
#pragma unroll
        for (int ch = 0; ch < 16; ++ch)
            s += part[(size_t)(b * 16 + ch) * CC + cc];
        rm_l[cc] = s * (1.0f / TT);
    }
    __syncthreads();
    int col = c0 + (tid & 63);
    int kq = tid >> 6;  // 0..3
    float s = 0.f;
#pragma unroll 8
    for (int i = kq * 256; i < kq * 256 + 256; ++i)
        s = fmaf(rm_l[i], w1[(size_t)i * CHALF + col], s);
    red[tid] = s;
    __syncthreads();
    if (tid < 64) {
        float t = red[tid] + red[tid + 64] + red[tid + 128] + red[tid + 192];
        acc1[b * CHALF + tid + c0] = t + b1[col];
    }
}

// ---------------------------------------------------------------------------
// temp_net stage 2: LN(acc1) -> GELU -> @w2 + b2 -> softplus + 0.5
// ---------------------------------------------------------------------------
__global__ __launch_bounds__(512) void temp_fin(
    const float* __restrict__ acc1, const float* __restrict__ g,
    const float* __restrict__ beta, const float* __restrict__ w2,
    const float* __restrict__ b2, float* __restrict__ temp) {
    __shared__ float red[512];
    __shared__ float wred[8][16];
    int b = blockIdx.x;
    int tid = threadIdx.x;
    int wave = tid >> 6, lane = tid & 63;
    float acc = acc1[b * CHALF + tid];
    red[tid] = acc;
    __syncthreads();
#pragma unroll
    for (int o = 256; o > 0; o >>= 1) {
        if (tid < o) red[tid] += red[tid + o];
        __syncthreads();
    }
    float mean = red[0] * (1.0f / CHALF);
    __syncthreads();
    float d = acc - mean;
    red[tid] = d * d;
    __syncthreads();
#pragma unroll
    for (int o = 256; o > 0; o >>= 1) {
        if (tid < o) red[tid] += red[tid + o];
        __syncthreads();
    }
    float inv = rsqrtf(red[0] * (1.0f / CHALF) + 1e-5f);
    float ht = gelu_exact((acc - mean) * inv * g[tid] + beta[tid]);
    float p[16];
#pragma unroll
    for (int j = 0; j < 16; ++j) p[j] = ht * w2[tid * HH + j];
#pragma unroll
    for (int off = 1; off < 64; off <<= 1)
#pragma unroll
        for (int j = 0; j < 16; ++j) p[j] += __shfl_xor(p[j], off, 64);
    if (lane == 0)
#pragma unroll
        for (int j = 0; j < 16; ++j) wred[wave][j] = p[j];
    __syncthreads();
    if (tid < HH) {
        float s = b2[tid];
#pragma unroll
        for (int w = 0; w < 8; ++w) s += wred[w][tid];
        float sp = fmaxf(s, 0.f) + log1pf(expf(-fabsf(s)));
        temp[b * HH + tid] = sp + 0.5f;
    }
}

// ---------------------------------------------------------------------------
// MFMA flash attention v5: 128-row q-tile (best measured shape), transposed-QK
// softmax in exp2 domain (q pre-scaled), V pre-transposed, packed bf16 cvt.
// ---------------------------------------------------------------------------
__global__ __launch_bounds__(256) void flash_attn_mfma(
    const short* __restrict__ q, const short* __restrict__ k,
    const short* __restrict__ vt, const int* __restrict__ mask,
    const int* __restrict__ flags, __hip_bfloat16* __restrict__ out) {
    __shared__ short Ks[64][72];    // [key][d]
    __shared__ short Vt[64][72];    // [d][key]
    __shared__ short Ps[128][72];   // [q-row][key], wave-private strips
    int tid = threadIdx.x;
    int wave = tid >> 6, lane = tid & 63;
    int m16 = lane & 15, quad = lane >> 4;
    int qt = blockIdx.x;            // 128-row q tile
    int q0 = qt * 128;
    int bh = blockIdx.y;
    int b = bh >> 4, h = bh & 15;

    short8 qf[2][2];
#pragma unroll
    for (int qg = 0; qg < 2; ++qg) {
        const short* qrow = q + ((size_t)(b * TT + q0 + wave * 32 + qg * 16 + m16)) * CC +
                            h * DD + quad * 8;
        qf[qg][0] = *(const short8*)(qrow);
        qf[qg][1] = *(const short8*)(qrow + 32);
    }

    float m_run[2] = {-INFINITY, -INFINITY};
    float l_run[2] = {0.f, 0.f};
    f32x4 acc_o[2][4];
#pragma unroll
    for (int qg = 0; qg < 2; ++qg)
#pragma unroll
        for (int t = 0; t < 4; ++t) acc_o[qg][t] = (f32x4){0.f, 0.f, 0.f, 0.f};

    for (int kt = 0; kt < TT / 64; ++kt) {
        int kb = kt * 64;
        // stage K rows and Vt rows (both coalesced b128)
#pragma unroll
        for (int i = 0; i < 2; ++i) {
            int idx = i * 256 + tid;
            int r = idx >> 3;
            int dc = (idx & 7) * 8;
            *(short8*)&Ks[r][dc] =
                *(const short8*)(k + ((size_t)(b * TT + kb + r)) * CC + h * DD + dc);
            *(short8*)&Vt[r][dc] =
                *(const short8*)(vt + ((size_t)bh * DD + r) * TT + kb + dc);
        }
        __syncthreads();

        short8 kf[4][2];
#pragma unroll
        for (int t = 0; t < 4; ++t) {
            kf[t][0] = *(const short8*)&Ks[t * 16 + m16][quad * 8];
            kf[t][1] = *(const short8*)&Ks[t * 16 + m16][32 + quad * 8];
        }
        int fl = flags[(b * 32 + 2 * qt + (wave >> 1)) * 32 + kt];

#pragma unroll
        for (int qg = 0; qg < 2; ++qg) {
            // S^T tiles: lane holds key = t*16 + quad*4 + r, q = m16
            f32x4 sacc[4];
#pragma unroll
            for (int t = 0; t < 4; ++t) sacc[t] = (f32x4){0.f, 0.f, 0.f, 0.f};
#pragma unroll
            for (int t = 0; t < 4; ++t) {
                sacc[t] = __builtin_amdgcn_mfma_f32_16x16x32_bf16(kf[t][0], qf[qg][0], sacc[t], 0, 0, 0);
                sacc[t] = __builtin_amdgcn_mfma_f32_16x16x32_bf16(kf[t][1], qf[qg][1], sacc[t], 0, 0, 0);
            }
            float sv[4][4];
#pragma unroll
            for (int t = 0; t < 4; ++t)
#pragma unroll
                for (int r = 0; r < 4; ++r) sv[t][r] = sacc[t][r];
            if (fl == 0) {
                int qrow = q0 + wave * 32 + qg * 16 + m16;
#pragma unroll
                for (int t = 0; t < 4; ++t)
#pragma unroll
                    for (int r = 0; r < 4; ++r) {
                        int kg = kb + t * 16 + quad * 4 + r;
                        if (mask[((size_t)(b * TT + qrow)) * TT + kg] == 0)
                            sv[t][r] = -INFINITY;
                    }
            }
            float mx = sv[0][0];
#pragma unroll
            for (int t = 0; t < 4; ++t)
#pragma unroll
                for (int r = 0; r < 4; ++r) mx = fmaxf(mx, sv[t][r]);
            mx = fmaxf(mx, __shfl_xor(mx, 16, 64));
            mx = fmaxf(mx, __shfl_xor(mx, 32, 64));
            float mnew = fmaxf(m_run[qg], mx);
            float alpha = exp2f(m_run[qg] - mnew);
            m_run[qg] = mnew;
            int prow = wave * 32 + qg * 16 + m16;
            float psum = 0.f;
#pragma unroll
            for (int t = 0; t < 4; ++t) {
                float p0 = exp2f(sv[t][0] - mnew);
                float p1 = exp2f(sv[t][1] - mnew);
                float p2 = exp2f(sv[t][2] - mnew);
                float p3 = exp2f(sv[t][3] - mnew);
                psum += (p0 + p1) + (p2 + p3);
                *(short4_t*)&Ps[prow][t * 16 + quad * 4] =
                    pack_bf16x4(p0, p1, p2, p3);
            }
            psum += __shfl_xor(psum, 16, 64);
            psum += __shfl_xor(psum, 32, 64);
            l_run[qg] = l_run[qg] * alpha + psum;
#pragma unroll
            for (int r = 0; r < 4; ++r) {
                float ar = __shfl(alpha, (lane & 48) | (quad * 4 + r), 64);
#pragma unroll
                for (int td = 0; td < 4; ++td) acc_o[qg][td][r] *= ar;
            }
        }

        // PV: V fragments shared across q-groups
#pragma unroll
        for (int kc = 0; kc < 2; ++kc) {
            short8 vf[4];
#pragma unroll
            for (int td = 0; td < 4; ++td)
                vf[td] = *(const short8*)&Vt[td * 16 + m16][kc * 32 + quad * 8];
#pragma unroll
            for (int qg = 0; qg < 2; ++qg) {
                short8 pf = *(const short8*)&Ps[wave * 32 + qg * 16 + m16][kc * 32 + quad * 8];
#pragma unroll
                for (int td = 0; td < 4; ++td)
                    acc_o[qg][td] = __builtin_amdgcn_mfma_f32_16x16x32_bf16(
                        pf, vf[td], acc_o[qg][td], 0, 0, 0);
            }
        }
        __syncthreads();
    }

#pragma unroll
    for (int qg = 0; qg < 2; ++qg) {
#pragma unroll
        for (int r = 0; r < 4; ++r) {
            float lr = __shfl(l_run[qg], (lane & 48) | (quad * 4 + r), 64);
            float inv = 1.0f / lr;
            int row = b * TT + q0 + wave * 32 + qg * 16 + quad * 4 + r;
#pragma unroll
            for (int td = 0; td < 4; ++td)
                out[(size_t)row * CC + h * DD + td * 16 + m16] =
                    __float2bfloat16(acc_o[qg][td][r] * inv);
        }
    }
}

// ---------------------------------------------------------------------------
// Final: out = LN(x + proj)
// ---------------------------------------------------------------------------
__global__ __launch_bounds__(256) void final_ln(
    const float* __restrict__ x, const float* __restrict__ p,
    const float* __restrict__ g, const float* __restrict__ beta,
    float* __restrict__ out) {
    int row = blockIdx.x;
    int tid = threadIdx.x;
    const float* xr = x + (size_t)row * CC;
    const float* pr = p + (size_t)row * CC;
    float v[4];
    float s = 0.f;
#pragma unroll
    for (int i = 0; i < 4; ++i) {
        int c = i * 256 + tid;
        v[i] = xr[c] + pr[c];
        s += v[i];
    }
    __shared__ float red[256];
    red[tid] = s;
    __syncthreads();
#pragma unroll
    for (int o = 128; o > 0; o >>= 1) {
        if (tid < o) red[tid] += red[tid + o];
        __syncthreads();
    }
    float mean = red[0] * (1.0f / CC);
    __syncthreads();
    s = 0.f;
#pragma unroll
    for (int i = 0; i < 4; ++i) {
        float d = v[i] - mean;
        s += d * d;
    }
    red[tid] = s;
    __syncthreads();
#pragma unroll
    for (int o = 128; o > 0; o >>= 1) {
        if (tid < o) red[tid] += red[tid + o];
        __syncthreads();
    }
    float inv = rsqrtf(red[0] * (1.0f / CC) + 1e-5f);
#pragma unroll
    for (int i = 0; i < 4; ++i) {
        int c = i * 256 + tid;
        out[(size_t)row * CC + c] = (v[i] - mean) * inv * g[c] + beta[c];
    }
}

extern "C" void kernel_launch(void* const* d_in, const int* in_sizes, int n_in,
                              void* d_out, int out_size, void* d_ws,
                              size_t ws_size, hipStream_t stream) {
    const float* x        = (const float*)d_in[0];
    const int*   mask     = (const int*)d_in[1];
    const float* imp_w1   = (const float*)d_in[2];
    const float* imp_b1   = (const float*)d_in[3];
    const float* imp_g    = (const float*)d_in[4];
    const float* imp_beta = (const float*)d_in[5];
    const float* imp_w2   = (const float*)d_in[6];
    const float* imp_b2   = (const float*)d_in[7];
    const float* rsn_w1   = (const float*)d_in[8];
    const float* rsn_b1   = (const float*)d_in[9];
    const float* rsn_g    = (const float*)d_in[10];
    const float* rsn_beta = (const float*)d_in[11];
    const float* rsn_w2   = (const float*)d_in[12];
    const float* rsn_b2   = (const float*)d_in[13];
    const float* q_w      = (const float*)d_in[14];
    const float* q_b      = (const float*)d_in[15];
    const float* k_w      = (const float*)d_in[16];
    const float* k_b      = (const float*)d_in[17];
    const float* v_w      = (const float*)d_in[18];
    const float* v_b      = (const float*)d_in[19];
    const float* o_w      = (const float*)d_in[20];
    const float* o_b      = (const float*)d_in[21];
    const float* tmp_w1   = (const float*)d_in[22];
    const float* tmp_b1   = (const float*)d_in[23];
    const float* tmp_g    = (const float*)d_in[24];
    const float* tmp_beta = (const float*)d_in[25];
    const float* tmp_w2   = (const float*)d_in[26];
    const float* tmp_b2   = (const float*)d_in[27];
    const float* norm_g   = (const float*)d_in[28];
    const float* norm_b   = (const float*)d_in[29];
    float* out = (float*)d_out;
    float* ws  = (float*)d_ws;

    // workspace layout (float offsets)
    float* h1  = ws;                       // [4096,512] fp32
    float* h2  = ws + 2097152;             // [4096,1024] fp32 (later o-proj out)
    __hip_bfloat16* x_bf  = (__hip_bfloat16*)(ws + 6291456);
    __hip_bfloat16* xi_bf = (__hip_bfloat16*)(ws + 8388608);
    __hip_bfloat16* h2b   = (__hip_bfloat16*)(ws + 10485760);
    __hip_bfloat16* rs_bf = (__hip_bfloat16*)(ws + 12582912);  // reasoned, later attn out
    __hip_bfloat16* qb    = (__hip_bfloat16*)(ws + 14680064);
    __hip_bfloat16* kb    = (__hip_bfloat16*)(ws + 16777216);
    __hip_bfloat16* vtb   = (__hip_bfloat16*)(ws + 20971520);  // [32,64,2048]
    __hip_bfloat16* imp_w1t = (__hip_bfloat16*)(ws + 23068672);  // [512,1024]
    __hip_bfloat16* rsn_w1t = (__hip_bfloat16*)(ws + 23330816);  // [1024,1024]
    __hip_bfloat16* rsn_w2t = (__hip_bfloat16*)(ws + 23855104);
    __hip_bfloat16* q_wt    = (__hip_bfloat16*)(ws + 24379392);
    __hip_bfloat16* k_wt    = (__hip_bfloat16*)(ws + 24903680);
    __hip_bfloat16* v_wt    = (__hip_bfloat16*)(ws + 25427968);
    __hip_bfloat16* o_wt    = (__hip_bfloat16*)(ws + 25952256);
    float* tmp  = ws + 26478592;   // [2,16]
    float* part = ws + 26479104;   // [2,16,1024]
    int*   flg  = (int*)(ws + 26511872);  // [2,32,32]
    float* acc1 = ws + 26513920;   // [2,512]

    dim3 blk(256);
    // fused prep: x->bf16, mask flags, 7 weight transposes
    prep<<<5760, blk, 0, stream>>>(
        x, x_bf, mask, flg,
        imp_w1, rsn_w1, rsn_w2, q_w, k_w, v_w, o_w,
        imp_w1t, rsn_w1t, rsn_w2t, q_wt, k_wt, v_wt, o_wt);

    // importance net (GEMM + fused LN/GELU/gate)
    gemm_mfma64<false><<<dim3(CHALF / 128, NN / 64), blk, 0, stream>>>(
        (const short*)x_bf, (const short*)imp_w1t, imp_b1, h1, nullptr, NN, CHALF, CC);
    imp_fused<<<NN, blk, 0, stream>>>(h1, imp_g, imp_beta, imp_w2, imp_b2, x, xi_bf);
    // reasoning net
    gemm_mfma64<false><<<dim3(CC / 128, NN / 64), blk, 0, stream>>>(
        (const short*)xi_bf, (const short*)rsn_w1t, rsn_b1, h2, nullptr, NN, CC, CC);
    ln_gelu_bf16<CC><<<NN, blk, 0, stream>>>(h2, rsn_g, rsn_beta, h2b);
    gemm_mfma64<true><<<dim3(CC / 128, NN / 64), blk, 0, stream>>>(
        (const short*)h2b, (const short*)rsn_w2t, rsn_b2, nullptr, rs_bf, NN, CC, CC);
    // temperature net
    mean_part<<<128, blk, 0, stream>>>(rs_bf, part);
    temp_gemv1<<<dim3(CHALF / 64, BB), blk, 0, stream>>>(part, tmp_w1, tmp_b1, acc1);
    temp_fin<<<BB, dim3(512), 0, stream>>>(acc1, tmp_g, tmp_beta, tmp_w2, tmp_b2, tmp);
    // q/k/v projections batched; q scaled by temp/8*log2e; v written transposed
    gemm_qkv<<<dim3(CC / 128, NN / 128, 3), blk, 0, stream>>>(
        (const short*)rs_bf, (const short*)xi_bf, (const short*)x_bf,
        (const short*)q_wt, (const short*)k_wt, (const short*)v_wt,
        q_b, k_b, v_b, qb, kb, vtb, tmp);
    // flash attention v5 (128-row q-tiles)
    flash_attn_mfma<<<dim3(TT / 128, BB * HH), blk, 0, stream>>>(
        (const short*)qb, (const short*)kb, (const short*)vtb, mask, flg, rs_bf);
    // output projection + residual LN
    gemm_mfma64<false><<<dim3(CC / 128, NN / 64), blk, 0, stream>>>(
        (const short*)rs_bf, (const short*)o_wt, o_b, h2, nullptr, NN, CC, CC);
    final_ln<<<NN, blk, 0, stream>>>(x, h2, norm_g, norm_b, out);
}

// Round 9
// 424.500 us; speedup vs baseline: 4.4601x; 1.0404x over previous
//
#include <hip/hip_runtime.h>
#include <hip/hip_bf16.h>
#include <math.h>

// Problem constants
#define BB 2
#define TT 2048
#define CC 1024
#define HH 16
#define DD 64
#define CHALF 512
#define NN (BB * TT)   // 4096 rows
#define LOG2E 1.44269504088896340736f

typedef __attribute__((ext_vector_type(8))) short short8;
typedef __attribute__((ext_vector_type(4))) short short4_t;
typedef __attribute__((ext_vector_type(4))) float f32x4;

__device__ __forceinline__ float gelu_exact(float x) {
    return 0.5f * x * (1.0f + erff(x * 0.70710678118654752f));
}

__device__ __forceinline__ short f2bf(float f) {
    __hip_bfloat16 h = __float2bfloat16(f);
    short s;
    __builtin_memcpy(&s, &h, 2);
    return s;
}

// packed f32x4 -> bf16x4 (used only in qkv epilogue, off critical path)
__device__ __forceinline__ short4_t pack_bf16x4(float a, float b, float c,
                                                float d) {
    short4_t s4;
    s4[0] = f2bf(a);
    s4[1] = f2bf(b);
    s4[2] = f2bf(c);
    s4[3] = f2bf(d);
    return s4;
}

// async global->LDS, 16 B per lane; LDS dst must be wave-uniform base
__device__ __forceinline__ void async_copy16(const void* g, void* l) {
    __builtin_amdgcn_global_load_lds(
        (const __attribute__((address_space(1))) void*)g,
        (__attribute__((address_space(3))) void*)l, 16, 0, 0);
}

// ---------------------------------------------------------------------------
// prep: one launch for x->bf16 convert, mask tile flags, 7 weight transposes.
// ---------------------------------------------------------------------------
__global__ __launch_bounds__(256) void prep(
    const float* __restrict__ x, __hip_bfloat16* __restrict__ x_bf,
    const int* __restrict__ mask, int* __restrict__ flags,
    const float* w0, const float* w1, const float* w2, const float* w3,
    const float* w4, const float* w5, const float* w6,
    __hip_bfloat16* t0, __hip_bfloat16* t1, __hip_bfloat16* t2,
    __hip_bfloat16* t3, __hip_bfloat16* t4, __hip_bfloat16* t5,
    __hip_bfloat16* t6) {
    __shared__ float T[64][65];
    int blk = blockIdx.x;
    int tid = threadIdx.x;
    if (blk < 2048) {
        int i = (blk * 256 + tid) * 8;
        float4 a = *(const float4*)&x[i];
        float4 b = *(const float4*)&x[i + 4];
        __hip_bfloat16 o[8] = {
            __float2bfloat16(a.x), __float2bfloat16(a.y),
            __float2bfloat16(a.z), __float2bfloat16(a.w),
            __float2bfloat16(b.x), __float2bfloat16(b.y),
            __float2bfloat16(b.z), __float2bfloat16(b.w)};
        *(float4*)&x_bf[i] = *(float4*)o;
    } else if (blk < 4096) {
        int idx = blk - 2048;
        int kt = idx & 31, qt = (idx >> 5) & 31, b = idx >> 10;
        int* red = (int*)T;
        int r = tid >> 2;
        int c0 = (tid & 3) * 16;
        const int* base =
            mask + ((size_t)(b * TT + qt * 64 + r)) * TT + kt * 64 + c0;
        int all = 1;
#pragma unroll
        for (int i = 0; i < 4; ++i) {
            int4 m4 = *(const int4*)(base + i * 4);
            all &= (m4.x != 0) & (m4.y != 0) & (m4.z != 0) & (m4.w != 0);
        }
        red[tid] = all;
        __syncthreads();
#pragma unroll
        for (int o = 128; o > 0; o >>= 1) {
            if (tid < o) red[tid] &= red[tid + o];
            __syncthreads();
        }
        if (tid == 0) flags[(b * 32 + qt) * 32 + kt] = red[0];
    } else {
        int idx = blk - 4096;
        const float* W;
        __hip_bfloat16* Wt;
        int N, n0, k0;
        if (idx < 128) {
            W = w0; Wt = t0; N = 512;
            n0 = (idx & 7) * 64;
            k0 = (idx >> 3) * 64;
        } else {
            idx -= 128;
            int w = idx >> 8;
            int r = idx & 255;
            N = 1024;
            n0 = (r & 15) * 64;
            k0 = (r >> 4) * 64;
            switch (w) {
                case 0: W = w1; Wt = t1; break;
                case 1: W = w2; Wt = t2; break;
                case 2: W = w3; Wt = t3; break;
                case 3: W = w4; Wt = t4; break;
                case 4: W = w5; Wt = t5; break;
                default: W = w6; Wt = t6; break;
            }
        }
        int c = tid & 63, r4 = tid >> 6;
#pragma unroll
        for (int i = 0; i < 16; ++i) {
            int row = i * 4 + r4;
            T[row][c] = W[(size_t)(k0 + row) * N + n0 + c];
        }
        __syncthreads();
#pragma unroll
        for (int i = 0; i < 16; ++i) {
            int row = i * 4 + r4;  // n index
            Wt[(size_t)(n0 + row) * CC + k0 + c] = __float2bfloat16(T[c][row]);
        }
    }
}

// ---------------------------------------------------------------------------
// bf16 MFMA GEMM, 64x128 tile: C = A @ Wt^T + bias
// ---------------------------------------------------------------------------
template <bool BF16OUT>
__global__ __launch_bounds__(256) void gemm_mfma64(
    const short* __restrict__ A, const short* __restrict__ Wt,
    const float* __restrict__ bias, float* __restrict__ Cf,
    __hip_bfloat16* __restrict__ Cb, int M, int N, int K) {
    __shared__ short As[64][32];
    __shared__ short Bs[128][32];
    int tid = threadIdx.x;
    int wave = tid >> 6, lane = tid & 63;
    int m16 = lane & 15, quad = lane >> 4;
    int wm = wave >> 1, wn = wave & 1;
    int row0 = blockIdx.y * 64, col0 = blockIdx.x * 128;
    int lr = lane >> 2;
    int kof = (lane & 3) * 8;

    f32x4 acc[2][4];
#pragma unroll
    for (int i = 0; i < 2; ++i)
#pragma unroll
        for (int j = 0; j < 4; ++j) acc[i][j] = (f32x4){0.f, 0.f, 0.f, 0.f};

    for (int k0 = 0; k0 < K; k0 += 32) {
        async_copy16(A + (size_t)(row0 + wave * 16 + lr) * K + k0 + kof,
                     &As[wave * 16][0]);
#pragma unroll
        for (int j = 0; j < 2; ++j) {
            int rbase = wave * 32 + j * 16;
            async_copy16(Wt + (size_t)(col0 + rbase + lr) * K + k0 + kof,
                         &Bs[rbase][0]);
        }
        __syncthreads();
        short8 af[2], bfr[4];
#pragma unroll
        for (int i = 0; i < 2; ++i)
            af[i] = *(const short8*)&As[wm * 32 + i * 16 + m16][quad * 8];
#pragma unroll
        for (int j = 0; j < 4; ++j)
            bfr[j] = *(const short8*)&Bs[wn * 64 + j * 16 + m16][quad * 8];
#pragma unroll
        for (int i = 0; i < 2; ++i)
#pragma unroll
            for (int j = 0; j < 4; ++j)
                acc[i][j] = __builtin_amdgcn_mfma_f32_16x16x32_bf16(
                    af[i], bfr[j], acc[i][j], 0, 0, 0);
        __syncthreads();
    }
#pragma unroll
    for (int i = 0; i < 2; ++i) {
#pragma unroll
        for (int j = 0; j < 4; ++j) {
            int col = col0 + wn * 64 + j * 16 + m16;
            float bv = bias[col];
#pragma unroll
            for (int rr = 0; rr < 4; ++rr) {
                int row = row0 + wm * 32 + i * 16 + quad * 4 + rr;
                float val = acc[i][j][rr] + bv;
                if (BF16OUT)
                    Cb[(size_t)row * N + col] = __float2bfloat16(val);
                else
                    Cf[(size_t)row * N + col] = val;
            }
        }
    }
}

// ---------------------------------------------------------------------------
// Batched q/k/v projections, 128x128 tile.
// z=0: q scaled by temp/8*log2e -> Cq [row][col]
// z=1: k -> Ck [row][col]
// z=2: v -> written TRANSPOSED into Cv = vt[(b*16+h)*64+d][t] (b64 stores)
// ---------------------------------------------------------------------------
__global__ __launch_bounds__(256) void gemm_qkv(
    const short* __restrict__ Aq, const short* __restrict__ Ak,
    const short* __restrict__ Av, const short* __restrict__ Wq,
    const short* __restrict__ Wk, const short* __restrict__ Wv,
    const float* __restrict__ bq, const float* __restrict__ bk,
    const float* __restrict__ bv, __hip_bfloat16* __restrict__ Cq,
    __hip_bfloat16* __restrict__ Ck, __hip_bfloat16* __restrict__ Cv,
    const float* __restrict__ tmp) {
    int z = blockIdx.z;
    const short* A = (z == 0) ? Aq : (z == 1) ? Ak : Av;
    const short* Wt = (z == 0) ? Wq : (z == 1) ? Wk : Wv;
    const float* bias = (z == 0) ? bq : (z == 1) ? bk : bv;

    __shared__ short As[128][32];
    __shared__ short Bs[128][32];
    int tid = threadIdx.x;
    int wave = tid >> 6, lane = tid & 63;
    int m16 = lane & 15, quad = lane >> 4;
    int wm = wave >> 1, wn = wave & 1;
    int row0 = blockIdx.y * 128, col0 = blockIdx.x * 128;
    int lr = lane >> 2;
    int kof = (lane & 3) * 8;

    float scale = 1.0f;
    if (z == 0)
        scale = tmp[(row0 >> 11) * HH + (col0 >> 6) + wn] * 0.125f * LOG2E;

    f32x4 acc[4][4];
#pragma unroll
    for (int i = 0; i < 4; ++i)
#pragma unroll
        for (int j = 0; j < 4; ++j) acc[i][j] = (f32x4){0.f, 0.f, 0.f, 0.f};

    for (int k0 = 0; k0 < CC; k0 += 32) {
#pragma unroll
        for (int j = 0; j < 2; ++j) {
            int rbase = wave * 32 + j * 16;
            async_copy16(A + (size_t)(row0 + rbase + lr) * CC + k0 + kof,
                         &As[rbase][0]);
            async_copy16(Wt + (size_t)(col0 + rbase + lr) * CC + k0 + kof,
                         &Bs[rbase][0]);
        }
        __syncthreads();
        short8 af[4], bfr[4];
#pragma unroll
        for (int i = 0; i < 4; ++i)
            af[i] = *(const short8*)&As[wm * 64 + i * 16 + m16][quad * 8];
#pragma unroll
        for (int j = 0; j < 4; ++j)
            bfr[j] = *(const short8*)&Bs[wn * 64 + j * 16 + m16][quad * 8];
#pragma unroll
        for (int i = 0; i < 4; ++i)
#pragma unroll
            for (int j = 0; j < 4; ++j)
                acc[i][j] = __builtin_amdgcn_mfma_f32_16x16x32_bf16(
                    af[i], bfr[j], acc[i][j], 0, 0, 0);
        __syncthreads();
    }
    if (z == 2) {
        // transposed V write: 4 consecutive t per lane -> one b64 store
        int b = row0 >> 11;
        int t0r = (row0 & (TT - 1)) + wm * 64 + quad * 4;
#pragma unroll
        for (int i = 0; i < 4; ++i) {
#pragma unroll
            for (int j = 0; j < 4; ++j) {
                int col = col0 + wn * 64 + j * 16 + m16;
                int h = col >> 6, d = col & 63;
                float bv2 = bias[col];
                short4_t pk = pack_bf16x4(
                    acc[i][j][0] + bv2, acc[i][j][1] + bv2,
                    acc[i][j][2] + bv2, acc[i][j][3] + bv2);
                *(short4_t*)&Cv[(((size_t)(b * HH + h) * DD) + d) * TT + t0r +
                                i * 16] = pk;
            }
        }
    } else {
        __hip_bfloat16* C = (z == 0) ? Cq : Ck;
#pragma unroll
        for (int i = 0; i < 4; ++i) {
#pragma unroll
            for (int j = 0; j < 4; ++j) {
                int col = col0 + wn * 64 + j * 16 + m16;
                float bv2 = bias[col];
#pragma unroll
                for (int rr = 0; rr < 4; ++rr) {
                    int row = row0 + wm * 64 + i * 16 + quad * 4 + rr;
                    C[(size_t)row * CC + col] =
                        __float2bfloat16((acc[i][j][rr] + bv2) * scale);
                }
            }
        }
    }
}

// ---------------------------------------------------------------------------
// fused importance epilogue: LN(h1)+GELU -> dot w2 -> sigmoid -> xi = x*imp
// ---------------------------------------------------------------------------
__global__ __launch_bounds__(256) void imp_fused(
    const float* __restrict__ h1, const float* __restrict__ g,
    const float* __restrict__ beta, const float* __restrict__ w2,
    const float* __restrict__ b2, const float* __restrict__ x,
    __hip_bfloat16* __restrict__ xi) {
    int row = blockIdx.x;
    int tid = threadIdx.x;
    const float* hr = h1 + (size_t)row * CHALF;
    float v0 = hr[tid], v1 = hr[tid + 256];
    __shared__ float red[256];
    red[tid] = v0 + v1;
    __syncthreads();
#pragma unroll
    for (int o = 128; o > 0; o >>= 1) {
        if (tid < o) red[tid] += red[tid + o];
        __syncthreads();
    }
    float mean = red[0] * (1.0f / CHALF);
    __syncthreads();
    float d0 = v0 - mean, d1 = v1 - mean;
    red[tid] = d0 * d0 + d1 * d1;
    __syncthreads();
#pragma unroll
    for (int o = 128; o > 0; o >>= 1) {
        if (tid < o) red[tid] += red[tid + o];
        __syncthreads();
    }
    float inv = rsqrtf(red[0] * (1.0f / CHALF) + 1e-5f);
    __syncthreads();
    float ge0 = gelu_exact(d0 * inv * g[tid] + beta[tid]);
    float ge1 = gelu_exact(d1 * inv * g[tid + 256] + beta[tid + 256]);
    red[tid] = ge0 * w2[tid] + ge1 * w2[tid + 256];
    __syncthreads();
#pragma unroll
    for (int o = 128; o > 0; o >>= 1) {
        if (tid < o) red[tid] += red[tid + o];
        __syncthreads();
    }
    float z = red[0] + b2[0];
    float sg = 1.0f / (1.0f + expf(-z));
    float imp = fmaxf(sg, 1e-6f);
#pragma unroll
    for (int i = 0; i < 4; ++i) {
        int c = i * 256 + tid;
        xi[(size_t)row * CC + c] =
            __float2bfloat16(x[(size_t)row * CC + c] * imp);
    }
}

// ---------------------------------------------------------------------------
// LN + GELU fp32 in -> bf16 out (for h2 -> h2b)
// ---------------------------------------------------------------------------
template <int WIDTH>
__global__ __launch_bounds__(256) void ln_gelu_bf16(
    const float* __restrict__ Y, const float* __restrict__ g,
    const float* __restrict__ beta, __hip_bfloat16* __restrict__ O) {
    constexpr int PT = WIDTH / 256;
    int row = blockIdx.x;
    int tid = threadIdx.x;
    const float* yr = Y + (size_t)row * WIDTH;
    float v[PT];
    float s = 0.f;
#pragma unroll
    for (int i = 0; i < PT; ++i) {
        v[i] = yr[i * 256 + tid];
        s += v[i];
    }
    __shared__ float red[256];
    red[tid] = s;
    __syncthreads();
#pragma unroll
    for (int o = 128; o > 0; o >>= 1) {
        if (tid < o) red[tid] += red[tid + o];
        __syncthreads();
    }
    float mean = red[0] * (1.0f / WIDTH);
    __syncthreads();
    s = 0.f;
#pragma unroll
    for (int i = 0; i < PT; ++i) {
        float d = v[i] - mean;
        s += d * d;
    }
    red[tid] = s;
    __syncthreads();
#pragma unroll
    for (int o = 128; o > 0; o >>= 1) {
        if (tid < o) red[tid] += red[tid + o];
        __syncthreads();
    }
    float inv = rsqrtf(red[0] * (1.0f / WIDTH) + 1e-5f);
#pragma unroll
    for (int i = 0; i < PT; ++i) {
        int c = i * 256 + tid;
        O[(size_t)row * WIDTH + c] =
            __float2bfloat16(gelu_exact((v[i] - mean) * inv * g[c] + beta[c]));
    }
}

// ---------------------------------------------------------------------------
// reasoned.mean(axis=1), stage 1 (partials over 128-row chunks)
// ---------------------------------------------------------------------------
__global__ __launch_bounds__(256) void mean_part(
    const __hip_bfloat16* __restrict__ R, float* __restrict__ part) {
    int idx = blockIdx.x * 256 + threadIdx.x;
    int c = idx & (CC - 1);
    int chunk = (idx >> 10) & 15;
    int b = idx >> 14;
    const __hip_bfloat16* base = R + ((size_t)(b * TT + chunk * 128)) * CC + c;
    float s = 0.f;
    for (int t = 0; t < 128; ++t) s += __bfloat162float(base[(size_t)t * CC]);
    part[idx] = s;
}

// ---------------------------------------------------------------------------
// temp_net stage 1 (+ fused mean finalize): acc1[b,col] = rm @ w1 + b1
// ---------------------------------------------------------------------------
__global__ __launch_bounds__(256) void temp_gemv1(
    const float* __restrict__ part, const float* __restrict__ w1,
    const float* __restrict__ b1, float* __restrict__ acc1) {
    __shared__ float rm_l[CC];
    __shared__ float red[256];
    int b = blockIdx.y;
    int c0 = blockIdx.x * 64;
    int tid = threadIdx.x;
    for (int cc = tid; cc < CC; cc += 256) {
        float s = 0.f;
#pragma unroll
        for (int ch = 0; ch < 16; ++ch)
            s += part[(size_t)(b * 16 + ch) * CC + cc];
        rm_l[cc] = s * (1.0f / TT);
    }
    __syncthreads();
    int col = c0 + (tid & 63);
    int kq = tid >> 6;  // 0..3
    float s = 0.f;
#pragma unroll 8
    for (int i = kq * 256; i < kq * 256 + 256; ++i)
        s = fmaf(rm_l[i], w1[(size_t)i * CHALF + col], s);
    red[tid] = s;
    __syncthreads();
    if (tid < 64) {
        float t = red[tid] + red[tid + 64] + red[tid + 128] + red[tid + 192];
        acc1[b * CHALF + tid + c0] = t + b1[col];
    }
}

// ---------------------------------------------------------------------------
// temp_net stage 2: LN(acc1) -> GELU -> @w2 + b2 -> softplus + 0.5
// ---------------------------------------------------------------------------
__global__ __launch_bounds__(512) void temp_fin(
    const float* __restrict__ acc1, const float* __restrict__ g,
    const float* __restrict__ beta, const float* __restrict__ w2,
    const float* __restrict__ b2, float* __restrict__ temp) {
    __shared__ float red[512];
    __shared__ float wred[8][16];
    int b = blockIdx.x;
    int tid = threadIdx.x;
    int wave = tid >> 6, lane = tid & 63;
    float acc = acc1[b * CHALF + tid];
    red[tid] = acc;
    __syncthreads();
#pragma unroll
    for (int o = 256; o > 0; o >>= 1) {
        if (tid < o) red[tid] += red[tid + o];
        __syncthreads();
    }
    float mean = red[0] * (1.0f / CHALF);
    __syncthreads();
    float d = acc - mean;
    red[tid] = d * d;
    __syncthreads();
#pragma unroll
    for (int o = 256; o > 0; o >>= 1) {
        if (tid < o) red[tid] += red[tid + o];
        __syncthreads();
    }
    float inv = rsqrtf(red[0] * (1.0f / CHALF) + 1e-5f);
    float ht = gelu_exact((acc - mean) * inv * g[tid] + beta[tid]);
    float p[16];
#pragma unroll
    for (int j = 0; j < 16; ++j) p[j] = ht * w2[tid * HH + j];
#pragma unroll
    for (int off = 1; off < 64; off <<= 1)
#pragma unroll
        for (int j = 0; j < 16; ++j) p[j] += __shfl_xor(p[j], off, 64);
    if (lane == 0)
#pragma unroll
        for (int j = 0; j < 16; ++j) wred[wave][j] = p[j];
    __syncthreads();
    if (tid < HH) {
        float s = b2[tid];
#pragma unroll
        for (int w = 0; w < 8; ++w) s += wred[w][tid];
        float sp = fmaxf(s, 0.f) + log1pf(expf(-fabsf(s)));
        temp[b * HH + tid] = sp + 0.5f;
    }
}

// ---------------------------------------------------------------------------
// MFMA flash attention v6: 128-row q-tile, transposed-QK softmax, exp2 domain
// via raw v_exp_f32 (__builtin_amdgcn_exp2f), f2bf conversions (measured-best),
// V pre-transposed by qkv epilogue.
// ---------------------------------------------------------------------------
__global__ __launch_bounds__(256) void flash_attn_mfma(
    const short* __restrict__ q, const short* __restrict__ k,
    const short* __restrict__ vt, const int* __restrict__ mask,
    const int* __restrict__ flags, __hip_bfloat16* __restrict__ out) {
    __shared__ short Ks[64][72];    // [key][d]
    __shared__ short Vt[64][72];    // [d][key]
    __shared__ short Ps[128][72];   // [q-row][key], wave-private strips
    int tid = threadIdx.x;
    int wave = tid >> 6, lane = tid & 63;
    int m16 = lane & 15, quad = lane >> 4;
    int qt = blockIdx.x;            // 128-row q tile
    int q0 = qt * 128;
    int bh = blockIdx.y;
    int b = bh >> 4, h = bh & 15;

    short8 qf[2][2];
#pragma unroll
    for (int qg = 0; qg < 2; ++qg) {
        const short* qrow = q + ((size_t)(b * TT + q0 + wave * 32 + qg * 16 + m16)) * CC +
                            h * DD + quad * 8;
        qf[qg][0] = *(const short8*)(qrow);
        qf[qg][1] = *(const short8*)(qrow + 32);
    }

    float m_run[2] = {-INFINITY, -INFINITY};
    float l_run[2] = {0.f, 0.f};
    f32x4 acc_o[2][4];
#pragma unroll
    for (int qg = 0; qg < 2; ++qg)
#pragma unroll
        for (int t = 0; t < 4; ++t) acc_o[qg][t] = (f32x4){0.f, 0.f, 0.f, 0.f};

    for (int kt = 0; kt < TT / 64; ++kt) {
        int kb = kt * 64;
        // stage K rows and Vt rows (both coalesced b128)
#pragma unroll
        for (int i = 0; i < 2; ++i) {
            int idx = i * 256 + tid;
            int r = idx >> 3;
            int dc = (idx & 7) * 8;
            *(short8*)&Ks[r][dc] =
                *(const short8*)(k + ((size_t)(b * TT + kb + r)) * CC + h * DD + dc);
            *(short8*)&Vt[r][dc] =
                *(const short8*)(vt + ((size_t)bh * DD + r) * TT + kb + dc);
        }
        __syncthreads();

        short8 kf[4][2];
#pragma unroll
        for (int t = 0; t < 4; ++t) {
            kf[t][0] = *(const short8*)&Ks[t * 16 + m16][quad * 8];
            kf[t][1] = *(const short8*)&Ks[t * 16 + m16][32 + quad * 8];
        }
        int fl = flags[(b * 32 + 2 * qt + (wave >> 1)) * 32 + kt];

#pragma unroll
        for (int qg = 0; qg < 2; ++qg) {
            // S^T tiles: lane holds key = t*16 + quad*4 + r, q = m16
            f32x4 sacc[4];
#pragma unroll
            for (int t = 0; t < 4; ++t) sacc[t] = (f32x4){0.f, 0.f, 0.f, 0.f};
#pragma unroll
            for (int t = 0; t < 4; ++t) {
                sacc[t] = __builtin_amdgcn_mfma_f32_16x16x32_bf16(kf[t][0], qf[qg][0], sacc[t], 0, 0, 0);
                sacc[t] = __builtin_amdgcn_mfma_f32_16x16x32_bf16(kf[t][1], qf[qg][1], sacc[t], 0, 0, 0);
            }
            float sv[4][4];
#pragma unroll
            for (int t = 0; t < 4; ++t)
#pragma unroll
                for (int r = 0; r < 4; ++r) sv[t][r] = sacc[t][r];
            if (fl == 0) {
                int qrow = q0 + wave * 32 + qg * 16 + m16;
#pragma unroll
                for (int t = 0; t < 4; ++t)
#pragma unroll
                    for (int r = 0; r < 4; ++r) {
                        int kg = kb + t * 16 + quad * 4 + r;
                        if (mask[((size_t)(b * TT + qrow)) * TT + kg] == 0)
                            sv[t][r] = -INFINITY;
                    }
            }
            float mx = sv[0][0];
#pragma unroll
            for (int t = 0; t < 4; ++t)
#pragma unroll
                for (int r = 0; r < 4; ++r) mx = fmaxf(mx, sv[t][r]);
            mx = fmaxf(mx, __shfl_xor(mx, 16, 64));
            mx = fmaxf(mx, __shfl_xor(mx, 32, 64));
            float mnew = fmaxf(m_run[qg], mx);
            float alpha = __builtin_amdgcn_exp2f(m_run[qg] - mnew);
            m_run[qg] = mnew;
            int prow = wave * 32 + qg * 16 + m16;
            float psum = 0.f;
#pragma unroll
            for (int t = 0; t < 4; ++t) {
                short4_t pk;
#pragma unroll
                for (int r = 0; r < 4; ++r) {
                    float p = __builtin_amdgcn_exp2f(sv[t][r] - mnew);
                    psum += p;
                    pk[r] = f2bf(p);
                }
                *(short4_t*)&Ps[prow][t * 16 + quad * 4] = pk;
            }
            psum += __shfl_xor(psum, 16, 64);
            psum += __shfl_xor(psum, 32, 64);
            l_run[qg] = l_run[qg] * alpha + psum;
#pragma unroll
            for (int r = 0; r < 4; ++r) {
                float ar = __shfl(alpha, (lane & 48) | (quad * 4 + r), 64);
#pragma unroll
                for (int td = 0; td < 4; ++td) acc_o[qg][td][r] *= ar;
            }
        }

        // PV: V fragments shared across q-groups
#pragma unroll
        for (int kc = 0; kc < 2; ++kc) {
            short8 vf[4];
#pragma unroll
            for (int td = 0; td < 4; ++td)
                vf[td] = *(const short8*)&Vt[td * 16 + m16][kc * 32 + quad * 8];
#pragma unroll
            for (int qg = 0; qg < 2; ++qg) {
                short8 pf = *(const short8*)&Ps[wave * 32 + qg * 16 + m16][kc * 32 + quad * 8];
#pragma unroll
                for (int td = 0; td < 4; ++td)
                    acc_o[qg][td] = __builtin_amdgcn_mfma_f32_16x16x32_bf16(
                        pf, vf[td], acc_o[qg][td], 0, 0, 0);
            }
        }
        __syncthreads();
    }

#pragma unroll
    for (int qg = 0; qg < 2; ++qg) {
#pragma unroll
        for (int r = 0; r < 4; ++r) {
            float lr = __shfl(l_run[qg], (lane & 48) | (quad * 4 + r), 64);
            float inv = 1.0f / lr;
            int row = b * TT + q0 + wave * 32 + qg * 16 + quad * 4 + r;
#pragma unroll
            for (int td = 0; td < 4; ++td)
                out[(size_t)row * CC + h * DD + td * 16 + m16] =
                    __float2bfloat16(acc_o[qg][td][r] * inv);
        }
    }
}

// ---------------------------------------------------------------------------
// Final: out = LN(x + proj)
// ---------------------------------------------------------------------------
__global__ __launch_bounds__(256) void final_ln(
    const float* __restrict__ x, const float* __restrict__ p,
    const float* __restrict__ g, const float* __restrict__ beta,
    float* __restrict__ out) {
    int row = blockIdx.x;
    int tid = threadIdx.x;
    const float* xr = x + (size_t)row * CC;
    const float* pr = p + (size_t)row * CC;
    float v[4];
    float s = 0.f;
#pragma unroll
    for (int i = 0; i < 4; ++i) {
        int c = i * 256 + tid;
        v[i] = xr[c] + pr[c];
        s += v[i];
    }
    __shared__ float red[256];
    red[tid] = s;
    __syncthreads();
#pragma unroll
    for (int o = 128; o > 0; o >>= 1) {
        if (tid < o) red[tid] += red[tid + o];
        __syncthreads();
    }
    float mean = red[0] * (1.0f / CC);
    __syncthreads();
    s = 0.f;
#pragma unroll
    for (int i = 0; i < 4; ++i) {
        float d = v[i] - mean;
        s += d * d;
    }
    red[tid] = s;
    __syncthreads();
#pragma unroll
    for (int o = 128; o > 0; o >>= 1) {
        if (tid < o) red[tid] += red[tid + o];
        __syncthreads();
    }
    float inv = rsqrtf(red[0] * (1.0f / CC) + 1e-5f);
#pragma unroll
    for (int i = 0; i < 4; ++i) {
        int c = i * 256 + tid;
        out[(size_t)row * CC + c] = (v[i] - mean) * inv * g[c] + beta[c];
    }
}

extern "C" void kernel_launch(void* const* d_in, const int* in_sizes, int n_in,
                              void* d_out, int out_size, void* d_ws,
                              size_t ws_size, hipStream_t stream) {
    const float* x        = (const float*)d_in[0];
    const int*   mask     = (const int*)d_in[1];
    const float* imp_w1   = (const float*)d_in[2];
    const float* imp_b1   = (const float*)d_in[3];
    const float* imp_g    = (const float*)d_in[4];
    const float* imp_beta = (const float*)d_in[5];
    const float* imp_w2   = (const float*)d_in[6];
    const float* imp_b2   = (const float*)d_in[7];
    const float* rsn_w1   = (const float*)d_in[8];
    const float* rsn_b1   = (const float*)d_in[9];
    const float* rsn_g    = (const float*)d_in[10];
    const float* rsn_beta = (const float*)d_in[11];
    const float* rsn_w2   = (const float*)d_in[12];
    const float* rsn_b2   = (const float*)d_in[13];
    const float* q_w      = (const float*)d_in[14];
    const float* q_b      = (const float*)d_in[15];
    const float* k_w      = (const float*)d_in[16];
    const float* k_b      = (const float*)d_in[17];
    const float* v_w      = (const float*)d_in[18];
    const float* v_b      = (const float*)d_in[19];
    const float* o_w      = (const float*)d_in[20];
    const float* o_b      = (const float*)d_in[21];
    const float* tmp_w1   = (const float*)d_in[22];
    const float* tmp_b1   = (const float*)d_in[23];
    const float* tmp_g    = (const float*)d_in[24];
    const float* tmp_beta = (const float*)d_in[25];
    const float* tmp_w2   = (const float*)d_in[26];
    const float* tmp_b2   = (const float*)d_in[27];
    const float* norm_g   = (const float*)d_in[28];
    const float* norm_b   = (const float*)d_in[29];
    float* out = (float*)d_out;
    float* ws  = (float*)d_ws;

    // workspace layout (float offsets)
    float* h1  = ws;                       // [4096,512] fp32
    float* h2  = ws + 2097152;             // [4096,1024] fp32 (later o-proj out)
    __hip_bfloat16* x_bf  = (__hip_bfloat16*)(ws + 6291456);
    __hip_bfloat16* xi_bf = (__hip_bfloat16*)(ws + 8388608);
    __hip_bfloat16* h2b   = (__hip_bfloat16*)(ws + 10485760);
    __hip_bfloat16* rs_bf = (__hip_bfloat16*)(ws + 12582912);  // reasoned, later attn out
    __hip_bfloat16* qb    = (__hip_bfloat16*)(ws + 14680064);
    __hip_bfloat16* kb    = (__hip_bfloat16*)(ws + 16777216);
    __hip_bfloat16* vtb   = (__hip_bfloat16*)(ws + 20971520);  // [32,64,2048]
    __hip_bfloat16* imp_w1t = (__hip_bfloat16*)(ws + 23068672);  // [512,1024]
    __hip_bfloat16* rsn_w1t = (__hip_bfloat16*)(ws + 23330816);  // [1024,1024]
    __hip_bfloat16* rsn_w2t = (__hip_bfloat16*)(ws + 23855104);
    __hip_bfloat16* q_wt    = (__hip_bfloat16*)(ws + 24379392);
    __hip_bfloat16* k_wt    = (__hip_bfloat16*)(ws + 24903680);
    __hip_bfloat16* v_wt    = (__hip_bfloat16*)(ws + 25427968);
    __hip_bfloat16* o_wt    = (__hip_bfloat16*)(ws + 25952256);
    float* tmp  = ws + 26478592;   // [2,16]
    float* part = ws + 26479104;   // [2,16,1024]
    int*   flg  = (int*)(ws + 26511872);  // [2,32,32]
    float* acc1 = ws + 26513920;   // [2,512]

    dim3 blk(256);
    // fused prep: x->bf16, mask flags, 7 weight transposes
    prep<<<5760, blk, 0, stream>>>(
        x, x_bf, mask, flg,
        imp_w1, rsn_w1, rsn_w2, q_w, k_w, v_w, o_w,
        imp_w1t, rsn_w1t, rsn_w2t, q_wt, k_wt, v_wt, o_wt);

    // importance net (GEMM + fused LN/GELU/gate)
    gemm_mfma64<false><<<dim3(CHALF / 128, NN / 64), blk, 0, stream>>>(
        (const short*)x_bf, (const short*)imp_w1t, imp_b1, h1, nullptr, NN, CHALF, CC);
    imp_fused<<<NN, blk, 0, stream>>>(h1, imp_g, imp_beta, imp_w2, imp_b2, x, xi_bf);
    // reasoning net
    gemm_mfma64<false><<<dim3(CC / 128, NN / 64), blk, 0, stream>>>(
        (const short*)xi_bf, (const short*)rsn_w1t, rsn_b1, h2, nullptr, NN, CC, CC);
    ln_gelu_bf16<CC><<<NN, blk, 0, stream>>>(h2, rsn_g, rsn_beta, h2b);
    gemm_mfma64<true><<<dim3(CC / 128, NN / 64), blk, 0, stream>>>(
        (const short*)h2b, (const short*)rsn_w2t, rsn_b2, nullptr, rs_bf, NN, CC, CC);
    // temperature net
    mean_part<<<128, blk, 0, stream>>>(rs_bf, part);
    temp_gemv1<<<dim3(CHALF / 64, BB), blk, 0, stream>>>(part, tmp_w1, tmp_b1, acc1);
    temp_fin<<<BB, dim3(512), 0, stream>>>(acc1, tmp_g, tmp_beta, tmp_w2, tmp_b2, tmp);
    // q/k/v projections batched; q scaled by temp/8*log2e; v written transposed
    gemm_qkv<<<dim3(CC / 128, NN / 128, 3), blk, 0, stream>>>(
        (const short*)rs_bf, (const short*)xi_bf, (const short*)x_bf,
        (const short*)q_wt, (const short*)k_wt, (const short*)v_wt,
        q_b, k_b, v_b, qb, kb, vtb, tmp);
    // flash attention v6 (128-row q-tiles, raw v_exp_f32 softmax)
    flash_attn_mfma<<<dim3(TT / 128, BB * HH), blk, 0, stream>>>(
        (const short*)qb, (const short*)kb, (const short*)vtb, mask, flg, rs_bf);
    // output projection + residual LN
    gemm_mfma64<false><<<dim3(CC / 128, NN / 64), blk, 0, stream>>>(
        (const short*)rs_bf, (const short*)o_wt, o_b, h2, nullptr, NN, CC, CC);
    final_ln<<<NN, blk, 0, stream>>>(x, h2, norm_g, norm_b, out);
}

// Round 10
// 413.945 us; speedup vs baseline: 4.5738x; 1.0255x over previous
//
#include <hip/hip_runtime.h>
#include <hip/hip_bf16.h>
#include <math.h>

// Problem constants
#define BB 2
#define TT 2048
#define CC 1024
#define HH 16
#define DD 64
#define CHALF 512
#define NN (BB * TT)   // 4096 rows
#define LOG2E 1.44269504088896340736f

typedef __attribute__((ext_vector_type(8))) short short8;
typedef __attribute__((ext_vector_type(4))) short short4_t;
typedef __attribute__((ext_vector_type(4))) float f32x4;

__device__ __forceinline__ float gelu_exact(float x) {
    return 0.5f * x * (1.0f + erff(x * 0.70710678118654752f));
}

__device__ __forceinline__ short f2bf(float f) {
    __hip_bfloat16 h = __float2bfloat16(f);
    short s;
    __builtin_memcpy(&s, &h, 2);
    return s;
}

__device__ __forceinline__ short4_t pack_bf16x4(float a, float b, float c,
                                                float d) {
    short4_t s4;
    s4[0] = f2bf(a);
    s4[1] = f2bf(b);
    s4[2] = f2bf(c);
    s4[3] = f2bf(d);
    return s4;
}

// async global->LDS, 16 B per lane; LDS dst must be wave-uniform base
__device__ __forceinline__ void async_copy16(const void* g, void* l) {
    __builtin_amdgcn_global_load_lds(
        (const __attribute__((address_space(1))) void*)g,
        (__attribute__((address_space(3))) void*)l, 16, 0, 0);
}

// ---------------------------------------------------------------------------
// prep: one launch for x->bf16 convert, mask tile flags, 7 weight transposes.
// ---------------------------------------------------------------------------
__global__ __launch_bounds__(256) void prep(
    const float* __restrict__ x, __hip_bfloat16* __restrict__ x_bf,
    const int* __restrict__ mask, int* __restrict__ flags,
    const float* w0, const float* w1, const float* w2, const float* w3,
    const float* w4, const float* w5, const float* w6,
    __hip_bfloat16* t0, __hip_bfloat16* t1, __hip_bfloat16* t2,
    __hip_bfloat16* t3, __hip_bfloat16* t4, __hip_bfloat16* t5,
    __hip_bfloat16* t6) {
    __shared__ float T[64][65];
    int blk = blockIdx.x;
    int tid = threadIdx.x;
    if (blk < 2048) {
        int i = (blk * 256 + tid) * 8;
        float4 a = *(const float4*)&x[i];
        float4 b = *(const float4*)&x[i + 4];
        __hip_bfloat16 o[8] = {
            __float2bfloat16(a.x), __float2bfloat16(a.y),
            __float2bfloat16(a.z), __float2bfloat16(a.w),
            __float2bfloat16(b.x), __float2bfloat16(b.y),
            __float2bfloat16(b.z), __float2bfloat16(b.w)};
        *(float4*)&x_bf[i] = *(float4*)o;
    } else if (blk < 4096) {
        int idx = blk - 2048;
        int kt = idx & 31, qt = (idx >> 5) & 31, b = idx >> 10;
        int* red = (int*)T;
        int r = tid >> 2;
        int c0 = (tid & 3) * 16;
        const int* base =
            mask + ((size_t)(b * TT + qt * 64 + r)) * TT + kt * 64 + c0;
        int all = 1;
#pragma unroll
        for (int i = 0; i < 4; ++i) {
            int4 m4 = *(const int4*)(base + i * 4);
            all &= (m4.x != 0) & (m4.y != 0) & (m4.z != 0) & (m4.w != 0);
        }
        red[tid] = all;
        __syncthreads();
#pragma unroll
        for (int o = 128; o > 0; o >>= 1) {
            if (tid < o) red[tid] &= red[tid + o];
            __syncthreads();
        }
        if (tid == 0) flags[(b * 32 + qt) * 32 + kt] = red[0];
    } else {
        int idx = blk - 4096;
        const float* W;
        __hip_bfloat16* Wt;
        int N, n0, k0;
        if (idx < 128) {
            W = w0; Wt = t0; N = 512;
            n0 = (idx & 7) * 64;
            k0 = (idx >> 3) * 64;
        } else {
            idx -= 128;
            int w = idx >> 8;
            int r = idx & 255;
            N = 1024;
            n0 = (r & 15) * 64;
            k0 = (r >> 4) * 64;
            switch (w) {
                case 0: W = w1; Wt = t1; break;
                case 1: W = w2; Wt = t2; break;
                case 2: W = w3; Wt = t3; break;
                case 3: W = w4; Wt = t4; break;
                case 4: W = w5; Wt = t5; break;
                default: W = w6; Wt = t6; break;
            }
        }
        int c = tid & 63, r4 = tid >> 6;
#pragma unroll
        for (int i = 0; i < 16; ++i) {
            int row = i * 4 + r4;
            T[row][c] = W[(size_t)(k0 + row) * N + n0 + c];
        }
        __syncthreads();
#pragma unroll
        for (int i = 0; i < 16; ++i) {
            int row = i * 4 + r4;  // n index
            Wt[(size_t)(n0 + row) * CC + k0 + c] = __float2bfloat16(T[c][row]);
        }
    }
}

// ---------------------------------------------------------------------------
// bf16 MFMA GEMM, 64x128 tile, BK=64 (16 MFMA/barrier): C = A @ Wt^T + bias
// Split-half LDS buffers keep the proven 64B-row (conflict-free) layout.
// ---------------------------------------------------------------------------
template <bool BF16OUT>
__global__ __launch_bounds__(256) void gemm_mfma64(
    const short* __restrict__ A, const short* __restrict__ Wt,
    const float* __restrict__ bias, float* __restrict__ Cf,
    __hip_bfloat16* __restrict__ Cb, int M, int N, int K) {
    __shared__ short As0[64][32], As1[64][32];
    __shared__ short Bs0[128][32], Bs1[128][32];
    int tid = threadIdx.x;
    int wave = tid >> 6, lane = tid & 63;
    int m16 = lane & 15, quad = lane >> 4;
    int wm = wave >> 1, wn = wave & 1;
    int row0 = blockIdx.y * 64, col0 = blockIdx.x * 128;
    int lr = lane >> 2;        // 0..15
    int kof = (lane & 3) * 8;

    f32x4 acc[2][4];
#pragma unroll
    for (int i = 0; i < 2; ++i)
#pragma unroll
        for (int j = 0; j < 4; ++j) acc[i][j] = (f32x4){0.f, 0.f, 0.f, 0.f};

    for (int k0 = 0; k0 < K; k0 += 64) {
        const short* arow = A + (size_t)(row0 + wave * 16 + lr) * K + k0 + kof;
        async_copy16(arow, &As0[wave * 16][0]);
        async_copy16(arow + 32, &As1[wave * 16][0]);
#pragma unroll
        for (int j = 0; j < 2; ++j) {
            int rbase = wave * 32 + j * 16;
            const short* brow =
                Wt + (size_t)(col0 + rbase + lr) * K + k0 + kof;
            async_copy16(brow, &Bs0[rbase][0]);
            async_copy16(brow + 32, &Bs1[rbase][0]);
        }
        __syncthreads();
#pragma unroll
        for (int kc = 0; kc < 2; ++kc) {
            short8 af[2], bfr[4];
#pragma unroll
            for (int i = 0; i < 2; ++i)
                af[i] = kc ? *(const short8*)&As1[wm * 32 + i * 16 + m16][quad * 8]
                           : *(const short8*)&As0[wm * 32 + i * 16 + m16][quad * 8];
#pragma unroll
            for (int j = 0; j < 4; ++j)
                bfr[j] = kc ? *(const short8*)&Bs1[wn * 64 + j * 16 + m16][quad * 8]
                            : *(const short8*)&Bs0[wn * 64 + j * 16 + m16][quad * 8];
#pragma unroll
            for (int i = 0; i < 2; ++i)
#pragma unroll
                for (int j = 0; j < 4; ++j)
                    acc[i][j] = __builtin_amdgcn_mfma_f32_16x16x32_bf16(
                        af[i], bfr[j], acc[i][j], 0, 0, 0);
        }
        __syncthreads();
    }
#pragma unroll
    for (int i = 0; i < 2; ++i) {
#pragma unroll
        for (int j = 0; j < 4; ++j) {
            int col = col0 + wn * 64 + j * 16 + m16;
            float bv = bias[col];
#pragma unroll
            for (int rr = 0; rr < 4; ++rr) {
                int row = row0 + wm * 32 + i * 16 + quad * 4 + rr;
                float val = acc[i][j][rr] + bv;
                if (BF16OUT)
                    Cb[(size_t)row * N + col] = __float2bfloat16(val);
                else
                    Cf[(size_t)row * N + col] = val;
            }
        }
    }
}

// ---------------------------------------------------------------------------
// Batched q/k/v projections, 128x128 tile.
// z=0: q scaled by temp/8*log2e; z=1: k; z=2: v written TRANSPOSED (vt)
// ---------------------------------------------------------------------------
__global__ __launch_bounds__(256) void gemm_qkv(
    const short* __restrict__ Aq, const short* __restrict__ Ak,
    const short* __restrict__ Av, const short* __restrict__ Wq,
    const short* __restrict__ Wk, const short* __restrict__ Wv,
    const float* __restrict__ bq, const float* __restrict__ bk,
    const float* __restrict__ bv, __hip_bfloat16* __restrict__ Cq,
    __hip_bfloat16* __restrict__ Ck, __hip_bfloat16* __restrict__ Cv,
    const float* __restrict__ tmp) {
    int z = blockIdx.z;
    const short* A = (z == 0) ? Aq : (z == 1) ? Ak : Av;
    const short* Wt = (z == 0) ? Wq : (z == 1) ? Wk : Wv;
    const float* bias = (z == 0) ? bq : (z == 1) ? bk : bv;

    __shared__ short As[128][32];
    __shared__ short Bs[128][32];
    int tid = threadIdx.x;
    int wave = tid >> 6, lane = tid & 63;
    int m16 = lane & 15, quad = lane >> 4;
    int wm = wave >> 1, wn = wave & 1;
    int row0 = blockIdx.y * 128, col0 = blockIdx.x * 128;
    int lr = lane >> 2;
    int kof = (lane & 3) * 8;

    float scale = 1.0f;
    if (z == 0)
        scale = tmp[(row0 >> 11) * HH + (col0 >> 6) + wn] * 0.125f * LOG2E;

    f32x4 acc[4][4];
#pragma unroll
    for (int i = 0; i < 4; ++i)
#pragma unroll
        for (int j = 0; j < 4; ++j) acc[i][j] = (f32x4){0.f, 0.f, 0.f, 0.f};

    for (int k0 = 0; k0 < CC; k0 += 32) {
#pragma unroll
        for (int j = 0; j < 2; ++j) {
            int rbase = wave * 32 + j * 16;
            async_copy16(A + (size_t)(row0 + rbase + lr) * CC + k0 + kof,
                         &As[rbase][0]);
            async_copy16(Wt + (size_t)(col0 + rbase + lr) * CC + k0 + kof,
                         &Bs[rbase][0]);
        }
        __syncthreads();
        short8 af[4], bfr[4];
#pragma unroll
        for (int i = 0; i < 4; ++i)
            af[i] = *(const short8*)&As[wm * 64 + i * 16 + m16][quad * 8];
#pragma unroll
        for (int j = 0; j < 4; ++j)
            bfr[j] = *(const short8*)&Bs[wn * 64 + j * 16 + m16][quad * 8];
#pragma unroll
        for (int i = 0; i < 4; ++i)
#pragma unroll
            for (int j = 0; j < 4; ++j)
                acc[i][j] = __builtin_amdgcn_mfma_f32_16x16x32_bf16(
                    af[i], bfr[j], acc[i][j], 0, 0, 0);
        __syncthreads();
    }
    if (z == 2) {
        int b = row0 >> 11;
        int t0r = (row0 & (TT - 1)) + wm * 64 + quad * 4;
#pragma unroll
        for (int i = 0; i < 4; ++i) {
#pragma unroll
            for (int j = 0; j < 4; ++j) {
                int col = col0 + wn * 64 + j * 16 + m16;
                int h = col >> 6, d = col & 63;
                float bv2 = bias[col];
                short4_t pk = pack_bf16x4(
                    acc[i][j][0] + bv2, acc[i][j][1] + bv2,
                    acc[i][j][2] + bv2, acc[i][j][3] + bv2);
                *(short4_t*)&Cv[(((size_t)(b * HH + h) * DD) + d) * TT + t0r +
                                i * 16] = pk;
            }
        }
    } else {
        __hip_bfloat16* C = (z == 0) ? Cq : Ck;
#pragma unroll
        for (int i = 0; i < 4; ++i) {
#pragma unroll
            for (int j = 0; j < 4; ++j) {
                int col = col0 + wn * 64 + j * 16 + m16;
                float bv2 = bias[col];
#pragma unroll
                for (int rr = 0; rr < 4; ++rr) {
                    int row = row0 + wm * 64 + i * 16 + quad * 4 + rr;
                    C[(size_t)row * CC + col] =
                        __float2bfloat16((acc[i][j][rr] + bv2) * scale);
                }
            }
        }
    }
}

// ---------------------------------------------------------------------------
// fused importance epilogue: LN(h1)+GELU -> dot w2 -> sigmoid -> xi = x*imp
// ---------------------------------------------------------------------------
__global__ __launch_bounds__(256) void imp_fused(
    const float* __restrict__ h1, const float* __restrict__ g,
    const float* __restrict__ beta, const float* __restrict__ w2,
    const float* __restrict__ b2, const float* __restrict__ x,
    __hip_bfloat16* __restrict__ xi) {
    int row = blockIdx.x;
    int tid = threadIdx.x;
    const float* hr = h1 + (size_t)row * CHALF;
    float v0 = hr[tid], v1 = hr[tid + 256];
    __shared__ float red[256];
    red[tid] = v0 + v1;
    __syncthreads();
#pragma unroll
    for (int o = 128; o > 0; o >>= 1) {
        if (tid < o) red[tid] += red[tid + o];
        __syncthreads();
    }
    float mean = red[0] * (1.0f / CHALF);
    __syncthreads();
    float d0 = v0 - mean, d1 = v1 - mean;
    red[tid] = d0 * d0 + d1 * d1;
    __syncthreads();
#pragma unroll
    for (int o = 128; o > 0; o >>= 1) {
        if (tid < o) red[tid] += red[tid + o];
        __syncthreads();
    }
    float inv = rsqrtf(red[0] * (1.0f / CHALF) + 1e-5f);
    __syncthreads();
    float ge0 = gelu_exact(d0 * inv * g[tid] + beta[tid]);
    float ge1 = gelu_exact(d1 * inv * g[tid + 256] + beta[tid + 256]);
    red[tid] = ge0 * w2[tid] + ge1 * w2[tid + 256];
    __syncthreads();
#pragma unroll
    for (int o = 128; o > 0; o >>= 1) {
        if (tid < o) red[tid] += red[tid + o];
        __syncthreads();
    }
    float z = red[0] + b2[0];
    float sg = 1.0f / (1.0f + expf(-z));
    float imp = fmaxf(sg, 1e-6f);
#pragma unroll
    for (int i = 0; i < 4; ++i) {
        int c = i * 256 + tid;
        xi[(size_t)row * CC + c] =
            __float2bfloat16(x[(size_t)row * CC + c] * imp);
    }
}

// ---------------------------------------------------------------------------
// LN + GELU fp32 in -> bf16 out (for h2 -> h2b)
// ---------------------------------------------------------------------------
template <int WIDTH>
__global__ __launch_bounds__(256) void ln_gelu_bf16(
    const float* __restrict__ Y, const float* __restrict__ g,
    const float* __restrict__ beta, __hip_bfloat16* __restrict__ O) {
    constexpr int PT = WIDTH / 256;
    int row = blockIdx.x;
    int tid = threadIdx.x;
    const float* yr = Y + (size_t)row * WIDTH;
    float v[PT];
    float s = 0.f;
#pragma unroll
    for (int i = 0; i < PT; ++i) {
        v[i] = yr[i * 256 + tid];
        s += v[i];
    }
    __shared__ float red[256];
    red[tid] = s;
    __syncthreads();
#pragma unroll
    for (int o = 128; o > 0; o >>= 1) {
        if (tid < o) red[tid] += red[tid + o];
        __syncthreads();
    }
    float mean = red[0] * (1.0f / WIDTH);
    __syncthreads();
    s = 0.f;
#pragma unroll
    for (int i = 0; i < PT; ++i) {
        float d = v[i] - mean;
        s += d * d;
    }
    red[tid] = s;
    __syncthreads();
#pragma unroll
    for (int o = 128; o > 0; o >>= 1) {
        if (tid < o) red[tid] += red[tid + o];
        __syncthreads();
    }
    float inv = rsqrtf(red[0] * (1.0f / WIDTH) + 1e-5f);
#pragma unroll
    for (int i = 0; i < PT; ++i) {
        int c = i * 256 + tid;
        O[(size_t)row * WIDTH + c] =
            __float2bfloat16(gelu_exact((v[i] - mean) * inv * g[c] + beta[c]));
    }
}

// ---------------------------------------------------------------------------
// reasoned.mean(axis=1), stage 1 (partials over 128-row chunks)
// ---------------------------------------------------------------------------
__global__ __launch_bounds__(256) void mean_part(
    const __hip_bfloat16* __restrict__ R, float* __restrict__ part) {
    int idx = blockIdx.x * 256 + threadIdx.x;
    int c = idx & (CC - 1);
    int chunk = (idx >> 10) & 15;
    int b = idx >> 14;
    const __hip_bfloat16* base = R + ((size_t)(b * TT + chunk * 128)) * CC + c;
    float s = 0.f;
    for (int t = 0; t < 128; ++t) s += __bfloat162float(base[(size_t)t * CC]);
    part[idx] = s;
}

// ---------------------------------------------------------------------------
// temp_net stage 1 (+ fused mean finalize): acc1[b,col] = rm @ w1 + b1
// ---------------------------------------------------------------------------
__global__ __launch_bounds__(256) void temp_gemv1(
    const float* __restrict__ part, const float* __restrict__ w1,
    const float* __restrict__ b1, float* __restrict__ acc1) {
    __shared__ float rm_l[CC];
    __shared__ float red[256];
    int b = blockIdx.y;
    int c0 = blockIdx.x * 64;
    int tid = threadIdx.x;
    for (int cc = tid; cc < CC; cc += 256) {
        float s = 0.f;
#pragma unroll
        for (int ch = 0; ch < 16; ++ch)
            s += part[(size_t)(b * 16 + ch) * CC + cc];
        rm_l[cc] = s * (1.0f / TT);
    }
    __syncthreads();
    int col = c0 + (tid & 63);
    int kq = tid >> 6;  // 0..3
    float s = 0.f;
#pragma unroll 8
    for (int i = kq * 256; i < kq * 256 + 256; ++i)
        s = fmaf(rm_l[i], w1[(size_t)i * CHALF + col], s);
    red[tid] = s;
    __syncthreads();
    if (tid < 64) {
        float t = red[tid] + red[tid + 64] + red[tid + 128] + red[tid + 192];
        acc1[b * CHALF + tid + c0] = t + b1[col];
    }
}

// ---------------------------------------------------------------------------
// temp_net stage 2: LN(acc1) -> GELU -> @w2 + b2 -> softplus + 0.5
// ---------------------------------------------------------------------------
__global__ __launch_bounds__(512) void temp_fin(
    const float* __restrict__ acc1, const float* __restrict__ g,
    const float* __restrict__ beta, const float* __restrict__ w2,
    const float* __restrict__ b2, float* __restrict__ temp) {
    __shared__ float red[512];
    __shared__ float wred[8][16];
    int b = blockIdx.x;
    int tid = threadIdx.x;
    int wave = tid >> 6, lane = tid & 63;
    float acc = acc1[b * CHALF + tid];
    red[tid] = acc;
    __syncthreads();
#pragma unroll
    for (int o = 256; o > 0; o >>= 1) {
        if (tid < o) red[tid] += red[tid + o];
        __syncthreads();
    }
    float mean = red[0] * (1.0f / CHALF);
    __syncthreads();
    float d = acc - mean;
    red[tid] = d * d;
    __syncthreads();
#pragma unroll
    for (int o = 256; o > 0; o >>= 1) {
        if (tid < o) red[tid] += red[tid + o];
        __syncthreads();
    }
    float inv = rsqrtf(red[0] * (1.0f / CHALF) + 1e-5f);
    float ht = gelu_exact((acc - mean) * inv * g[tid] + beta[tid]);
    float p[16];
#pragma unroll
    for (int j = 0; j < 16; ++j) p[j] = ht * w2[tid * HH + j];
#pragma unroll
    for (int off = 1; off < 64; off <<= 1)
#pragma unroll
        for (int j = 0; j < 16; ++j) p[j] += __shfl_xor(p[j], off, 64);
    if (lane == 0)
#pragma unroll
        for (int j = 0; j < 16; ++j) wred[wave][j] = p[j];
    __syncthreads();
    if (tid < HH) {
        float s = b2[tid];
#pragma unroll
        for (int w = 0; w < 8; ++w) s += wred[w][tid];
        float sp = fmaxf(s, 0.f) + log1pf(expf(-fabsf(s)));
        temp[b * HH + tid] = sp + 0.5f;
    }
}

// ---------------------------------------------------------------------------
// MFMA flash attention v7: 128-row q-tile, transposed-QK softmax, O^T PV
// (per-lane alpha/l, no shuffles), ballot-gated rescale, raw v_exp_f32.
// ---------------------------------------------------------------------------
__global__ __launch_bounds__(256) void flash_attn_mfma(
    const short* __restrict__ q, const short* __restrict__ k,
    const short* __restrict__ vt, const int* __restrict__ mask,
    const int* __restrict__ flags, __hip_bfloat16* __restrict__ out) {
    __shared__ short Ks[64][72];    // [key][d]
    __shared__ short Vt[64][72];    // [d][key]
    __shared__ short Ps[128][72];   // [q-row][key], wave-private strips
    int tid = threadIdx.x;
    int wave = tid >> 6, lane = tid & 63;
    int m16 = lane & 15, quad = lane >> 4;
    int qt = blockIdx.x;            // 128-row q tile
    int q0 = qt * 128;
    int bh = blockIdx.y;
    int b = bh >> 4, h = bh & 15;

    short8 qf[2][2];
#pragma unroll
    for (int qg = 0; qg < 2; ++qg) {
        const short* qrow = q + ((size_t)(b * TT + q0 + wave * 32 + qg * 16 + m16)) * CC +
                            h * DD + quad * 8;
        qf[qg][0] = *(const short8*)(qrow);
        qf[qg][1] = *(const short8*)(qrow + 32);
    }

    float m_run[2] = {-INFINITY, -INFINITY};
    float l_run[2] = {0.f, 0.f};
    // acc_o in O^T layout: lane col=m16 -> q; row=quad*4+r -> d within td block
    f32x4 acc_o[2][4];
#pragma unroll
    for (int qg = 0; qg < 2; ++qg)
#pragma unroll
        for (int t = 0; t < 4; ++t) acc_o[qg][t] = (f32x4){0.f, 0.f, 0.f, 0.f};

    for (int kt = 0; kt < TT / 64; ++kt) {
        int kb = kt * 64;
        // stage K rows and Vt rows (both coalesced b128)
#pragma unroll
        for (int i = 0; i < 2; ++i) {
            int idx = i * 256 + tid;
            int r = idx >> 3;
            int dc = (idx & 7) * 8;
            *(short8*)&Ks[r][dc] =
                *(const short8*)(k + ((size_t)(b * TT + kb + r)) * CC + h * DD + dc);
            *(short8*)&Vt[r][dc] =
                *(const short8*)(vt + ((size_t)bh * DD + r) * TT + kb + dc);
        }
        __syncthreads();

        short8 kf[4][2];
#pragma unroll
        for (int t = 0; t < 4; ++t) {
            kf[t][0] = *(const short8*)&Ks[t * 16 + m16][quad * 8];
            kf[t][1] = *(const short8*)&Ks[t * 16 + m16][32 + quad * 8];
        }
        int fl = flags[(b * 32 + 2 * qt + (wave >> 1)) * 32 + kt];

#pragma unroll
        for (int qg = 0; qg < 2; ++qg) {
            // S^T tiles: lane holds key = t*16 + quad*4 + r, q = m16
            f32x4 sacc[4];
#pragma unroll
            for (int t = 0; t < 4; ++t) sacc[t] = (f32x4){0.f, 0.f, 0.f, 0.f};
#pragma unroll
            for (int t = 0; t < 4; ++t) {
                sacc[t] = __builtin_amdgcn_mfma_f32_16x16x32_bf16(kf[t][0], qf[qg][0], sacc[t], 0, 0, 0);
                sacc[t] = __builtin_amdgcn_mfma_f32_16x16x32_bf16(kf[t][1], qf[qg][1], sacc[t], 0, 0, 0);
            }
            float sv[4][4];
#pragma unroll
            for (int t = 0; t < 4; ++t)
#pragma unroll
                for (int r = 0; r < 4; ++r) sv[t][r] = sacc[t][r];
            if (fl == 0) {
                int qrow = q0 + wave * 32 + qg * 16 + m16;
#pragma unroll
                for (int t = 0; t < 4; ++t)
#pragma unroll
                    for (int r = 0; r < 4; ++r) {
                        int kg = kb + t * 16 + quad * 4 + r;
                        if (mask[((size_t)(b * TT + qrow)) * TT + kg] == 0)
                            sv[t][r] = -INFINITY;
                    }
            }
            float mx = sv[0][0];
#pragma unroll
            for (int t = 0; t < 4; ++t)
#pragma unroll
                for (int r = 0; r < 4; ++r) mx = fmaxf(mx, sv[t][r]);
            mx = fmaxf(mx, __shfl_xor(mx, 16, 64));
            mx = fmaxf(mx, __shfl_xor(mx, 32, 64));
            float mnew = fmaxf(m_run[qg], mx);
            // rescale only when some lane's max advanced (rare in steady state)
            if (__any(mnew > m_run[qg])) {
                float alpha = __builtin_amdgcn_exp2f(m_run[qg] - mnew);
                l_run[qg] *= alpha;
#pragma unroll
                for (int td = 0; td < 4; ++td)
#pragma unroll
                    for (int r = 0; r < 4; ++r) acc_o[qg][td][r] *= alpha;
            }
            m_run[qg] = mnew;
            int prow = wave * 32 + qg * 16 + m16;
            float psum = 0.f;
#pragma unroll
            for (int t = 0; t < 4; ++t) {
                short4_t pk;
#pragma unroll
                for (int r = 0; r < 4; ++r) {
                    float p = __builtin_amdgcn_exp2f(sv[t][r] - mnew);
                    psum += p;
                    pk[r] = f2bf(p);
                }
                *(short4_t*)&Ps[prow][t * 16 + quad * 4] = pk;
            }
            psum += __shfl_xor(psum, 16, 64);
            psum += __shfl_xor(psum, 32, 64);
            l_run[qg] += psum;
        }

        // PV as O^T = V^T P^T: A=V-frag (m=d), B=P-frag (n=q); q stays in lanes
#pragma unroll
        for (int kc = 0; kc < 2; ++kc) {
            short8 vf[4];
#pragma unroll
            for (int td = 0; td < 4; ++td)
                vf[td] = *(const short8*)&Vt[td * 16 + m16][kc * 32 + quad * 8];
#pragma unroll
            for (int qg = 0; qg < 2; ++qg) {
                short8 pf = *(const short8*)&Ps[wave * 32 + qg * 16 + m16][kc * 32 + quad * 8];
#pragma unroll
                for (int td = 0; td < 4; ++td)
                    acc_o[qg][td] = __builtin_amdgcn_mfma_f32_16x16x32_bf16(
                        vf[td], pf, acc_o[qg][td], 0, 0, 0);
            }
        }
        __syncthreads();
    }

    // epilogue: per-lane l; O^T layout packs 4 consecutive d -> b64 store
#pragma unroll
    for (int qg = 0; qg < 2; ++qg) {
        float inv = 1.0f / l_run[qg];
        int row = b * TT + q0 + wave * 32 + qg * 16 + m16;
#pragma unroll
        for (int td = 0; td < 4; ++td) {
            short4_t pk = pack_bf16x4(
                acc_o[qg][td][0] * inv, acc_o[qg][td][1] * inv,
                acc_o[qg][td][2] * inv, acc_o[qg][td][3] * inv);
            *(short4_t*)&out[(size_t)row * CC + h * DD + td * 16 + quad * 4] = pk;
        }
    }
}

// ---------------------------------------------------------------------------
// Final: out = LN(x + proj)
// ---------------------------------------------------------------------------
__global__ __launch_bounds__(256) void final_ln(
    const float* __restrict__ x, const float* __restrict__ p,
    const float* __restrict__ g, const float* __restrict__ beta,
    float* __restrict__ out) {
    int row = blockIdx.x;
    int tid = threadIdx.x;
    const float* xr = x + (size_t)row * CC;
    const float* pr = p + (size_t)row * CC;
    float v[4];
    float s = 0.f;
#pragma unroll
    for (int i = 0; i < 4; ++i) {
        int c = i * 256 + tid;
        v[i] = xr[c] + pr[c];
        s += v[i];
    }
    __shared__ float red[256];
    red[tid] = s;
    __syncthreads();
#pragma unroll
    for (int o = 128; o > 0; o >>= 1) {
        if (tid < o) red[tid] += red[tid + o];
        __syncthreads();
    }
    float mean = red[0] * (1.0f / CC);
    __syncthreads();
    s = 0.f;
#pragma unroll
    for (int i = 0; i < 4; ++i) {
        float d = v[i] - mean;
        s += d * d;
    }
    red[tid] = s;
    __syncthreads();
#pragma unroll
    for (int o = 128; o > 0; o >>= 1) {
        if (tid < o) red[tid] += red[tid + o];
        __syncthreads();
    }
    float inv = rsqrtf(red[0] * (1.0f / CC) + 1e-5f);
#pragma unroll
    for (int i = 0; i < 4; ++i) {
        int c = i * 256 + tid;
        out[(size_t)row * CC + c] = (v[i] - mean) * inv * g[c] + beta[c];
    }
}

extern "C" void kernel_launch(void* const* d_in, const int* in_sizes, int n_in,
                              void* d_out, int out_size, void* d_ws,
                              size_t ws_size, hipStream_t stream) {
    const float* x        = (const float*)d_in[0];
    const int*   mask     = (const int*)d_in[1];
    const float* imp_w1   = (const float*)d_in[2];
    const float* imp_b1   = (const float*)d_in[3];
    const float* imp_g    = (const float*)d_in[4];
    const float* imp_beta = (const float*)d_in[5];
    const float* imp_w2   = (const float*)d_in[6];
    const float* imp_b2   = (const float*)d_in[7];
    const float* rsn_w1   = (const float*)d_in[8];
    const float* rsn_b1   = (const float*)d_in[9];
    const float* rsn_g    = (const float*)d_in[10];
    const float* rsn_beta = (const float*)d_in[11];
    const float* rsn_w2   = (const float*)d_in[12];
    const float* rsn_b2   = (const float*)d_in[13];
    const float* q_w      = (const float*)d_in[14];
    const float* q_b      = (const float*)d_in[15];
    const float* k_w      = (const float*)d_in[16];
    const float* k_b      = (const float*)d_in[17];
    const float* v_w      = (const float*)d_in[18];
    const float* v_b      = (const float*)d_in[19];
    const float* o_w      = (const float*)d_in[20];
    const float* o_b      = (const float*)d_in[21];
    const float* tmp_w1   = (const float*)d_in[22];
    const float* tmp_b1   = (const float*)d_in[23];
    const float* tmp_g    = (const float*)d_in[24];
    const float* tmp_beta = (const float*)d_in[25];
    const float* tmp_w2   = (const float*)d_in[26];
    const float* tmp_b2   = (const float*)d_in[27];
    const float* norm_g   = (const float*)d_in[28];
    const float* norm_b   = (const float*)d_in[29];
    float* out = (float*)d_out;
    float* ws  = (float*)d_ws;

    // workspace layout (float offsets)
    float* h1  = ws;                       // [4096,512] fp32
    float* h2  = ws + 2097152;             // [4096,1024] fp32 (later o-proj out)
    __hip_bfloat16* x_bf  = (__hip_bfloat16*)(ws + 6291456);
    __hip_bfloat16* xi_bf = (__hip_bfloat16*)(ws + 8388608);
    __hip_bfloat16* h2b   = (__hip_bfloat16*)(ws + 10485760);
    __hip_bfloat16* rs_bf = (__hip_bfloat16*)(ws + 12582912);  // reasoned, later attn out
    __hip_bfloat16* qb    = (__hip_bfloat16*)(ws + 14680064);
    __hip_bfloat16* kb    = (__hip_bfloat16*)(ws + 16777216);
    __hip_bfloat16* vtb   = (__hip_bfloat16*)(ws + 20971520);  // [32,64,2048]
    __hip_bfloat16* imp_w1t = (__hip_bfloat16*)(ws + 23068672);  // [512,1024]
    __hip_bfloat16* rsn_w1t = (__hip_bfloat16*)(ws + 23330816);  // [1024,1024]
    __hip_bfloat16* rsn_w2t = (__hip_bfloat16*)(ws + 23855104);
    __hip_bfloat16* q_wt    = (__hip_bfloat16*)(ws + 24379392);
    __hip_bfloat16* k_wt    = (__hip_bfloat16*)(ws + 24903680);
    __hip_bfloat16* v_wt    = (__hip_bfloat16*)(ws + 25427968);
    __hip_bfloat16* o_wt    = (__hip_bfloat16*)(ws + 25952256);
    float* tmp  = ws + 26478592;   // [2,16]
    float* part = ws + 26479104;   // [2,16,1024]
    int*   flg  = (int*)(ws + 26511872);  // [2,32,32]
    float* acc1 = ws + 26513920;   // [2,512]

    dim3 blk(256);
    // fused prep: x->bf16, mask flags, 7 weight transposes
    prep<<<5760, blk, 0, stream>>>(
        x, x_bf, mask, flg,
        imp_w1, rsn_w1, rsn_w2, q_w, k_w, v_w, o_w,
        imp_w1t, rsn_w1t, rsn_w2t, q_wt, k_wt, v_wt, o_wt);

    // importance net (GEMM + fused LN/GELU/gate)
    gemm_mfma64<false><<<dim3(CHALF / 128, NN / 64), blk, 0, stream>>>(
        (const short*)x_bf, (const short*)imp_w1t, imp_b1, h1, nullptr, NN, CHALF, CC);
    imp_fused<<<NN, blk, 0, stream>>>(h1, imp_g, imp_beta, imp_w2, imp_b2, x, xi_bf);
    // reasoning net
    gemm_mfma64<false><<<dim3(CC / 128, NN / 64), blk, 0, stream>>>(
        (const short*)xi_bf, (const short*)rsn_w1t, rsn_b1, h2, nullptr, NN, CC, CC);
    ln_gelu_bf16<CC><<<NN, blk, 0, stream>>>(h2, rsn_g, rsn_beta, h2b);
    gemm_mfma64<true><<<dim3(CC / 128, NN / 64), blk, 0, stream>>>(
        (const short*)h2b, (const short*)rsn_w2t, rsn_b2, nullptr, rs_bf, NN, CC, CC);
    // temperature net
    mean_part<<<128, blk, 0, stream>>>(rs_bf, part);
    temp_gemv1<<<dim3(CHALF / 64, BB), blk, 0, stream>>>(part, tmp_w1, tmp_b1, acc1);
    temp_fin<<<BB, dim3(512), 0, stream>>>(acc1, tmp_g, tmp_beta, tmp_w2, tmp_b2, tmp);
    // q/k/v projections batched; q scaled by temp/8*log2e; v written transposed
    gemm_qkv<<<dim3(CC / 128, NN / 128, 3), blk, 0, stream>>>(
        (const short*)rs_bf, (const short*)xi_bf, (const short*)x_bf,
        (const short*)q_wt, (const short*)k_wt, (const short*)v_wt,
        q_b, k_b, v_b, qb, kb, vtb, tmp);
    // flash attention v7 (O^T accumulation, ballot-gated rescale)
    flash_attn_mfma<<<dim3(TT / 128, BB * HH), blk, 0, stream>>>(
        (const short*)qb, (const short*)kb, (const short*)vtb, mask, flg, rs_bf);
    // output projection + residual LN
    gemm_mfma64<false><<<dim3(CC / 128, NN / 64), blk, 0, stream>>>(
        (const short*)rs_bf, (const short*)o_wt, o_b, h2, nullptr, NN, CC, CC);
    final_ln<<<NN, blk, 0, stream>>>(x, h2, norm_g, norm_b, out);
}

// Round 11
// 413.766 us; speedup vs baseline: 4.5758x; 1.0004x over previous
//
#include <hip/hip_runtime.h>
#include <hip/hip_bf16.h>
#include <math.h>

// Problem constants
#define BB 2
#define TT 2048
#define CC 1024
#define HH 16
#define DD 64
#define CHALF 512
#define NN (BB * TT)   // 4096 rows
#define LOG2E 1.44269504088896340736f

typedef __attribute__((ext_vector_type(8))) short short8;
typedef __attribute__((ext_vector_type(4))) short short4_t;
typedef __attribute__((ext_vector_type(4))) float f32x4;

__device__ __forceinline__ float gelu_exact(float x) {
    return 0.5f * x * (1.0f + erff(x * 0.70710678118654752f));
}

__device__ __forceinline__ short f2bf(float f) {
    __hip_bfloat16 h = __float2bfloat16(f);
    short s;
    __builtin_memcpy(&s, &h, 2);
    return s;
}

__device__ __forceinline__ float bf2f(short s) {
    __hip_bfloat16 h;
    __builtin_memcpy(&h, &s, 2);
    return __bfloat162float(h);
}

__device__ __forceinline__ short4_t pack_bf16x4(float a, float b, float c,
                                                float d) {
    short4_t s4;
    s4[0] = f2bf(a);
    s4[1] = f2bf(b);
    s4[2] = f2bf(c);
    s4[3] = f2bf(d);
    return s4;
}

// async global->LDS, 16 B per lane; LDS dst must be wave-uniform base
__device__ __forceinline__ void async_copy16(const void* g, void* l) {
    __builtin_amdgcn_global_load_lds(
        (const __attribute__((address_space(1))) void*)g,
        (__attribute__((address_space(3))) void*)l, 16, 0, 0);
}

// ---------------------------------------------------------------------------
// prep: one launch for x->bf16 convert, mask tile flags, 7 weight transposes.
// ---------------------------------------------------------------------------
__global__ __launch_bounds__(256) void prep(
    const float* __restrict__ x, __hip_bfloat16* __restrict__ x_bf,
    const int* __restrict__ mask, int* __restrict__ flags,
    const float* w0, const float* w1, const float* w2, const float* w3,
    const float* w4, const float* w5, const float* w6,
    __hip_bfloat16* t0, __hip_bfloat16* t1, __hip_bfloat16* t2,
    __hip_bfloat16* t3, __hip_bfloat16* t4, __hip_bfloat16* t5,
    __hip_bfloat16* t6) {
    __shared__ float T[64][65];
    int blk = blockIdx.x;
    int tid = threadIdx.x;
    if (blk < 2048) {
        int i = (blk * 256 + tid) * 8;
        float4 a = *(const float4*)&x[i];
        float4 b = *(const float4*)&x[i + 4];
        __hip_bfloat16 o[8] = {
            __float2bfloat16(a.x), __float2bfloat16(a.y),
            __float2bfloat16(a.z), __float2bfloat16(a.w),
            __float2bfloat16(b.x), __float2bfloat16(b.y),
            __float2bfloat16(b.z), __float2bfloat16(b.w)};
        *(float4*)&x_bf[i] = *(float4*)o;
    } else if (blk < 4096) {
        int idx = blk - 2048;
        int kt = idx & 31, qt = (idx >> 5) & 31, b = idx >> 10;
        int* red = (int*)T;
        int r = tid >> 2;
        int c0 = (tid & 3) * 16;
        const int* base =
            mask + ((size_t)(b * TT + qt * 64 + r)) * TT + kt * 64 + c0;
        int all = 1;
#pragma unroll
        for (int i = 0; i < 4; ++i) {
            int4 m4 = *(const int4*)(base + i * 4);
            all &= (m4.x != 0) & (m4.y != 0) & (m4.z != 0) & (m4.w != 0);
        }
        red[tid] = all;
        __syncthreads();
#pragma unroll
        for (int o = 128; o > 0; o >>= 1) {
            if (tid < o) red[tid] &= red[tid + o];
            __syncthreads();
        }
        if (tid == 0) flags[(b * 32 + qt) * 32 + kt] = red[0];
    } else {
        int idx = blk - 4096;
        const float* W;
        __hip_bfloat16* Wt;
        int N, n0, k0;
        if (idx < 128) {
            W = w0; Wt = t0; N = 512;
            n0 = (idx & 7) * 64;
            k0 = (idx >> 3) * 64;
        } else {
            idx -= 128;
            int w = idx >> 8;
            int r = idx & 255;
            N = 1024;
            n0 = (r & 15) * 64;
            k0 = (r >> 4) * 64;
            switch (w) {
                case 0: W = w1; Wt = t1; break;
                case 1: W = w2; Wt = t2; break;
                case 2: W = w3; Wt = t3; break;
                case 3: W = w4; Wt = t4; break;
                case 4: W = w5; Wt = t5; break;
                default: W = w6; Wt = t6; break;
            }
        }
        int c = tid & 63, r4 = tid >> 6;
#pragma unroll
        for (int i = 0; i < 16; ++i) {
            int row = i * 4 + r4;
            T[row][c] = W[(size_t)(k0 + row) * N + n0 + c];
        }
        __syncthreads();
#pragma unroll
        for (int i = 0; i < 16; ++i) {
            int row = i * 4 + r4;  // n index
            Wt[(size_t)(n0 + row) * CC + k0 + c] = __float2bfloat16(T[c][row]);
        }
    }
}

// ---------------------------------------------------------------------------
// bf16 MFMA GEMM, 64x128 tile, BK=64 (16 MFMA/barrier): C = A @ Wt^T + bias
// ---------------------------------------------------------------------------
template <bool BF16OUT>
__global__ __launch_bounds__(256) void gemm_mfma64(
    const short* __restrict__ A, const short* __restrict__ Wt,
    const float* __restrict__ bias, float* __restrict__ Cf,
    __hip_bfloat16* __restrict__ Cb, int M, int N, int K) {
    __shared__ short As0[64][32], As1[64][32];
    __shared__ short Bs0[128][32], Bs1[128][32];
    int tid = threadIdx.x;
    int wave = tid >> 6, lane = tid & 63;
    int m16 = lane & 15, quad = lane >> 4;
    int wm = wave >> 1, wn = wave & 1;
    int row0 = blockIdx.y * 64, col0 = blockIdx.x * 128;
    int lr = lane >> 2;        // 0..15
    int kof = (lane & 3) * 8;

    f32x4 acc[2][4];
#pragma unroll
    for (int i = 0; i < 2; ++i)
#pragma unroll
        for (int j = 0; j < 4; ++j) acc[i][j] = (f32x4){0.f, 0.f, 0.f, 0.f};

    for (int k0 = 0; k0 < K; k0 += 64) {
        const short* arow = A + (size_t)(row0 + wave * 16 + lr) * K + k0 + kof;
        async_copy16(arow, &As0[wave * 16][0]);
        async_copy16(arow + 32, &As1[wave * 16][0]);
#pragma unroll
        for (int j = 0; j < 2; ++j) {
            int rbase = wave * 32 + j * 16;
            const short* brow =
                Wt + (size_t)(col0 + rbase + lr) * K + k0 + kof;
            async_copy16(brow, &Bs0[rbase][0]);
            async_copy16(brow + 32, &Bs1[rbase][0]);
        }
        __syncthreads();
#pragma unroll
        for (int kc = 0; kc < 2; ++kc) {
            short8 af[2], bfr[4];
#pragma unroll
            for (int i = 0; i < 2; ++i)
                af[i] = kc ? *(const short8*)&As1[wm * 32 + i * 16 + m16][quad * 8]
                           : *(const short8*)&As0[wm * 32 + i * 16 + m16][quad * 8];
#pragma unroll
            for (int j = 0; j < 4; ++j)
                bfr[j] = kc ? *(const short8*)&Bs1[wn * 64 + j * 16 + m16][quad * 8]
                            : *(const short8*)&Bs0[wn * 64 + j * 16 + m16][quad * 8];
#pragma unroll
            for (int i = 0; i < 2; ++i)
#pragma unroll
                for (int j = 0; j < 4; ++j)
                    acc[i][j] = __builtin_amdgcn_mfma_f32_16x16x32_bf16(
                        af[i], bfr[j], acc[i][j], 0, 0, 0);
        }
        __syncthreads();
    }
#pragma unroll
    for (int i = 0; i < 2; ++i) {
#pragma unroll
        for (int j = 0; j < 4; ++j) {
            int col = col0 + wn * 64 + j * 16 + m16;
            float bv = bias[col];
#pragma unroll
            for (int rr = 0; rr < 4; ++rr) {
                int row = row0 + wm * 32 + i * 16 + quad * 4 + rr;
                float val = acc[i][j][rr] + bv;
                if (BF16OUT)
                    Cb[(size_t)row * N + col] = __float2bfloat16(val);
                else
                    Cf[(size_t)row * N + col] = val;
            }
        }
    }
}

// ---------------------------------------------------------------------------
// Batched q/k/v projections, 128x128 tile, BK=64 (32 MFMA/barrier).
// z=0: q scaled by temp/8*log2e; z=1: k; z=2: v written TRANSPOSED (vt)
// ---------------------------------------------------------------------------
__global__ __launch_bounds__(256) void gemm_qkv(
    const short* __restrict__ Aq, const short* __restrict__ Ak,
    const short* __restrict__ Av, const short* __restrict__ Wq,
    const short* __restrict__ Wk, const short* __restrict__ Wv,
    const float* __restrict__ bq, const float* __restrict__ bk,
    const float* __restrict__ bv, __hip_bfloat16* __restrict__ Cq,
    __hip_bfloat16* __restrict__ Ck, __hip_bfloat16* __restrict__ Cv,
    const float* __restrict__ tmp) {
    int z = blockIdx.z;
    const short* A = (z == 0) ? Aq : (z == 1) ? Ak : Av;
    const short* Wt = (z == 0) ? Wq : (z == 1) ? Wk : Wv;
    const float* bias = (z == 0) ? bq : (z == 1) ? bk : bv;

    __shared__ short As0[128][32], As1[128][32];
    __shared__ short Bs0[128][32], Bs1[128][32];
    int tid = threadIdx.x;
    int wave = tid >> 6, lane = tid & 63;
    int m16 = lane & 15, quad = lane >> 4;
    int wm = wave >> 1, wn = wave & 1;
    int row0 = blockIdx.y * 128, col0 = blockIdx.x * 128;
    int lr = lane >> 2;
    int kof = (lane & 3) * 8;

    float scale = 1.0f;
    if (z == 0)
        scale = tmp[(row0 >> 11) * HH + (col0 >> 6) + wn] * 0.125f * LOG2E;

    f32x4 acc[4][4];
#pragma unroll
    for (int i = 0; i < 4; ++i)
#pragma unroll
        for (int j = 0; j < 4; ++j) acc[i][j] = (f32x4){0.f, 0.f, 0.f, 0.f};

    for (int k0 = 0; k0 < CC; k0 += 64) {
#pragma unroll
        for (int j = 0; j < 2; ++j) {
            int rbase = wave * 32 + j * 16;
            const short* ar = A + (size_t)(row0 + rbase + lr) * CC + k0 + kof;
            async_copy16(ar, &As0[rbase][0]);
            async_copy16(ar + 32, &As1[rbase][0]);
            const short* br = Wt + (size_t)(col0 + rbase + lr) * CC + k0 + kof;
            async_copy16(br, &Bs0[rbase][0]);
            async_copy16(br + 32, &Bs1[rbase][0]);
        }
        __syncthreads();
#pragma unroll
        for (int kc = 0; kc < 2; ++kc) {
            short8 af[4], bfr[4];
#pragma unroll
            for (int i = 0; i < 4; ++i)
                af[i] = kc ? *(const short8*)&As1[wm * 64 + i * 16 + m16][quad * 8]
                           : *(const short8*)&As0[wm * 64 + i * 16 + m16][quad * 8];
#pragma unroll
            for (int j = 0; j < 4; ++j)
                bfr[j] = kc ? *(const short8*)&Bs1[wn * 64 + j * 16 + m16][quad * 8]
                            : *(const short8*)&Bs0[wn * 64 + j * 16 + m16][quad * 8];
#pragma unroll
            for (int i = 0; i < 4; ++i)
#pragma unroll
                for (int j = 0; j < 4; ++j)
                    acc[i][j] = __builtin_amdgcn_mfma_f32_16x16x32_bf16(
                        af[i], bfr[j], acc[i][j], 0, 0, 0);
        }
        __syncthreads();
    }
    if (z == 2) {
        int b = row0 >> 11;
        int t0r = (row0 & (TT - 1)) + wm * 64 + quad * 4;
#pragma unroll
        for (int i = 0; i < 4; ++i) {
#pragma unroll
            for (int j = 0; j < 4; ++j) {
                int col = col0 + wn * 64 + j * 16 + m16;
                int h = col >> 6, d = col & 63;
                float bv2 = bias[col];
                short4_t pk = pack_bf16x4(
                    acc[i][j][0] + bv2, acc[i][j][1] + bv2,
                    acc[i][j][2] + bv2, acc[i][j][3] + bv2);
                *(short4_t*)&Cv[(((size_t)(b * HH + h) * DD) + d) * TT + t0r +
                                i * 16] = pk;
            }
        }
    } else {
        __hip_bfloat16* C = (z == 0) ? Cq : Ck;
#pragma unroll
        for (int i = 0; i < 4; ++i) {
#pragma unroll
            for (int j = 0; j < 4; ++j) {
                int col = col0 + wn * 64 + j * 16 + m16;
                float bv2 = bias[col];
#pragma unroll
                for (int rr = 0; rr < 4; ++rr) {
                    int row = row0 + wm * 64 + i * 16 + quad * 4 + rr;
                    C[(size_t)row * CC + col] =
                        __float2bfloat16((acc[i][j][rr] + bv2) * scale);
                }
            }
        }
    }
}

// ---------------------------------------------------------------------------
// fused importance epilogue: LN(h1)+GELU -> dot w2 -> sigmoid -> xi = x*imp
// ---------------------------------------------------------------------------
__global__ __launch_bounds__(256) void imp_fused(
    const float* __restrict__ h1, const float* __restrict__ g,
    const float* __restrict__ beta, const float* __restrict__ w2,
    const float* __restrict__ b2, const float* __restrict__ x,
    __hip_bfloat16* __restrict__ xi) {
    int row = blockIdx.x;
    int tid = threadIdx.x;
    const float* hr = h1 + (size_t)row * CHALF;
    float v0 = hr[tid], v1 = hr[tid + 256];
    __shared__ float red[256];
    red[tid] = v0 + v1;
    __syncthreads();
#pragma unroll
    for (int o = 128; o > 0; o >>= 1) {
        if (tid < o) red[tid] += red[tid + o];
        __syncthreads();
    }
    float mean = red[0] * (1.0f / CHALF);
    __syncthreads();
    float d0 = v0 - mean, d1 = v1 - mean;
    red[tid] = d0 * d0 + d1 * d1;
    __syncthreads();
#pragma unroll
    for (int o = 128; o > 0; o >>= 1) {
        if (tid < o) red[tid] += red[tid + o];
        __syncthreads();
    }
    float inv = rsqrtf(red[0] * (1.0f / CHALF) + 1e-5f);
    __syncthreads();
    float ge0 = gelu_exact(d0 * inv * g[tid] + beta[tid]);
    float ge1 = gelu_exact(d1 * inv * g[tid + 256] + beta[tid + 256]);
    red[tid] = ge0 * w2[tid] + ge1 * w2[tid + 256];
    __syncthreads();
#pragma unroll
    for (int o = 128; o > 0; o >>= 1) {
        if (tid < o) red[tid] += red[tid + o];
        __syncthreads();
    }
    float z = red[0] + b2[0];
    float sg = 1.0f / (1.0f + expf(-z));
    float imp = fmaxf(sg, 1e-6f);
#pragma unroll
    for (int i = 0; i < 4; ++i) {
        int c = i * 256 + tid;
        xi[(size_t)row * CC + c] =
            __float2bfloat16(x[(size_t)row * CC + c] * imp);
    }
}

// ---------------------------------------------------------------------------
// LN + GELU, bf16 in -> bf16 out (vectorized short4 per thread)
// ---------------------------------------------------------------------------
__global__ __launch_bounds__(256) void ln_gelu_bb(
    const __hip_bfloat16* __restrict__ Y, const float* __restrict__ g,
    const float* __restrict__ beta, __hip_bfloat16* __restrict__ O) {
    int row = blockIdx.x;
    int tid = threadIdx.x;
    int c0 = tid * 4;
    short4_t raw = *(const short4_t*)&Y[(size_t)row * CC + c0];
    float v[4];
    float s = 0.f;
#pragma unroll
    for (int i = 0; i < 4; ++i) {
        v[i] = bf2f(raw[i]);
        s += v[i];
    }
    __shared__ float red[256];
    red[tid] = s;
    __syncthreads();
#pragma unroll
    for (int o = 128; o > 0; o >>= 1) {
        if (tid < o) red[tid] += red[tid + o];
        __syncthreads();
    }
    float mean = red[0] * (1.0f / CC);
    __syncthreads();
    s = 0.f;
#pragma unroll
    for (int i = 0; i < 4; ++i) {
        float d = v[i] - mean;
        s += d * d;
    }
    red[tid] = s;
    __syncthreads();
#pragma unroll
    for (int o = 128; o > 0; o >>= 1) {
        if (tid < o) red[tid] += red[tid + o];
        __syncthreads();
    }
    float inv = rsqrtf(red[0] * (1.0f / CC) + 1e-5f);
    float4 gg = *(const float4*)&g[c0];
    float4 bb = *(const float4*)&beta[c0];
    short4_t ov = pack_bf16x4(
        gelu_exact((v[0] - mean) * inv * gg.x + bb.x),
        gelu_exact((v[1] - mean) * inv * gg.y + bb.y),
        gelu_exact((v[2] - mean) * inv * gg.z + bb.z),
        gelu_exact((v[3] - mean) * inv * gg.w + bb.w));
    *(short4_t*)&O[(size_t)row * CC + c0] = ov;
}

// ---------------------------------------------------------------------------
// reasoned.mean(axis=1), stage 1 (partials over 128-row chunks)
// ---------------------------------------------------------------------------
__global__ __launch_bounds__(256) void mean_part(
    const __hip_bfloat16* __restrict__ R, float* __restrict__ part) {
    int idx = blockIdx.x * 256 + threadIdx.x;
    int c = idx & (CC - 1);
    int chunk = (idx >> 10) & 15;
    int b = idx >> 14;
    const __hip_bfloat16* base = R + ((size_t)(b * TT + chunk * 128)) * CC + c;
    float s = 0.f;
    for (int t = 0; t < 128; ++t) s += __bfloat162float(base[(size_t)t * CC]);
    part[idx] = s;
}

// ---------------------------------------------------------------------------
// temp_net stage 1 (+ fused mean finalize): acc1[b,col] = rm @ w1 + b1
// ---------------------------------------------------------------------------
__global__ __launch_bounds__(256) void temp_gemv1(
    const float* __restrict__ part, const float* __restrict__ w1,
    const float* __restrict__ b1, float* __restrict__ acc1) {
    __shared__ float rm_l[CC];
    __shared__ float red[256];
    int b = blockIdx.y;
    int c0 = blockIdx.x * 64;
    int tid = threadIdx.x;
    for (int cc = tid; cc < CC; cc += 256) {
        float s = 0.f;
#pragma unroll
        for (int ch = 0; ch < 16; ++ch)
            s += part[(size_t)(b * 16 + ch) * CC + cc];
        rm_l[cc] = s * (1.0f / TT);
    }
    __syncthreads();
    int col = c0 + (tid & 63);
    int kq = tid >> 6;  // 0..3
    float s = 0.f;
#pragma unroll 8
    for (int i = kq * 256; i < kq * 256 + 256; ++i)
        s = fmaf(rm_l[i], w1[(size_t)i * CHALF + col], s);
    red[tid] = s;
    __syncthreads();
    if (tid < 64) {
        float t = red[tid] + red[tid + 64] + red[tid + 128] + red[tid + 192];
        acc1[b * CHALF + tid + c0] = t + b1[col];
    }
}

// ---------------------------------------------------------------------------
// temp_net stage 2: LN(acc1) -> GELU -> @w2 + b2 -> softplus + 0.5
// ---------------------------------------------------------------------------
__global__ __launch_bounds__(512) void temp_fin(
    const float* __restrict__ acc1, const float* __restrict__ g,
    const float* __restrict__ beta, const float* __restrict__ w2,
    const float* __restrict__ b2, float* __restrict__ temp) {
    __shared__ float red[512];
    __shared__ float wred[8][16];
    int b = blockIdx.x;
    int tid = threadIdx.x;
    int wave = tid >> 6, lane = tid & 63;
    float acc = acc1[b * CHALF + tid];
    red[tid] = acc;
    __syncthreads();
#pragma unroll
    for (int o = 256; o > 0; o >>= 1) {
        if (tid < o) red[tid] += red[tid + o];
        __syncthreads();
    }
    float mean = red[0] * (1.0f / CHALF);
    __syncthreads();
    float d = acc - mean;
    red[tid] = d * d;
    __syncthreads();
#pragma unroll
    for (int o = 256; o > 0; o >>= 1) {
        if (tid < o) red[tid] += red[tid + o];
        __syncthreads();
    }
    float inv = rsqrtf(red[0] * (1.0f / CHALF) + 1e-5f);
    float ht = gelu_exact((acc - mean) * inv * g[tid] + beta[tid]);
    float p[16];
#pragma unroll
    for (int j = 0; j < 16; ++j) p[j] = ht * w2[tid * HH + j];
#pragma unroll
    for (int off = 1; off < 64; off <<= 1)
#pragma unroll
        for (int j = 0; j < 16; ++j) p[j] += __shfl_xor(p[j], off, 64);
    if (lane == 0)
#pragma unroll
        for (int j = 0; j < 16; ++j) wred[wave][j] = p[j];
    __syncthreads();
    if (tid < HH) {
        float s = b2[tid];
#pragma unroll
        for (int w = 0; w < 8; ++w) s += wred[w][tid];
        float sp = fmaxf(s, 0.f) + log1pf(expf(-fabsf(s)));
        temp[b * HH + tid] = sp + 0.5f;
    }
}

// ---------------------------------------------------------------------------
// MFMA flash attention v7: 128-row q-tile, transposed-QK softmax, O^T PV
// (per-lane alpha/l), ballot-gated rescale, raw v_exp_f32.
// ---------------------------------------------------------------------------
__global__ __launch_bounds__(256) void flash_attn_mfma(
    const short* __restrict__ q, const short* __restrict__ k,
    const short* __restrict__ vt, const int* __restrict__ mask,
    const int* __restrict__ flags, __hip_bfloat16* __restrict__ out) {
    __shared__ short Ks[64][72];    // [key][d]
    __shared__ short Vt[64][72];    // [d][key]
    __shared__ short Ps[128][72];   // [q-row][key], wave-private strips
    int tid = threadIdx.x;
    int wave = tid >> 6, lane = tid & 63;
    int m16 = lane & 15, quad = lane >> 4;
    int qt = blockIdx.x;            // 128-row q tile
    int q0 = qt * 128;
    int bh = blockIdx.y;
    int b = bh >> 4, h = bh & 15;

    short8 qf[2][2];
#pragma unroll
    for (int qg = 0; qg < 2; ++qg) {
        const short* qrow = q + ((size_t)(b * TT + q0 + wave * 32 + qg * 16 + m16)) * CC +
                            h * DD + quad * 8;
        qf[qg][0] = *(const short8*)(qrow);
        qf[qg][1] = *(const short8*)(qrow + 32);
    }

    float m_run[2] = {-INFINITY, -INFINITY};
    float l_run[2] = {0.f, 0.f};
    f32x4 acc_o[2][4];
#pragma unroll
    for (int qg = 0; qg < 2; ++qg)
#pragma unroll
        for (int t = 0; t < 4; ++t) acc_o[qg][t] = (f32x4){0.f, 0.f, 0.f, 0.f};

    for (int kt = 0; kt < TT / 64; ++kt) {
        int kb = kt * 64;
#pragma unroll
        for (int i = 0; i < 2; ++i) {
            int idx = i * 256 + tid;
            int r = idx >> 3;
            int dc = (idx & 7) * 8;
            *(short8*)&Ks[r][dc] =
                *(const short8*)(k + ((size_t)(b * TT + kb + r)) * CC + h * DD + dc);
            *(short8*)&Vt[r][dc] =
                *(const short8*)(vt + ((size_t)bh * DD + r) * TT + kb + dc);
        }
        __syncthreads();

        short8 kf[4][2];
#pragma unroll
        for (int t = 0; t < 4; ++t) {
            kf[t][0] = *(const short8*)&Ks[t * 16 + m16][quad * 8];
            kf[t][1] = *(const short8*)&Ks[t * 16 + m16][32 + quad * 8];
        }
        int fl = flags[(b * 32 + 2 * qt + (wave >> 1)) * 32 + kt];

#pragma unroll
        for (int qg = 0; qg < 2; ++qg) {
            f32x4 sacc[4];
#pragma unroll
            for (int t = 0; t < 4; ++t) sacc[t] = (f32x4){0.f, 0.f, 0.f, 0.f};
#pragma unroll
            for (int t = 0; t < 4; ++t) {
                sacc[t] = __builtin_amdgcn_mfma_f32_16x16x32_bf16(kf[t][0], qf[qg][0], sacc[t], 0, 0, 0);
                sacc[t] = __builtin_amdgcn_mfma_f32_16x16x32_bf16(kf[t][1], qf[qg][1], sacc[t], 0, 0, 0);
            }
            float sv[4][4];
#pragma unroll
            for (int t = 0; t < 4; ++t)
#pragma unroll
                for (int r = 0; r < 4; ++r) sv[t][r] = sacc[t][r];
            if (fl == 0) {
                int qrow = q0 + wave * 32 + qg * 16 + m16;
#pragma unroll
                for (int t = 0; t < 4; ++t)
#pragma unroll
                    for (int r = 0; r < 4; ++r) {
                        int kg = kb + t * 16 + quad * 4 + r;
                        if (mask[((size_t)(b * TT + qrow)) * TT + kg] == 0)
                            sv[t][r] = -INFINITY;
                    }
            }
            float mx = sv[0][0];
#pragma unroll
            for (int t = 0; t < 4; ++t)
#pragma unroll
                for (int r = 0; r < 4; ++r) mx = fmaxf(mx, sv[t][r]);
            mx = fmaxf(mx, __shfl_xor(mx, 16, 64));
            mx = fmaxf(mx, __shfl_xor(mx, 32, 64));
            float mnew = fmaxf(m_run[qg], mx);
            if (__any(mnew > m_run[qg])) {
                float alpha = __builtin_amdgcn_exp2f(m_run[qg] - mnew);
                l_run[qg] *= alpha;
#pragma unroll
                for (int td = 0; td < 4; ++td)
#pragma unroll
                    for (int r = 0; r < 4; ++r) acc_o[qg][td][r] *= alpha;
            }
            m_run[qg] = mnew;
            int prow = wave * 32 + qg * 16 + m16;
            float psum = 0.f;
#pragma unroll
            for (int t = 0; t < 4; ++t) {
                short4_t pk;
#pragma unroll
                for (int r = 0; r < 4; ++r) {
                    float p = __builtin_amdgcn_exp2f(sv[t][r] - mnew);
                    psum += p;
                    pk[r] = f2bf(p);
                }
                *(short4_t*)&Ps[prow][t * 16 + quad * 4] = pk;
            }
            psum += __shfl_xor(psum, 16, 64);
            psum += __shfl_xor(psum, 32, 64);
            l_run[qg] += psum;
        }

        // PV as O^T = V^T P^T
#pragma unroll
        for (int kc = 0; kc < 2; ++kc) {
            short8 vf[4];
#pragma unroll
            for (int td = 0; td < 4; ++td)
                vf[td] = *(const short8*)&Vt[td * 16 + m16][kc * 32 + quad * 8];
#pragma unroll
            for (int qg = 0; qg < 2; ++qg) {
                short8 pf = *(const short8*)&Ps[wave * 32 + qg * 16 + m16][kc * 32 + quad * 8];
#pragma unroll
                for (int td = 0; td < 4; ++td)
                    acc_o[qg][td] = __builtin_amdgcn_mfma_f32_16x16x32_bf16(
                        vf[td], pf, acc_o[qg][td], 0, 0, 0);
            }
        }
        __syncthreads();
    }

#pragma unroll
    for (int qg = 0; qg < 2; ++qg) {
        float inv = 1.0f / l_run[qg];
        int row = b * TT + q0 + wave * 32 + qg * 16 + m16;
#pragma unroll
        for (int td = 0; td < 4; ++td) {
            short4_t pk = pack_bf16x4(
                acc_o[qg][td][0] * inv, acc_o[qg][td][1] * inv,
                acc_o[qg][td][2] * inv, acc_o[qg][td][3] * inv);
            *(short4_t*)&out[(size_t)row * CC + h * DD + td * 16 + quad * 4] = pk;
        }
    }
}

// ---------------------------------------------------------------------------
// Final: out = LN(x + proj), proj in bf16 (vectorized 4/thread)
// ---------------------------------------------------------------------------
__global__ __launch_bounds__(256) void final_ln_b(
    const float* __restrict__ x, const __hip_bfloat16* __restrict__ p,
    const float* __restrict__ g, const float* __restrict__ beta,
    float* __restrict__ out) {
    int row = blockIdx.x;
    int tid = threadIdx.x;
    int c0 = tid * 4;
    float4 xv = *(const float4*)&x[(size_t)row * CC + c0];
    short4_t pv = *(const short4_t*)&p[(size_t)row * CC + c0];
    float v[4] = {xv.x + bf2f(pv[0]), xv.y + bf2f(pv[1]),
                  xv.z + bf2f(pv[2]), xv.w + bf2f(pv[3])};
    float s = v[0] + v[1] + v[2] + v[3];
    __shared__ float red[256];
    red[tid] = s;
    __syncthreads();
#pragma unroll
    for (int o = 128; o > 0; o >>= 1) {
        if (tid < o) red[tid] += red[tid + o];
        __syncthreads();
    }
    float mean = red[0] * (1.0f / CC);
    __syncthreads();
    s = 0.f;
#pragma unroll
    for (int i = 0; i < 4; ++i) {
        float d = v[i] - mean;
        s += d * d;
    }
    red[tid] = s;
    __syncthreads();
#pragma unroll
    for (int o = 128; o > 0; o >>= 1) {
        if (tid < o) red[tid] += red[tid + o];
        __syncthreads();
    }
    float inv = rsqrtf(red[0] * (1.0f / CC) + 1e-5f);
    float4 gg = *(const float4*)&g[c0];
    float4 bb = *(const float4*)&beta[c0];
    float4 ov = {(v[0] - mean) * inv * gg.x + bb.x,
                 (v[1] - mean) * inv * gg.y + bb.y,
                 (v[2] - mean) * inv * gg.z + bb.z,
                 (v[3] - mean) * inv * gg.w + bb.w};
    *(float4*)&out[(size_t)row * CC + c0] = ov;
}

extern "C" void kernel_launch(void* const* d_in, const int* in_sizes, int n_in,
                              void* d_out, int out_size, void* d_ws,
                              size_t ws_size, hipStream_t stream) {
    const float* x        = (const float*)d_in[0];
    const int*   mask     = (const int*)d_in[1];
    const float* imp_w1   = (const float*)d_in[2];
    const float* imp_b1   = (const float*)d_in[3];
    const float* imp_g    = (const float*)d_in[4];
    const float* imp_beta = (const float*)d_in[5];
    const float* imp_w2   = (const float*)d_in[6];
    const float* imp_b2   = (const float*)d_in[7];
    const float* rsn_w1   = (const float*)d_in[8];
    const float* rsn_b1   = (const float*)d_in[9];
    const float* rsn_g    = (const float*)d_in[10];
    const float* rsn_beta = (const float*)d_in[11];
    const float* rsn_w2   = (const float*)d_in[12];
    const float* rsn_b2   = (const float*)d_in[13];
    const float* q_w      = (const float*)d_in[14];
    const float* q_b      = (const float*)d_in[15];
    const float* k_w      = (const float*)d_in[16];
    const float* k_b      = (const float*)d_in[17];
    const float* v_w      = (const float*)d_in[18];
    const float* v_b      = (const float*)d_in[19];
    const float* o_w      = (const float*)d_in[20];
    const float* o_b      = (const float*)d_in[21];
    const float* tmp_w1   = (const float*)d_in[22];
    const float* tmp_b1   = (const float*)d_in[23];
    const float* tmp_g    = (const float*)d_in[24];
    const float* tmp_beta = (const float*)d_in[25];
    const float* tmp_w2   = (const float*)d_in[26];
    const float* tmp_b2   = (const float*)d_in[27];
    const float* norm_g   = (const float*)d_in[28];
    const float* norm_b   = (const float*)d_in[29];
    float* out = (float*)d_out;
    float* ws  = (float*)d_ws;

    // workspace layout (float offsets)
    float* h1  = ws;                       // [4096,512] fp32
    __hip_bfloat16* g1b   = (__hip_bfloat16*)(ws + 2097152);   // rsn1 out bf16 (later o-proj out)
    __hip_bfloat16* x_bf  = (__hip_bfloat16*)(ws + 6291456);
    __hip_bfloat16* xi_bf = (__hip_bfloat16*)(ws + 8388608);
    __hip_bfloat16* h2b   = (__hip_bfloat16*)(ws + 10485760);  // LN(rsn1) out
    __hip_bfloat16* rs_bf = (__hip_bfloat16*)(ws + 12582912);  // reasoned, later attn out
    __hip_bfloat16* qb    = (__hip_bfloat16*)(ws + 14680064);
    __hip_bfloat16* kb    = (__hip_bfloat16*)(ws + 16777216);
    __hip_bfloat16* vtb   = (__hip_bfloat16*)(ws + 20971520);  // [32,64,2048]
    __hip_bfloat16* imp_w1t = (__hip_bfloat16*)(ws + 23068672);  // [512,1024]
    __hip_bfloat16* rsn_w1t = (__hip_bfloat16*)(ws + 23330816);  // [1024,1024]
    __hip_bfloat16* rsn_w2t = (__hip_bfloat16*)(ws + 23855104);
    __hip_bfloat16* q_wt    = (__hip_bfloat16*)(ws + 24379392);
    __hip_bfloat16* k_wt    = (__hip_bfloat16*)(ws + 24903680);
    __hip_bfloat16* v_wt    = (__hip_bfloat16*)(ws + 25427968);
    __hip_bfloat16* o_wt    = (__hip_bfloat16*)(ws + 25952256);
    float* tmp  = ws + 26478592;   // [2,16]
    float* part = ws + 26479104;   // [2,16,1024]
    int*   flg  = (int*)(ws + 26511872);  // [2,32,32]
    float* acc1 = ws + 26513920;   // [2,512]

    dim3 blk(256);
    // fused prep: x->bf16, mask flags, 7 weight transposes
    prep<<<5760, blk, 0, stream>>>(
        x, x_bf, mask, flg,
        imp_w1, rsn_w1, rsn_w2, q_w, k_w, v_w, o_w,
        imp_w1t, rsn_w1t, rsn_w2t, q_wt, k_wt, v_wt, o_wt);

    // importance net (GEMM + fused LN/GELU/gate)
    gemm_mfma64<false><<<dim3(CHALF / 128, NN / 64), blk, 0, stream>>>(
        (const short*)x_bf, (const short*)imp_w1t, imp_b1, h1, nullptr, NN, CHALF, CC);
    imp_fused<<<NN, blk, 0, stream>>>(h1, imp_g, imp_beta, imp_w2, imp_b2, x, xi_bf);
    // reasoning net (all-bf16 intermediates)
    gemm_mfma64<true><<<dim3(CC / 128, NN / 64), blk, 0, stream>>>(
        (const short*)xi_bf, (const short*)rsn_w1t, rsn_b1, nullptr, g1b, NN, CC, CC);
    ln_gelu_bb<<<NN, blk, 0, stream>>>(g1b, rsn_g, rsn_beta, h2b);
    gemm_mfma64<true><<<dim3(CC / 128, NN / 64), blk, 0, stream>>>(
        (const short*)h2b, (const short*)rsn_w2t, rsn_b2, nullptr, rs_bf, NN, CC, CC);
    // temperature net
    mean_part<<<128, blk, 0, stream>>>(rs_bf, part);
    temp_gemv1<<<dim3(CHALF / 64, BB), blk, 0, stream>>>(part, tmp_w1, tmp_b1, acc1);
    temp_fin<<<BB, dim3(512), 0, stream>>>(acc1, tmp_g, tmp_beta, tmp_w2, tmp_b2, tmp);
    // q/k/v projections batched, BK=64; q scaled by temp/8*log2e; v transposed
    gemm_qkv<<<dim3(CC / 128, NN / 128, 3), blk, 0, stream>>>(
        (const short*)rs_bf, (const short*)xi_bf, (const short*)x_bf,
        (const short*)q_wt, (const short*)k_wt, (const short*)v_wt,
        q_b, k_b, v_b, qb, kb, vtb, tmp);
    // flash attention v7
    flash_attn_mfma<<<dim3(TT / 128, BB * HH), blk, 0, stream>>>(
        (const short*)qb, (const short*)kb, (const short*)vtb, mask, flg, rs_bf);
    // output projection (bf16 out into g1b, free now) + residual LN
    gemm_mfma64<true><<<dim3(CC / 128, NN / 64), blk, 0, stream>>>(
        (const short*)rs_bf, (const short*)o_wt, o_b, nullptr, g1b, NN, CC, CC);
    final_ln_b<<<NN, blk, 0, stream>>>(x, g1b, norm_g, norm_b, out);
}